// Round 3
// baseline (419.750 us; speedup 1.0000x reference)
//
#include <hip/hip_runtime.h>

// ---------------------------------------------------------------------------
// ReliabilityGatedCrossAttention — MFMA bf16 hi/lo split, gfx950.
//
// R3 changes vs R2 (theory: attn was VGPR-starved -> serialized L3 loads):
//   * attn: head-split waves (qh x h), register double-buffered K/V prefetch,
//     PV fused into pass 1 (unnormalized, rescale at end), pass 2 only for
//     attn_mean (needs full row-sum first). No cross-wave PV combine.
//   * proj3/final: launch_bounds min-waves 2 -> 1 (VGPR cap 128 -> 512) so
//     the compiler can keep B-fragment loads in flight.
// ---------------------------------------------------------------------------

typedef __attribute__((ext_vector_type(8))) short short8;
typedef __attribute__((ext_vector_type(4))) float f32x4;

#define MFMA16(A, B, C) __builtin_amdgcn_mfma_f32_16x16x32_bf16((A), (B), (C), 0, 0, 0)

__device__ __forceinline__ unsigned short f2bf(float f) {
    union { float f; unsigned int u; } v; v.f = f;
    unsigned int u = v.u;
    return (unsigned short)((u + 0x7fffu + ((u >> 16) & 1u)) >> 16);
}
__device__ __forceinline__ float bf2f(unsigned short h) {
    union { unsigned int u; float f; } v; v.u = ((unsigned int)h) << 16;
    return v.f;
}
__device__ __forceinline__ short8 ld8(const unsigned short* p) {
    return *reinterpret_cast<const short8*>(p);
}

// ---------------------------------------------------------------------------
// 1. Split + transpose weights -> bf16 hi/lo, [n][k]
// ---------------------------------------------------------------------------
__global__ void wsplit_kernel(const float* __restrict__ Wq, const float* __restrict__ Wk,
                              const float* __restrict__ Wv, const float* __restrict__ Wo,
                              unsigned short* __restrict__ WThi, unsigned short* __restrict__ WTlo) {
    int e = blockIdx.x * 256 + threadIdx.x;   // 0 .. 262143
    int m = e >> 16;
    int idx = e & 65535;
    int k = idx >> 8, n = idx & 255;
    const float* W = (m == 0) ? Wq : (m == 1) ? Wk : (m == 2) ? Wv : Wo;
    float v = W[idx];                          // W[k][n]
    unsigned short h = f2bf(v);
    WThi[m * 65536 + n * 256 + k] = h;
    WTlo[m * 65536 + n * 256 + k] = f2bf(v - bf2f(h));
}

// ---------------------------------------------------------------------------
// Shared GEMM inner loop (3-MFMA split).
// ---------------------------------------------------------------------------
__device__ __forceinline__ void gemm_core(const short8 ah[8], const short8 al[8],
                                          const unsigned short* __restrict__ WThi,
                                          const unsigned short* __restrict__ WTlo,
                                          int l15, int lg, f32x4 acc[16]) {
#pragma unroll
    for (int ks = 0; ks < 8; ++ks) {
#pragma unroll
        for (int n = 0; n < 16; ++n) {
            short8 bh = ld8(&WThi[(n * 16 + l15) * 256 + ks * 32 + lg * 8]);
            short8 bl = ld8(&WTlo[(n * 16 + l15) * 256 + ks * 32 + lg * 8]);
            acc[n] = MFMA16(ah[ks], bh, acc[n]);
            acc[n] = MFMA16(ah[ks], bl, acc[n]);
            acc[n] = MFMA16(al[ks], bh, acc[n]);
        }
    }
}

// ---------------------------------------------------------------------------
// 2. Projections (job 0:Q, 1:K, 2:V).  launch_bounds(256,1): VGPR cap 512 so
//    B-fragment loads can stay in flight (at (256,2) acc+A-frags = 128 VGPR
//    exactly -> compiler serialized every load).
// ---------------------------------------------------------------------------
__global__ __launch_bounds__(256, 1) void proj3_kernel(
    const float* __restrict__ query, const float* __restrict__ kv,
    const float* __restrict__ rel,
    const unsigned short* __restrict__ WThi, const unsigned short* __restrict__ WTlo,
    const float* __restrict__ bq, const float* __restrict__ bk, const float* __restrict__ bv,
    unsigned short* __restrict__ Qhi, unsigned short* __restrict__ Qlo,
    unsigned short* __restrict__ Khi, unsigned short* __restrict__ Klo,
    unsigned short* __restrict__ Vtmp) {
    const int job = blockIdx.y;
    const float* X = (job == 0) ? query : kv;
    const unsigned short* wh = WThi + job * 65536;
    const unsigned short* wl = WTlo + job * 65536;
    const float* bias = (job == 0) ? bq : (job == 1) ? bk : bv;
    const float* rs = (job == 0) ? nullptr : rel;
    unsigned short* ohi = (job == 0) ? Qhi : (job == 1) ? Khi : Vtmp;
    unsigned short* olo = (job == 0) ? Qlo : (job == 1) ? Klo : nullptr;

    const int w = threadIdx.x >> 6, l = threadIdx.x & 63;
    const int l15 = l & 15, lg = l >> 4;
    const int arow = blockIdx.x * 64 + w * 16 + l15;

    short8 ah[8], al[8];
#pragma unroll
    for (int ks = 0; ks < 8; ++ks) {
        const float* p = &X[arow * 256 + ks * 32 + lg * 8];
        float4 f0 = *reinterpret_cast<const float4*>(p);
        float4 f1 = *reinterpret_cast<const float4*>(p + 4);
        float vv[8] = {f0.x, f0.y, f0.z, f0.w, f1.x, f1.y, f1.z, f1.w};
#pragma unroll
        for (int j = 0; j < 8; ++j) {
            unsigned short h = f2bf(vv[j]);
            ah[ks][j] = (short)h;
            al[ks][j] = (short)f2bf(vv[j] - bf2f(h));
        }
    }
    f32x4 acc[16];
#pragma unroll
    for (int n = 0; n < 16; ++n) acc[n] = (f32x4){0.f, 0.f, 0.f, 0.f};
    gemm_core(ah, al, wh, wl, l15, lg, acc);

    const int orow0 = blockIdx.x * 64 + w * 16 + lg * 4;
    float rsv[4];
#pragma unroll
    for (int r = 0; r < 4; ++r) rsv[r] = rs ? rs[orow0 + r] : 1.0f;
#pragma unroll
    for (int n = 0; n < 16; ++n) {
        const int col = n * 16 + l15;
        const float bn = bias[col];
#pragma unroll
        for (int r = 0; r < 4; ++r) {
            float c = (acc[n][r] + bn) * rsv[r];
            unsigned short h = f2bf(c);
            ohi[(orow0 + r) * 256 + col] = h;
            if (olo) olo[(orow0 + r) * 256 + col] = f2bf(c - bf2f(h));
        }
    }
}

// ---------------------------------------------------------------------------
// 3. Transpose V: [b][k][256] -> Vt [b][256][2048]
// ---------------------------------------------------------------------------
__global__ void transpose_v_kernel(const unsigned short* __restrict__ Vtmp,
                                   unsigned short* __restrict__ Vt) {
    __shared__ unsigned short tile[32][36];
    const int b = blockIdx.z;
    const int k0 = blockIdx.x * 32, d0 = blockIdx.y * 32;
    const int t = threadIdx.x;
    {
        int kr = t >> 3, dc4 = (t & 7) * 4;
        ushort4 v = *reinterpret_cast<const ushort4*>(&Vtmp[(b * 2048 + k0 + kr) * 256 + d0 + dc4]);
        tile[kr][dc4 + 0] = v.x; tile[kr][dc4 + 1] = v.y;
        tile[kr][dc4 + 2] = v.z; tile[kr][dc4 + 3] = v.w;
    }
    __syncthreads();
    {
        int dr = t >> 3, kc4 = (t & 7) * 4;
        ushort4 o;
        o.x = tile[kc4 + 0][dr]; o.y = tile[kc4 + 1][dr];
        o.z = tile[kc4 + 2][dr]; o.w = tile[kc4 + 3][dr];
        *reinterpret_cast<ushort4*>(&Vt[(b * 256 + d0 + dr) * 2048 + k0 + kc4]) = o;
    }
}

// ---------------------------------------------------------------------------
// 4. Attention.  8 waves = (qh 0..1) x (h 0..3); each wave: 16 q-rows, ONE
//    head, ALL kt.  Register double-buffered K/V prefetch (8+4 loads/kt).
//    Pass 1: QK -> ptilde=exp(S/8)*r ; s += ptilde ; PV accumulates ptilde*V
//            (rescaled by 1/s at the end).
//    Pass 2: QK again -> p = ptilde/s -> pstage ; h==0 waves sum 4 heads ->
//            attn_mean.  One barrier per kt (pstage double-buffered).
// ---------------------------------------------------------------------------
__global__ __launch_bounds__(512, 2) void attn_kernel(
    const unsigned short* __restrict__ Qhi, const unsigned short* __restrict__ Qlo,
    const unsigned short* __restrict__ Khi, const unsigned short* __restrict__ Klo,
    const unsigned short* __restrict__ Vt, const float* __restrict__ rel,
    float* __restrict__ attn_mean,
    unsigned short* __restrict__ AOhi, unsigned short* __restrict__ AOlo) {
    const int b = blockIdx.y;
    const int q0 = blockIdx.x * 32;
    const int tid = threadIdx.x;
    const int w = tid >> 6;
    const int qh = w >> 2, h = w & 3;
    const int l = tid & 63, l15 = l & 15, lg = l >> 4;
    const float C = 0.125f;

    __shared__ __align__(16) unsigned short pstage[2][8][16][40];
    __shared__ float obuf[32][256];

    // Q fragments for this wave's head (A-frag: row=l15, k=lg*8+j)
    short8 qfh[2], qfl[2];
    {
        const int qrow = b * 2048 + q0 + qh * 16 + l15;
#pragma unroll
        for (int kd = 0; kd < 2; ++kd) {
            int off = qrow * 256 + h * 64 + kd * 32 + lg * 8;
            qfh[kd] = ld8(&Qhi[off]);
            qfl[kd] = ld8(&Qlo[off]);
        }
    }

#define KOFF(kt, kc, kd) ((size_t)((b * 2048 + (kt) * 32 + (kc) * 16 + l15) * 256 + h * 64 + (kd) * 32 + lg * 8))
#define VOFF(kt, dc)     ((size_t)((b * 256 + h * 64 + (dc) * 16 + l15) * 2048 + (kt) * 32 + lg * 8))

    short8 kfh[2][2][2], kfl[2][2][2], vf[2][4];
    // prologue: kt = 0
#pragma unroll
    for (int kc = 0; kc < 2; ++kc)
#pragma unroll
        for (int kd = 0; kd < 2; ++kd) {
            kfh[0][kc][kd] = ld8(&Khi[KOFF(0, kc, kd)]);
            kfl[0][kc][kd] = ld8(&Klo[KOFF(0, kc, kd)]);
        }
#pragma unroll
    for (int dc = 0; dc < 4; ++dc) vf[0][dc] = ld8(&Vt[VOFF(0, dc)]);

    float ssum[4] = {0.f, 0.f, 0.f, 0.f};
    f32x4 oacc[4];
#pragma unroll
    for (int dc = 0; dc < 4; ++dc) oacc[dc] = (f32x4){0.f, 0.f, 0.f, 0.f};

    // ---------------- pass 1: ptilde, row-sum, unnormalized PV -------------
#pragma unroll 2
    for (int kt = 0; kt < 64; ++kt) {
        const int cur = kt & 1, nxt = cur ^ 1;
        const int ktn = (kt < 63) ? kt + 1 : 63;
#pragma unroll
        for (int kc = 0; kc < 2; ++kc)
#pragma unroll
            for (int kd = 0; kd < 2; ++kd) {
                kfh[nxt][kc][kd] = ld8(&Khi[KOFF(ktn, kc, kd)]);
                kfl[nxt][kc][kd] = ld8(&Klo[KOFF(ktn, kc, kd)]);
            }
#pragma unroll
        for (int dc = 0; dc < 4; ++dc) vf[nxt][dc] = ld8(&Vt[VOFF(ktn, dc)]);

#pragma unroll
        for (int kc = 0; kc < 2; ++kc) {
            const float rc = fmaxf(rel[b * 2048 + kt * 32 + kc * 16 + l15], 1e-6f);
            f32x4 a = (f32x4){0.f, 0.f, 0.f, 0.f};
#pragma unroll
            for (int kd = 0; kd < 2; ++kd) {
                a = MFMA16(qfh[kd], kfh[cur][kc][kd], a);
                a = MFMA16(qfh[kd], kfl[cur][kc][kd], a);
                a = MFMA16(qfl[kd], kfh[cur][kc][kd], a);
            }
#pragma unroll
            for (int r = 0; r < 4; ++r) {
                float p = __expf(a[r] * C) * rc;
                ssum[r] += p;
                pstage[cur][w][lg * 4 + r][kc * 16 + l15] = f2bf(p);
            }
        }
        // PV with unnormalized ptilde (same-wave LDS RAW)
        short8 pa = ld8(&pstage[cur][w][l15][lg * 8]);
#pragma unroll
        for (int dc = 0; dc < 4; ++dc)
            oacc[dc] = MFMA16(pa, vf[cur][dc], oacc[dc]);
    }

    // row-sum reduce over the 16 column-lanes; all lanes get the sum
    float sinv[4];
#pragma unroll
    for (int r = 0; r < 4; ++r) {
        float v = ssum[r];
        v += __shfl_xor(v, 1); v += __shfl_xor(v, 2);
        v += __shfl_xor(v, 4); v += __shfl_xor(v, 8);
        sinv[r] = 1.0f / v;
    }

    // ---------------- pass 2: attn_mean ------------------------------------
    // re-prologue K (kt = 0)
#pragma unroll
    for (int kc = 0; kc < 2; ++kc)
#pragma unroll
        for (int kd = 0; kd < 2; ++kd) {
            kfh[0][kc][kd] = ld8(&Khi[KOFF(0, kc, kd)]);
            kfl[0][kc][kd] = ld8(&Klo[KOFF(0, kc, kd)]);
        }

#pragma unroll 2
    for (int kt = 0; kt < 64; ++kt) {
        const int cur = kt & 1, nxt = cur ^ 1;
        const int ktn = (kt < 63) ? kt + 1 : 63;
#pragma unroll
        for (int kc = 0; kc < 2; ++kc)
#pragma unroll
            for (int kd = 0; kd < 2; ++kd) {
                kfh[nxt][kc][kd] = ld8(&Khi[KOFF(ktn, kc, kd)]);
                kfl[nxt][kc][kd] = ld8(&Klo[KOFF(ktn, kc, kd)]);
            }
#pragma unroll
        for (int kc = 0; kc < 2; ++kc) {
            const float rc = fmaxf(rel[b * 2048 + kt * 32 + kc * 16 + l15], 1e-6f);
            f32x4 a = (f32x4){0.f, 0.f, 0.f, 0.f};
#pragma unroll
            for (int kd = 0; kd < 2; ++kd) {
                a = MFMA16(qfh[kd], kfh[cur][kc][kd], a);
                a = MFMA16(qfh[kd], kfl[cur][kc][kd], a);
                a = MFMA16(qfl[kd], kfh[cur][kc][kd], a);
            }
#pragma unroll
            for (int r = 0; r < 4; ++r) {
                float p = __expf(a[r] * C) * rc * sinv[r];
                pstage[cur][w][lg * 4 + r][kc * 16 + l15] = f2bf(p);
            }
        }
        __syncthreads();
        // head-mean: the h==0 wave of each qh sums the 4 head slices
        if (h == 0) {
            const int row = l >> 2, k0 = (l & 3) * 8;
            short8 a0 = ld8(&pstage[cur][qh * 4 + 0][row][k0]);
            short8 a1 = ld8(&pstage[cur][qh * 4 + 1][row][k0]);
            short8 a2 = ld8(&pstage[cur][qh * 4 + 2][row][k0]);
            short8 a3 = ld8(&pstage[cur][qh * 4 + 3][row][k0]);
            float m[8];
#pragma unroll
            for (int j = 0; j < 8; ++j)
                m[j] = (bf2f((unsigned short)a0[j]) + bf2f((unsigned short)a1[j]) +
                        bf2f((unsigned short)a2[j]) + bf2f((unsigned short)a3[j])) * 0.25f;
            float* dst = &attn_mean[(size_t)(b * 2048 + q0 + qh * 16 + row) * 2048 + kt * 32 + k0];
            *reinterpret_cast<float4*>(dst)     = (float4){m[0], m[1], m[2], m[3]};
            *reinterpret_cast<float4*>(dst + 4) = (float4){m[4], m[5], m[6], m[7]};
        }
    }

    // ---------------- epilogue: rescale O, write AO -------------------------
    __syncthreads();
#pragma unroll
    for (int dc = 0; dc < 4; ++dc)
#pragma unroll
        for (int r = 0; r < 4; ++r)
            obuf[qh * 16 + lg * 4 + r][h * 64 + dc * 16 + l15] = oacc[dc][r] * sinv[r];
    __syncthreads();
    {
        const int row = tid >> 4;            // 0..31
        const int col0 = (tid & 15) * 16;
        const int orow = b * 2048 + q0 + row;
#pragma unroll
        for (int j = 0; j < 16; ++j) {
            float v = obuf[row][col0 + j];
            unsigned short hh = f2bf(v);
            AOhi[orow * 256 + col0 + j] = hh;
            AOlo[orow * 256 + col0 + j] = f2bf(v - bf2f(hh));
        }
    }
#undef KOFF
#undef VOFF
}

// ---------------------------------------------------------------------------
// 5. out = AO @ Wo + bo
// ---------------------------------------------------------------------------
__global__ __launch_bounds__(256, 1) void final_kernel(
    const unsigned short* __restrict__ AOhi, const unsigned short* __restrict__ AOlo,
    const unsigned short* __restrict__ WThi, const unsigned short* __restrict__ WTlo,
    const float* __restrict__ bo, float* __restrict__ out) {
    const int w = threadIdx.x >> 6, l = threadIdx.x & 63;
    const int l15 = l & 15, lg = l >> 4;
    const int arow = blockIdx.x * 64 + w * 16 + l15;
    short8 ah[8], al[8];
#pragma unroll
    for (int ks = 0; ks < 8; ++ks) {
        ah[ks] = ld8(&AOhi[arow * 256 + ks * 32 + lg * 8]);
        al[ks] = ld8(&AOlo[arow * 256 + ks * 32 + lg * 8]);
    }
    f32x4 acc[16];
#pragma unroll
    for (int n = 0; n < 16; ++n) acc[n] = (f32x4){0.f, 0.f, 0.f, 0.f};
    gemm_core(ah, al, WThi, WTlo, l15, lg, acc);

    const int orow0 = blockIdx.x * 64 + w * 16 + lg * 4;
#pragma unroll
    for (int n = 0; n < 16; ++n) {
        const int col = n * 16 + l15;
        const float bn = bo[col];
#pragma unroll
        for (int r = 0; r < 4; ++r)
            out[(orow0 + r) * 256 + col] = acc[n][r] + bn;
    }
}

// ---------------------------------------------------------------------------
extern "C" void kernel_launch(void* const* d_in, const int* in_sizes, int n_in,
                              void* d_out, int out_size, void* d_ws, size_t ws_size,
                              hipStream_t stream) {
    const float* query = (const float*)d_in[0];
    const float* kv    = (const float*)d_in[1];
    const float* rel   = (const float*)d_in[2];
    const float* Wq    = (const float*)d_in[3];
    const float* bq    = (const float*)d_in[4];
    const float* Wk    = (const float*)d_in[5];
    const float* bk    = (const float*)d_in[6];
    const float* Wv    = (const float*)d_in[7];
    const float* bv    = (const float*)d_in[8];
    const float* Wo    = (const float*)d_in[9];
    const float* bo    = (const float*)d_in[10];

    char* ws = (char*)d_ws;
    unsigned short* WThi = (unsigned short*)(ws + 0);          // 512KB
    unsigned short* WTlo = (unsigned short*)(ws + 524288);     // 512KB
    unsigned short* Qhi  = (unsigned short*)(ws + 1048576);    // 4MB each below
    unsigned short* Qlo  = (unsigned short*)(ws + 5242880);
    unsigned short* Khi  = (unsigned short*)(ws + 9437184);
    unsigned short* Klo  = (unsigned short*)(ws + 13631488);
    unsigned short* Vtmp = (unsigned short*)(ws + 17825792);
    unsigned short* Vt   = (unsigned short*)(ws + 22020096);
    unsigned short* AOhi = (unsigned short*)(ws + 26214400);
    unsigned short* AOlo = (unsigned short*)(ws + 30408704);   // end = 34603008

    float* out = (float*)d_out;
    float* attn_mean = (float*)d_out + 2097152;

    wsplit_kernel<<<1024, 256, 0, stream>>>(Wq, Wk, Wv, Wo, WThi, WTlo);
    proj3_kernel<<<dim3(128, 3), 256, 0, stream>>>(query, kv, rel, WThi, WTlo,
                                                   bq, bk, bv, Qhi, Qlo, Khi, Klo, Vtmp);
    transpose_v_kernel<<<dim3(64, 8, 4), 256, 0, stream>>>(Vtmp, Vt);
    attn_kernel<<<dim3(64, 4), 512, 0, stream>>>(Qhi, Qlo, Khi, Klo, Vt, rel,
                                                 attn_mean, AOhi, AOlo);
    final_kernel<<<128, 256, 0, stream>>>(AOhi, AOlo, WThi + 3 * 65536, WTlo + 3 * 65536,
                                          bo, out);
}

// Round 4
// 417.593 us; speedup vs baseline: 1.0052x; 1.0052x over previous
//
#include <hip/hip_runtime.h>

// ---------------------------------------------------------------------------
// ReliabilityGatedCrossAttention — MFMA bf16 hi/lo split, gfx950.
//
// R4 changes (R3 post-mortem: VGPR=80 proved the compiler demoted the
// runtime-indexed double-buffer arrays -> loads fully serialized at ~500cy
// L3 latency, 6000 cyc/kt-iter):
//   * attn: NAMED-FIELD register double buffers (KBuf/VBuf structs), explicit
//     kt+=2 software pipeline with compile-time buffer selection everywhere.
//   * rel[] staged in LDS once per block (clamped) - kills a serialized
//     scalar load per iteration.
//   * grid 512 x 256thr (16-row q-tiles, 4 head-waves); XCD swizzle so each
//     XCD serves ONE batch -> K/V (5MB) ~fits its private 4MB L2.
// ---------------------------------------------------------------------------

typedef __attribute__((ext_vector_type(8))) short short8;
typedef __attribute__((ext_vector_type(4))) float f32x4;

#define MFMA16(A, B, C) __builtin_amdgcn_mfma_f32_16x16x32_bf16((A), (B), (C), 0, 0, 0)

__device__ __forceinline__ unsigned short f2bf(float f) {
    union { float f; unsigned int u; } v; v.f = f;
    unsigned int u = v.u;
    return (unsigned short)((u + 0x7fffu + ((u >> 16) & 1u)) >> 16);
}
__device__ __forceinline__ float bf2f(unsigned short h) {
    union { unsigned int u; float f; } v; v.u = ((unsigned int)h) << 16;
    return v.f;
}
__device__ __forceinline__ short8 ld8(const unsigned short* p) {
    return *reinterpret_cast<const short8*>(p);
}

// ---------------------------------------------------------------------------
// 1. Split + transpose weights -> bf16 hi/lo, [n][k]
// ---------------------------------------------------------------------------
__global__ void wsplit_kernel(const float* __restrict__ Wq, const float* __restrict__ Wk,
                              const float* __restrict__ Wv, const float* __restrict__ Wo,
                              unsigned short* __restrict__ WThi, unsigned short* __restrict__ WTlo) {
    int e = blockIdx.x * 256 + threadIdx.x;   // 0 .. 262143
    int m = e >> 16;
    int idx = e & 65535;
    int k = idx >> 8, n = idx & 255;
    const float* W = (m == 0) ? Wq : (m == 1) ? Wk : (m == 2) ? Wv : Wo;
    float v = W[idx];                          // W[k][n]
    unsigned short h = f2bf(v);
    WThi[m * 65536 + n * 256 + k] = h;
    WTlo[m * 65536 + n * 256 + k] = f2bf(v - bf2f(h));
}

// ---------------------------------------------------------------------------
// Shared GEMM inner loop (3-MFMA split).
// ---------------------------------------------------------------------------
__device__ __forceinline__ void gemm_core(const short8 ah[8], const short8 al[8],
                                          const unsigned short* __restrict__ WThi,
                                          const unsigned short* __restrict__ WTlo,
                                          int l15, int lg, f32x4 acc[16]) {
#pragma unroll
    for (int ks = 0; ks < 8; ++ks) {
#pragma unroll
        for (int n = 0; n < 16; ++n) {
            short8 bh = ld8(&WThi[(n * 16 + l15) * 256 + ks * 32 + lg * 8]);
            short8 bl = ld8(&WTlo[(n * 16 + l15) * 256 + ks * 32 + lg * 8]);
            acc[n] = MFMA16(ah[ks], bh, acc[n]);
            acc[n] = MFMA16(ah[ks], bl, acc[n]);
            acc[n] = MFMA16(al[ks], bh, acc[n]);
        }
    }
}

// ---------------------------------------------------------------------------
// 2. Projections (job 0:Q, 1:K, 2:V).
// ---------------------------------------------------------------------------
__global__ __launch_bounds__(256, 1) void proj3_kernel(
    const float* __restrict__ query, const float* __restrict__ kv,
    const float* __restrict__ rel,
    const unsigned short* __restrict__ WThi, const unsigned short* __restrict__ WTlo,
    const float* __restrict__ bq, const float* __restrict__ bk, const float* __restrict__ bv,
    unsigned short* __restrict__ Qhi, unsigned short* __restrict__ Qlo,
    unsigned short* __restrict__ Khi, unsigned short* __restrict__ Klo,
    unsigned short* __restrict__ Vtmp) {
    const int job = blockIdx.y;
    const float* X = (job == 0) ? query : kv;
    const unsigned short* wh = WThi + job * 65536;
    const unsigned short* wl = WTlo + job * 65536;
    const float* bias = (job == 0) ? bq : (job == 1) ? bk : bv;
    const float* rs = (job == 0) ? nullptr : rel;
    unsigned short* ohi = (job == 0) ? Qhi : (job == 1) ? Khi : Vtmp;
    unsigned short* olo = (job == 0) ? Qlo : (job == 1) ? Klo : nullptr;

    const int w = threadIdx.x >> 6, l = threadIdx.x & 63;
    const int l15 = l & 15, lg = l >> 4;
    const int arow = blockIdx.x * 64 + w * 16 + l15;

    short8 ah[8], al[8];
#pragma unroll
    for (int ks = 0; ks < 8; ++ks) {
        const float* p = &X[arow * 256 + ks * 32 + lg * 8];
        float4 f0 = *reinterpret_cast<const float4*>(p);
        float4 f1 = *reinterpret_cast<const float4*>(p + 4);
        float vv[8] = {f0.x, f0.y, f0.z, f0.w, f1.x, f1.y, f1.z, f1.w};
#pragma unroll
        for (int j = 0; j < 8; ++j) {
            unsigned short h = f2bf(vv[j]);
            ah[ks][j] = (short)h;
            al[ks][j] = (short)f2bf(vv[j] - bf2f(h));
        }
    }
    f32x4 acc[16];
#pragma unroll
    for (int n = 0; n < 16; ++n) acc[n] = (f32x4){0.f, 0.f, 0.f, 0.f};
    gemm_core(ah, al, wh, wl, l15, lg, acc);

    const int orow0 = blockIdx.x * 64 + w * 16 + lg * 4;
    float rsv[4];
#pragma unroll
    for (int r = 0; r < 4; ++r) rsv[r] = rs ? rs[orow0 + r] : 1.0f;
#pragma unroll
    for (int n = 0; n < 16; ++n) {
        const int col = n * 16 + l15;
        const float bn = bias[col];
#pragma unroll
        for (int r = 0; r < 4; ++r) {
            float c = (acc[n][r] + bn) * rsv[r];
            unsigned short h = f2bf(c);
            ohi[(orow0 + r) * 256 + col] = h;
            if (olo) olo[(orow0 + r) * 256 + col] = f2bf(c - bf2f(h));
        }
    }
}

// ---------------------------------------------------------------------------
// 3. Transpose V: [b][k][256] -> Vt [b][256][2048]
// ---------------------------------------------------------------------------
__global__ void transpose_v_kernel(const unsigned short* __restrict__ Vtmp,
                                   unsigned short* __restrict__ Vt) {
    __shared__ unsigned short tile[32][36];
    const int b = blockIdx.z;
    const int k0 = blockIdx.x * 32, d0 = blockIdx.y * 32;
    const int t = threadIdx.x;
    {
        int kr = t >> 3, dc4 = (t & 7) * 4;
        ushort4 v = *reinterpret_cast<const ushort4*>(&Vtmp[(b * 2048 + k0 + kr) * 256 + d0 + dc4]);
        tile[kr][dc4 + 0] = v.x; tile[kr][dc4 + 1] = v.y;
        tile[kr][dc4 + 2] = v.z; tile[kr][dc4 + 3] = v.w;
    }
    __syncthreads();
    {
        int dr = t >> 3, kc4 = (t & 7) * 4;
        ushort4 o;
        o.x = tile[kc4 + 0][dr]; o.y = tile[kc4 + 1][dr];
        o.z = tile[kc4 + 2][dr]; o.w = tile[kc4 + 3][dr];
        *reinterpret_cast<ushort4*>(&Vt[(b * 256 + d0 + dr) * 2048 + k0 + kc4]) = o;
    }
}

// ---------------------------------------------------------------------------
// 4. Attention, R4.  Grid 512 (1D, XCD-swizzled), block 256 = 4 waves = 4
//    heads, 16 q-rows/block, full kt range.  Named-buffer double-buffered
//    register prefetch; rel in LDS; pass1 = ptilde/rowsum/unnormalized PV;
//    pass2 = attn_mean (p = ptilde * sinv).
// ---------------------------------------------------------------------------
struct KBuf { short8 h00, h01, h10, h11, l00, l01, l10, l11; };
struct VBuf { short8 v0, v1, v2, v3; };

__global__ __launch_bounds__(256, 2) void attn_kernel(
    const unsigned short* __restrict__ Qhi, const unsigned short* __restrict__ Qlo,
    const unsigned short* __restrict__ Khi, const unsigned short* __restrict__ Klo,
    const unsigned short* __restrict__ Vt, const float* __restrict__ rel,
    float* __restrict__ attn_mean,
    unsigned short* __restrict__ AOhi, unsigned short* __restrict__ AOlo) {
    const int bid = blockIdx.x;                       // 0..511
    const int sw = (bid & 7) * 64 + (bid >> 3);       // XCD batch-locality swizzle
    const int b = sw >> 7;                            // batch 0..3
    const int q0 = (sw & 127) * 16;                   // q-tile base row
    const int tid = threadIdx.x;
    const int w = tid >> 6;                           // wave = head
    const int l = tid & 63, l15 = l & 15, lg = l >> 4;

    __shared__ float rel_lds[2048];
    __shared__ __align__(16) unsigned short pstage[2][4][16][40];
    __shared__ float obuf[16][256];

    // stage clamped rel for this batch
    {
        const float4* src = reinterpret_cast<const float4*>(&rel[b * 2048]);
#pragma unroll
        for (int i = 0; i < 2; ++i) {
            float4 v = src[tid * 2 + i];
            float* dst = &rel_lds[tid * 8 + i * 4];
            dst[0] = fmaxf(v.x, 1e-6f); dst[1] = fmaxf(v.y, 1e-6f);
            dst[2] = fmaxf(v.z, 1e-6f); dst[3] = fmaxf(v.w, 1e-6f);
        }
    }

    // Q fragments for this wave's head (A-frag: row=l15, k=lg*8+j)
    short8 qfh0, qfh1, qfl0, qfl1;
    {
        const int qrow = b * 2048 + q0 + l15;
        const int off = qrow * 256 + w * 64 + lg * 8;
        qfh0 = ld8(&Qhi[off]);      qfl0 = ld8(&Qlo[off]);
        qfh1 = ld8(&Qhi[off + 32]); qfl1 = ld8(&Qlo[off + 32]);
    }
    __syncthreads();   // rel_lds ready

#define KOFF(kt_, kc_, kd_) ((size_t)((b * 2048 + (kt_) * 32 + (kc_) * 16 + l15) * 256 + w * 64 + (kd_) * 32 + lg * 8))
#define VOFF(kt_, dc_)      ((size_t)((b * 256 + w * 64 + (dc_) * 16 + l15) * 2048 + (kt_) * 32 + lg * 8))

#define LOADK(B_, kt_) do { \
        B_.h00 = ld8(&Khi[KOFF((kt_), 0, 0)]); B_.h01 = ld8(&Khi[KOFF((kt_), 0, 1)]); \
        B_.h10 = ld8(&Khi[KOFF((kt_), 1, 0)]); B_.h11 = ld8(&Khi[KOFF((kt_), 1, 1)]); \
        B_.l00 = ld8(&Klo[KOFF((kt_), 0, 0)]); B_.l01 = ld8(&Klo[KOFF((kt_), 0, 1)]); \
        B_.l10 = ld8(&Klo[KOFF((kt_), 1, 0)]); B_.l11 = ld8(&Klo[KOFF((kt_), 1, 1)]); \
    } while (0)
#define LOADV(B_, kt_) do { \
        B_.v0 = ld8(&Vt[VOFF((kt_), 0)]); B_.v1 = ld8(&Vt[VOFF((kt_), 1)]); \
        B_.v2 = ld8(&Vt[VOFF((kt_), 2)]); B_.v3 = ld8(&Vt[VOFF((kt_), 3)]); \
    } while (0)

#define QK3(a_, KH_, KL_, QH_, QL_) do { \
        a_ = MFMA16(QH_, KH_, a_); a_ = MFMA16(QH_, KL_, a_); a_ = MFMA16(QL_, KH_, a_); \
    } while (0)

    float ssum[4] = {0.f, 0.f, 0.f, 0.f};
    f32x4 oacc0 = (f32x4){0.f, 0.f, 0.f, 0.f}, oacc1 = oacc0, oacc2 = oacc0, oacc3 = oacc0;

#define STEP1(KB_, VB_, kt_, PB_) do { \
        const float rc0 = rel_lds[(kt_) * 32 + l15]; \
        const float rc1 = rel_lds[(kt_) * 32 + 16 + l15]; \
        f32x4 a0 = (f32x4){0.f, 0.f, 0.f, 0.f}, a1 = (f32x4){0.f, 0.f, 0.f, 0.f}; \
        QK3(a0, KB_.h00, KB_.l00, qfh0, qfl0); QK3(a1, KB_.h10, KB_.l10, qfh0, qfl0); \
        QK3(a0, KB_.h01, KB_.l01, qfh1, qfl1); QK3(a1, KB_.h11, KB_.l11, qfh1, qfl1); \
        _Pragma("unroll") \
        for (int r = 0; r < 4; ++r) { \
            float p0 = __expf(a0[r] * 0.125f) * rc0; \
            float p1 = __expf(a1[r] * 0.125f) * rc1; \
            ssum[r] += p0 + p1; \
            pstage[PB_][w][lg * 4 + r][l15] = f2bf(p0); \
            pstage[PB_][w][lg * 4 + r][16 + l15] = f2bf(p1); \
        } \
        short8 pa = ld8(&pstage[PB_][w][l15][lg * 8]); \
        oacc0 = MFMA16(pa, VB_.v0, oacc0); oacc1 = MFMA16(pa, VB_.v1, oacc1); \
        oacc2 = MFMA16(pa, VB_.v2, oacc2); oacc3 = MFMA16(pa, VB_.v3, oacc3); \
    } while (0)

    // ---------------- pass 1: ptilde, row-sum, unnormalized PV -------------
    {
        KBuf kA, kB; VBuf vA, vB;
        LOADK(kA, 0); LOADV(vA, 0);
        for (int kt = 0; kt < 64; kt += 2) {
            LOADK(kB, kt + 1); LOADV(vB, kt + 1);
            STEP1(kA, vA, kt, 0);
            LOADK(kA, (kt + 2) & 63); LOADV(vA, (kt + 2) & 63);
            STEP1(kB, vB, kt + 1, 1);
        }
    }

    // row-sum reduce over the 16 column-lanes
    float sinv[4];
#pragma unroll
    for (int r = 0; r < 4; ++r) {
        float v = ssum[r];
        v += __shfl_xor(v, 1); v += __shfl_xor(v, 2);
        v += __shfl_xor(v, 4); v += __shfl_xor(v, 8);
        sinv[r] = 1.0f / v;
    }

#define STEP2(KB_, kt_, PB_) do { \
        const float rc0 = rel_lds[(kt_) * 32 + l15]; \
        const float rc1 = rel_lds[(kt_) * 32 + 16 + l15]; \
        f32x4 a0 = (f32x4){0.f, 0.f, 0.f, 0.f}, a1 = (f32x4){0.f, 0.f, 0.f, 0.f}; \
        QK3(a0, KB_.h00, KB_.l00, qfh0, qfl0); QK3(a1, KB_.h10, KB_.l10, qfh0, qfl0); \
        QK3(a0, KB_.h01, KB_.l01, qfh1, qfl1); QK3(a1, KB_.h11, KB_.l11, qfh1, qfl1); \
        _Pragma("unroll") \
        for (int r = 0; r < 4; ++r) { \
            float p0 = __expf(a0[r] * 0.125f) * rc0 * sinv[r]; \
            float p1 = __expf(a1[r] * 0.125f) * rc1 * sinv[r]; \
            pstage[PB_][w][lg * 4 + r][l15] = f2bf(p0); \
            pstage[PB_][w][lg * 4 + r][16 + l15] = f2bf(p1); \
        } \
        __syncthreads(); \
        if (w == 0) { \
            const int row = l >> 2, k0 = (l & 3) * 8; \
            short8 s0 = ld8(&pstage[PB_][0][row][k0]); \
            short8 s1 = ld8(&pstage[PB_][1][row][k0]); \
            short8 s2 = ld8(&pstage[PB_][2][row][k0]); \
            short8 s3 = ld8(&pstage[PB_][3][row][k0]); \
            float m[8]; \
            _Pragma("unroll") \
            for (int j = 0; j < 8; ++j) \
                m[j] = (bf2f((unsigned short)s0[j]) + bf2f((unsigned short)s1[j]) + \
                        bf2f((unsigned short)s2[j]) + bf2f((unsigned short)s3[j])) * 0.25f; \
            float* dst = &attn_mean[(size_t)(b * 2048 + q0 + row) * 2048 + (kt_) * 32 + k0]; \
            *reinterpret_cast<float4*>(dst) = (float4){m[0], m[1], m[2], m[3]}; \
            *reinterpret_cast<float4*>(dst + 4) = (float4){m[4], m[5], m[6], m[7]}; \
        } \
    } while (0)

    // ---------------- pass 2: attn_mean ------------------------------------
    {
        KBuf kA, kB;
        LOADK(kA, 0);
        for (int kt = 0; kt < 64; kt += 2) {
            LOADK(kB, kt + 1);
            STEP2(kA, kt, 0);
            LOADK(kA, (kt + 2) & 63);
            STEP2(kB, kt + 1, 1);
        }
    }

    // ---------------- epilogue: rescale O, write AO -------------------------
#pragma unroll
    for (int r = 0; r < 4; ++r) {
        obuf[lg * 4 + r][w * 64 + l15]      = oacc0[r] * sinv[r];
        obuf[lg * 4 + r][w * 64 + 16 + l15] = oacc1[r] * sinv[r];
        obuf[lg * 4 + r][w * 64 + 32 + l15] = oacc2[r] * sinv[r];
        obuf[lg * 4 + r][w * 64 + 48 + l15] = oacc3[r] * sinv[r];
    }
    __syncthreads();
    {
        const int row = tid >> 4;            // 0..15
        const int col0 = (tid & 15) * 16;
        const int orow = b * 2048 + q0 + row;
#pragma unroll
        for (int j = 0; j < 16; ++j) {
            float v = obuf[row][col0 + j];
            unsigned short hh = f2bf(v);
            AOhi[orow * 256 + col0 + j] = hh;
            AOlo[orow * 256 + col0 + j] = f2bf(v - bf2f(hh));
        }
    }
#undef KOFF
#undef VOFF
#undef LOADK
#undef LOADV
#undef QK3
#undef STEP1
#undef STEP2
}

// ---------------------------------------------------------------------------
// 5. out = AO @ Wo + bo
// ---------------------------------------------------------------------------
__global__ __launch_bounds__(256, 1) void final_kernel(
    const unsigned short* __restrict__ AOhi, const unsigned short* __restrict__ AOlo,
    const unsigned short* __restrict__ WThi, const unsigned short* __restrict__ WTlo,
    const float* __restrict__ bo, float* __restrict__ out) {
    const int w = threadIdx.x >> 6, l = threadIdx.x & 63;
    const int l15 = l & 15, lg = l >> 4;
    const int arow = blockIdx.x * 64 + w * 16 + l15;
    short8 ah[8], al[8];
#pragma unroll
    for (int ks = 0; ks < 8; ++ks) {
        ah[ks] = ld8(&AOhi[arow * 256 + ks * 32 + lg * 8]);
        al[ks] = ld8(&AOlo[arow * 256 + ks * 32 + lg * 8]);
    }
    f32x4 acc[16];
#pragma unroll
    for (int n = 0; n < 16; ++n) acc[n] = (f32x4){0.f, 0.f, 0.f, 0.f};
    gemm_core(ah, al, WThi, WTlo, l15, lg, acc);

    const int orow0 = blockIdx.x * 64 + w * 16 + lg * 4;
#pragma unroll
    for (int n = 0; n < 16; ++n) {
        const int col = n * 16 + l15;
        const float bn = bo[col];
#pragma unroll
        for (int r = 0; r < 4; ++r)
            out[(orow0 + r) * 256 + col] = acc[n][r] + bn;
    }
}

// ---------------------------------------------------------------------------
extern "C" void kernel_launch(void* const* d_in, const int* in_sizes, int n_in,
                              void* d_out, int out_size, void* d_ws, size_t ws_size,
                              hipStream_t stream) {
    const float* query = (const float*)d_in[0];
    const float* kv    = (const float*)d_in[1];
    const float* rel   = (const float*)d_in[2];
    const float* Wq    = (const float*)d_in[3];
    const float* bq    = (const float*)d_in[4];
    const float* Wk    = (const float*)d_in[5];
    const float* bk    = (const float*)d_in[6];
    const float* Wv    = (const float*)d_in[7];
    const float* bv    = (const float*)d_in[8];
    const float* Wo    = (const float*)d_in[9];
    const float* bo    = (const float*)d_in[10];

    char* ws = (char*)d_ws;
    unsigned short* WThi = (unsigned short*)(ws + 0);          // 512KB
    unsigned short* WTlo = (unsigned short*)(ws + 524288);     // 512KB
    unsigned short* Qhi  = (unsigned short*)(ws + 1048576);    // 4MB each below
    unsigned short* Qlo  = (unsigned short*)(ws + 5242880);
    unsigned short* Khi  = (unsigned short*)(ws + 9437184);
    unsigned short* Klo  = (unsigned short*)(ws + 13631488);
    unsigned short* Vtmp = (unsigned short*)(ws + 17825792);
    unsigned short* Vt   = (unsigned short*)(ws + 22020096);
    unsigned short* AOhi = (unsigned short*)(ws + 26214400);
    unsigned short* AOlo = (unsigned short*)(ws + 30408704);   // end = 34603008

    float* out = (float*)d_out;
    float* attn_mean = (float*)d_out + 2097152;

    wsplit_kernel<<<1024, 256, 0, stream>>>(Wq, Wk, Wv, Wo, WThi, WTlo);
    proj3_kernel<<<dim3(128, 3), 256, 0, stream>>>(query, kv, rel, WThi, WTlo,
                                                   bq, bk, bv, Qhi, Qlo, Khi, Klo, Vtmp);
    transpose_v_kernel<<<dim3(64, 8, 4), 256, 0, stream>>>(Vtmp, Vt);
    attn_kernel<<<512, 256, 0, stream>>>(Qhi, Qlo, Khi, Klo, Vt, rel,
                                         attn_mean, AOhi, AOlo);
    final_kernel<<<128, 256, 0, stream>>>(AOhi, AOlo, WThi + 3 * 65536, WTlo + 3 * 65536,
                                          bo, out);
}

// Round 5
// 254.902 us; speedup vs baseline: 1.6467x; 1.6382x over previous
//
#include <hip/hip_runtime.h>

// ---------------------------------------------------------------------------
// ReliabilityGatedCrossAttention — MFMA bf16 hi/lo split, gfx950.
//
// R5: R2-R4 post-mortems proved hipcc will not keep global->register
// prefetch in flight (VGPR counts 80/112 << buffer size; ~20 serialized
// ~300cy loads per kt = the whole 320us).  Rewrite attn + proj GEMMs on the
// proven global_load_lds + LDS double-buffer template (guide §5 T3-minimum):
//   stage(next tile) -> compute(cur from LDS) -> __syncthreads -> swap.
// LDS layouts XOR-swizzled; global SOURCE pre-swizzled (linear LDS dest).
// ---------------------------------------------------------------------------

typedef __attribute__((ext_vector_type(8))) short short8;
typedef __attribute__((ext_vector_type(4))) float f32x4;

#define MFMA16(A, B, C) __builtin_amdgcn_mfma_f32_16x16x32_bf16((A), (B), (C), 0, 0, 0)

__device__ __forceinline__ unsigned short f2bf(float f) {
    union { float f; unsigned int u; } v; v.f = f;
    unsigned int u = v.u;
    return (unsigned short)((u + 0x7fffu + ((u >> 16) & 1u)) >> 16);
}
__device__ __forceinline__ float bf2f(unsigned short h) {
    union { unsigned int u; float f; } v; v.u = ((unsigned int)h) << 16;
    return v.f;
}
__device__ __forceinline__ short8 ld8(const unsigned short* p) {
    return *reinterpret_cast<const short8*>(p);
}
// async global->LDS, 16B per lane. lds dest must be wave-uniform base.
__device__ __forceinline__ void gld16(const unsigned short* g, unsigned short* l) {
    __builtin_amdgcn_global_load_lds(
        (const __attribute__((address_space(1))) unsigned int*)g,
        (__attribute__((address_space(3))) unsigned int*)l, 16, 0, 0);
}

// ---------------------------------------------------------------------------
// 1. Split + transpose weights -> bf16 hi/lo, [n][k]
// ---------------------------------------------------------------------------
__global__ void wsplit_kernel(const float* __restrict__ Wq, const float* __restrict__ Wk,
                              const float* __restrict__ Wv, const float* __restrict__ Wo,
                              unsigned short* __restrict__ WThi, unsigned short* __restrict__ WTlo) {
    int e = blockIdx.x * 256 + threadIdx.x;   // 0 .. 262143
    int m = e >> 16;
    int idx = e & 65535;
    int k = idx >> 8, n = idx & 255;
    const float* W = (m == 0) ? Wq : (m == 1) ? Wk : (m == 2) ? Wv : Wo;
    float v = W[idx];                          // W[k][n]
    unsigned short h = f2bf(v);
    WThi[m * 65536 + n * 256 + k] = h;
    WTlo[m * 65536 + n * 256 + k] = f2bf(v - bf2f(h));
}

// ---------------------------------------------------------------------------
// Weight-staged GEMM core used by proj3 and final.
// LDS tile: [256 n][64 k] bf16, rows 128B = 8 granules, swizzle g^=(row&7).
// Stage: 32 slots/matrix/tile, 8 waves x 4 slots; slot s = rows 8s..8s+7.
// ---------------------------------------------------------------------------
#define STAGE_W(dsth, dstl, srch, srcl, kt_) do {                                   \
    _Pragma("unroll")                                                               \
    for (int j_ = 0; j_ < 4; ++j_) {                                                \
        int s_ = w * 4 + j_;                                                        \
        int rowl_ = 8 * s_ + (l >> 3);                                              \
        int g_ = l & 7;                                                             \
        int src_ = rowl_ * 256 + (kt_) * 64 + ((g_ ^ (rowl_ & 7)) << 3);            \
        gld16(&(srch)[src_], &(dsth)[s_ * 512]);                                    \
        gld16(&(srcl)[src_], &(dstl)[s_ * 512]);                                    \
    }                                                                               \
} while (0)

#define GEMM_TILE(bufh, bufl, kt_) do {                                             \
    _Pragma("unroll")                                                               \
    for (int ksl_ = 0; ksl_ < 2; ++ksl_) {                                          \
        _Pragma("unroll")                                                           \
        for (int n_ = 0; n_ < 16; ++n_) {                                           \
            int r_ = n_ * 16 + l15;                                                 \
            int g0_ = ksl_ * 4 + lg;                                                \
            int idx_ = r_ * 64 + ((g0_ ^ (r_ & 7)) << 3);                           \
            short8 bh_ = ld8(&(bufh)[idx_]);                                        \
            short8 bl_ = ld8(&(bufl)[idx_]);                                        \
            acc[n_] = MFMA16(ah[(kt_) * 2 + ksl_], bh_, acc[n_]);                   \
            acc[n_] = MFMA16(ah[(kt_) * 2 + ksl_], bl_, acc[n_]);                   \
            acc[n_] = MFMA16(al[(kt_) * 2 + ksl_], bh_, acc[n_]);                   \
        }                                                                           \
    }                                                                               \
} while (0)

// ---------------------------------------------------------------------------
// 2. Projections (job 0:Q, 1:K, 2:V).  512 thr = 8 waves x 16 rows = 128 rows
//    per block; grid (64, 3).  Weights LDS-staged, double-buffered BK=64.
// ---------------------------------------------------------------------------
__global__ __launch_bounds__(512, 1) void proj3_kernel(
    const float* __restrict__ query, const float* __restrict__ kv,
    const float* __restrict__ rel,
    const unsigned short* __restrict__ WThi, const unsigned short* __restrict__ WTlo,
    const float* __restrict__ bq, const float* __restrict__ bk, const float* __restrict__ bv,
    unsigned short* __restrict__ Qhi, unsigned short* __restrict__ Qlo,
    unsigned short* __restrict__ Khi, unsigned short* __restrict__ Klo,
    unsigned short* __restrict__ Vtmp) {
    const int job = blockIdx.y;
    const float* X = (job == 0) ? query : kv;
    const unsigned short* wgh = WThi + job * 65536;
    const unsigned short* wgl = WTlo + job * 65536;
    const float* bias = (job == 0) ? bq : (job == 1) ? bk : bv;
    const float* rs = (job == 0) ? nullptr : rel;
    unsigned short* ohi = (job == 0) ? Qhi : (job == 1) ? Khi : Vtmp;
    unsigned short* olo = (job == 0) ? Qlo : (job == 1) ? Klo : nullptr;

    __shared__ unsigned short wh_lds[2][256 * 64];   // 32KB each
    __shared__ unsigned short wl_lds[2][256 * 64];   // 32KB each  -> 128KB

    const int w = threadIdx.x >> 6, l = threadIdx.x & 63;
    const int l15 = l & 15, lg = l >> 4;
    const int arow = blockIdx.x * 128 + w * 16 + l15;

    short8 ah[8], al[8];
#pragma unroll
    for (int ks = 0; ks < 8; ++ks) {
        const float* p = &X[arow * 256 + ks * 32 + lg * 8];
        float4 f0 = *reinterpret_cast<const float4*>(p);
        float4 f1 = *reinterpret_cast<const float4*>(p + 4);
        float vv[8] = {f0.x, f0.y, f0.z, f0.w, f1.x, f1.y, f1.z, f1.w};
#pragma unroll
        for (int j = 0; j < 8; ++j) {
            unsigned short h = f2bf(vv[j]);
            ah[ks][j] = (short)h;
            al[ks][j] = (short)f2bf(vv[j] - bf2f(h));
        }
    }
    f32x4 acc[16];
#pragma unroll
    for (int n = 0; n < 16; ++n) acc[n] = (f32x4){0.f, 0.f, 0.f, 0.f};

    STAGE_W(wh_lds[0], wl_lds[0], wgh, wgl, 0);
    __syncthreads();
#pragma unroll
    for (int kt = 0; kt < 4; ++kt) {
        const int cur = kt & 1, nx = cur ^ 1;
        if (kt < 3) STAGE_W(wh_lds[nx], wl_lds[nx], wgh, wgl, kt + 1);
        GEMM_TILE(wh_lds[cur], wl_lds[cur], kt);
        __syncthreads();
    }

    const int orow0 = blockIdx.x * 128 + w * 16 + lg * 4;
    float rsv[4];
#pragma unroll
    for (int r = 0; r < 4; ++r) rsv[r] = rs ? rs[orow0 + r] : 1.0f;
#pragma unroll
    for (int n = 0; n < 16; ++n) {
        const int col = n * 16 + l15;
        const float bn = bias[col];
#pragma unroll
        for (int r = 0; r < 4; ++r) {
            float c = (acc[n][r] + bn) * rsv[r];
            unsigned short h = f2bf(c);
            ohi[(orow0 + r) * 256 + col] = h;
            if (olo) olo[(orow0 + r) * 256 + col] = f2bf(c - bf2f(h));
        }
    }
}

// ---------------------------------------------------------------------------
// 3. Transpose V: [b][k][256] -> Vt [b][256][2048]
// ---------------------------------------------------------------------------
__global__ void transpose_v_kernel(const unsigned short* __restrict__ Vtmp,
                                   unsigned short* __restrict__ Vt) {
    __shared__ unsigned short tile[32][36];
    const int b = blockIdx.z;
    const int k0 = blockIdx.x * 32, d0 = blockIdx.y * 32;
    const int t = threadIdx.x;
    {
        int kr = t >> 3, dc4 = (t & 7) * 4;
        ushort4 v = *reinterpret_cast<const ushort4*>(&Vtmp[(b * 2048 + k0 + kr) * 256 + d0 + dc4]);
        tile[kr][dc4 + 0] = v.x; tile[kr][dc4 + 1] = v.y;
        tile[kr][dc4 + 2] = v.z; tile[kr][dc4 + 3] = v.w;
    }
    __syncthreads();
    {
        int dr = t >> 3, kc4 = (t & 7) * 4;
        ushort4 o;
        o.x = tile[kc4 + 0][dr]; o.y = tile[kc4 + 1][dr];
        o.z = tile[kc4 + 2][dr]; o.w = tile[kc4 + 3][dr];
        *reinterpret_cast<ushort4*>(&Vt[(b * 256 + d0 + dr) * 2048 + k0 + kc4]) = o;
    }
}

// ---------------------------------------------------------------------------
// 4. Attention, R5.  Grid 256 (XCD-swizzled: batch per XCD-pair), block 512
//    = 8 waves = (qs 0..1) x (h 0..3); 32 q-rows/block.
//    Per kt (32 k-rows): cooperative global_load_lds stage of K-hi/K-lo/V
//    (48KB) into double buffer; one __syncthreads per kt (implicit vmcnt(0)
//    = the T3-minimum pipeline).  K rows 512B: granule swizzle ^(row&7);
//    V rows 64B: ^(row&3).  Pass1: ptilde/rowsum/unnormalized PV.
//    Pass2: p=ptilde*sinv -> fp32 pstage -> head-mean -> attn_mean.
// ---------------------------------------------------------------------------
__global__ __launch_bounds__(512, 1) void attn_kernel(
    const unsigned short* __restrict__ Qhi, const unsigned short* __restrict__ Qlo,
    const unsigned short* __restrict__ Khi, const unsigned short* __restrict__ Klo,
    const unsigned short* __restrict__ Vt, const float* __restrict__ rel,
    float* __restrict__ attn_mean,
    unsigned short* __restrict__ AOhi, unsigned short* __restrict__ AOlo) {
    const int bid = blockIdx.x;                       // 0..255
    const int sw = (bid & 7) * 32 + (bid >> 3);       // XCD batch-locality
    const int b = sw >> 6;                            // batch 0..3
    const int q0 = (sw & 63) * 32;                    // q-tile base (32 rows)
    const int tid = threadIdx.x;
    const int w = tid >> 6;                           // 0..7
    const int h = w & 3, qs = w >> 2;
    const int l = tid & 63, l15 = l & 15, lg = l >> 4;
    const float C2 = 0.18033688011112042f;            // 0.125 * log2(e)

    __shared__ unsigned short ldsKh[2][32 * 256];     // 16KB x2
    __shared__ unsigned short ldsKl[2][32 * 256];     // 16KB x2
    __shared__ unsigned short ldsV[2][256 * 32];      // 16KB x2
    __shared__ float rel_lds[2048];                   // 8KB
    __shared__ __align__(16) char ps_raw[2 * 8 * 16 * 36 * 4];  // 36KB
    unsigned short* pbf = (unsigned short*)ps_raw;    // pass1: [8][16][40] bf16
    float* ps32 = (float*)ps_raw;                     // pass2: [2][8][16][36] f32

    // stage clamped rel for this batch (512 thr x 4 floats)
    {
        float4 v = reinterpret_cast<const float4*>(&rel[b * 2048])[tid];
        float* d = &rel_lds[tid * 4];
        d[0] = fmaxf(v.x, 1e-6f); d[1] = fmaxf(v.y, 1e-6f);
        d[2] = fmaxf(v.z, 1e-6f); d[3] = fmaxf(v.w, 1e-6f);
    }

    // Q fragments: wave = (qs, h); A-frag row = l15, k = kd*32 + lg*8 + j
    short8 qfh0, qfh1, qfl0, qfl1;
    {
        const int off = (b * 2048 + q0 + qs * 16 + l15) * 256 + h * 64 + lg * 8;
        qfh0 = ld8(&Qhi[off]);      qfl0 = ld8(&Qlo[off]);
        qfh1 = ld8(&Qhi[off + 32]); qfl1 = ld8(&Qlo[off + 32]);
    }

    // staging: K 16KB = 16 slots (2 rows/slot), V 16KB = 16 slots (16 rows)
#define STAGE_K(nx_, kt_) do {                                                      \
    _Pragma("unroll")                                                               \
    for (int j_ = 0; j_ < 2; ++j_) {                                                \
        int s_ = w * 2 + j_;                                                        \
        int rowl_ = 2 * s_ + (l >> 5);                                              \
        int g_ = l & 31;                                                            \
        size_t src_ = (size_t)(b * 2048 + (kt_) * 32 + rowl_) * 256 +               \
                      ((g_ ^ (rowl_ & 7)) << 3);                                    \
        gld16(&Khi[src_], &ldsKh[nx_][s_ * 512]);                                   \
        gld16(&Klo[src_], &ldsKl[nx_][s_ * 512]);                                   \
    }                                                                               \
} while (0)
#define STAGE_V(nx_, kt_) do {                                                      \
    _Pragma("unroll")                                                               \
    for (int j_ = 0; j_ < 2; ++j_) {                                                \
        int s_ = w * 2 + j_;                                                        \
        int rowl_ = s_ * 16 + (l >> 2);                                             \
        int g_ = l & 3;                                                             \
        size_t src_ = (size_t)(b * 256 + rowl_) * 2048 + (kt_) * 32 +               \
                      ((g_ ^ (rowl_ & 3)) << 3);                                    \
        gld16(&Vt[src_], &ldsV[nx_][s_ * 512]);                                     \
    }                                                                               \
} while (0)

    // QK from swizzled LDS: r = kc*16+l15 (r&7 == l15&7)
#define QK_TILE(cur_, kc_, adst_) do {                                              \
    const int r_ = (kc_) * 16 + l15;                                                \
    const int sz_ = l15 & 7;                                                        \
    short8 kh0_ = ld8(&ldsKh[cur_][r_ * 256 + (((h * 8 + lg) ^ sz_) << 3)]);        \
    short8 kh1_ = ld8(&ldsKh[cur_][r_ * 256 + (((h * 8 + 4 + lg) ^ sz_) << 3)]);    \
    short8 kl0_ = ld8(&ldsKl[cur_][r_ * 256 + (((h * 8 + lg) ^ sz_) << 3)]);        \
    short8 kl1_ = ld8(&ldsKl[cur_][r_ * 256 + (((h * 8 + 4 + lg) ^ sz_) << 3)]);    \
    adst_ = MFMA16(qfh0, kh0_, adst_); adst_ = MFMA16(qfh0, kl0_, adst_);           \
    adst_ = MFMA16(qfl0, kh0_, adst_);                                              \
    adst_ = MFMA16(qfh1, kh1_, adst_); adst_ = MFMA16(qfh1, kl1_, adst_);           \
    adst_ = MFMA16(qfl1, kh1_, adst_);                                              \
} while (0)

    float ssum[4] = {0.f, 0.f, 0.f, 0.f};
    f32x4 oacc0 = (f32x4){0.f, 0.f, 0.f, 0.f};
    f32x4 oacc1 = oacc0, oacc2 = oacc0, oacc3 = oacc0;

    // ---------------- pass 1 ------------------------------------------------
    STAGE_K(0, 0); STAGE_V(0, 0);
    __syncthreads();
    for (int kt = 0; kt < 64; ++kt) {
        const int cur = kt & 1, nx = cur ^ 1;
        if (kt < 63) { STAGE_K(nx, kt + 1); STAGE_V(nx, kt + 1); }
#pragma unroll
        for (int kc = 0; kc < 2; ++kc) {
            f32x4 a = (f32x4){0.f, 0.f, 0.f, 0.f};
            QK_TILE(cur, kc, a);
            const float rc = rel_lds[kt * 32 + kc * 16 + l15];
#pragma unroll
            for (int r4 = 0; r4 < 4; ++r4) {
                float p = exp2f(a[r4] * C2) * rc;
                ssum[r4] += p;
                pbf[w * 640 + (lg * 4 + r4) * 40 + kc * 16 + l15] = f2bf(p);
            }
        }
        {   // PV (same-wave LDS RAW; in-order DS + compiler lgkmcnt)
            short8 pa = ld8(&pbf[w * 640 + l15 * 40 + lg * 8]);
            const int vsz = l15 & 3;
            short8 v0 = ld8(&ldsV[cur][(h * 64 + l15) * 32 + ((lg ^ vsz) << 3)]);
            short8 v1 = ld8(&ldsV[cur][(h * 64 + 16 + l15) * 32 + ((lg ^ vsz) << 3)]);
            short8 v2 = ld8(&ldsV[cur][(h * 64 + 32 + l15) * 32 + ((lg ^ vsz) << 3)]);
            short8 v3 = ld8(&ldsV[cur][(h * 64 + 48 + l15) * 32 + ((lg ^ vsz) << 3)]);
            oacc0 = MFMA16(pa, v0, oacc0); oacc1 = MFMA16(pa, v1, oacc1);
            oacc2 = MFMA16(pa, v2, oacc2); oacc3 = MFMA16(pa, v3, oacc3);
        }
        __syncthreads();
    }

    // row sums -> sinv (reduce over the 16 k-col lanes)
    float sinv[4];
#pragma unroll
    for (int r4 = 0; r4 < 4; ++r4) {
        float v = ssum[r4];
        v += __shfl_xor(v, 1); v += __shfl_xor(v, 2);
        v += __shfl_xor(v, 4); v += __shfl_xor(v, 8);
        sinv[r4] = 1.0f / v;
    }

    // ---------------- pass 2: attn_mean -------------------------------------
    STAGE_K(0, 0);
    __syncthreads();
    for (int kt = 0; kt < 64; ++kt) {
        const int cur = kt & 1, nx = cur ^ 1;
        if (kt < 63) STAGE_K(nx, kt + 1);
        const int par = kt & 1;
#pragma unroll
        for (int kc = 0; kc < 2; ++kc) {
            f32x4 a = (f32x4){0.f, 0.f, 0.f, 0.f};
            QK_TILE(cur, kc, a);
            const float rc = rel_lds[kt * 32 + kc * 16 + l15];
#pragma unroll
            for (int r4 = 0; r4 < 4; ++r4) {
                float p = exp2f(a[r4] * C2) * rc * sinv[r4];
                ps32[((par * 8 + w) * 16 + lg * 4 + r4) * 36 + kc * 16 + l15] = p;
            }
        }
        __syncthreads();
        if (h == 0) {   // waves 0 (qs=0) and 4 (qs=1): head-mean -> attn_mean
            const int rr = l & 15, kq = l >> 4;
            float m[8];
#pragma unroll
            for (int j = 0; j < 8; ++j) m[j] = 0.f;
#pragma unroll
            for (int hh = 0; hh < 4; ++hh) {
                const float* src = &ps32[((par * 8 + qs * 4 + hh) * 16 + rr) * 36 + kq * 8];
                float4 x0 = *reinterpret_cast<const float4*>(src);
                float4 x1 = *reinterpret_cast<const float4*>(src + 4);
                m[0] += x0.x; m[1] += x0.y; m[2] += x0.z; m[3] += x0.w;
                m[4] += x1.x; m[5] += x1.y; m[6] += x1.z; m[7] += x1.w;
            }
            float* dst = &attn_mean[(size_t)(b * 2048 + q0 + qs * 16 + rr) * 2048 +
                                    kt * 32 + kq * 8];
            *reinterpret_cast<float4*>(dst) = (float4){m[0] * 0.25f, m[1] * 0.25f,
                                                       m[2] * 0.25f, m[3] * 0.25f};
            *reinterpret_cast<float4*>(dst + 4) = (float4){m[4] * 0.25f, m[5] * 0.25f,
                                                           m[6] * 0.25f, m[7] * 0.25f};
        }
    }

    // ---------------- epilogue: rescale O, write AO (hi/lo) ------------------
#pragma unroll
    for (int r4 = 0; r4 < 4; ++r4) {
        const size_t orow = (size_t)(b * 2048 + q0 + qs * 16 + lg * 4 + r4) * 256 + h * 64 + l15;
        float v0 = oacc0[r4] * sinv[r4], v1 = oacc1[r4] * sinv[r4];
        float v2 = oacc2[r4] * sinv[r4], v3 = oacc3[r4] * sinv[r4];
        unsigned short h0 = f2bf(v0), h1 = f2bf(v1), h2 = f2bf(v2), h3 = f2bf(v3);
        AOhi[orow]      = h0; AOlo[orow]      = f2bf(v0 - bf2f(h0));
        AOhi[orow + 16] = h1; AOlo[orow + 16] = f2bf(v1 - bf2f(h1));
        AOhi[orow + 32] = h2; AOlo[orow + 32] = f2bf(v2 - bf2f(h2));
        AOhi[orow + 48] = h3; AOlo[orow + 48] = f2bf(v3 - bf2f(h3));
    }
#undef STAGE_K
#undef STAGE_V
#undef QK_TILE
}

// ---------------------------------------------------------------------------
// 5. out = AO @ Wo + bo  (LDS-staged weights, same template as proj3)
// ---------------------------------------------------------------------------
__global__ __launch_bounds__(512, 1) void final_kernel(
    const unsigned short* __restrict__ AOhi, const unsigned short* __restrict__ AOlo,
    const unsigned short* __restrict__ WThi, const unsigned short* __restrict__ WTlo,
    const float* __restrict__ bo, float* __restrict__ out) {
    __shared__ unsigned short wh_lds[2][256 * 64];
    __shared__ unsigned short wl_lds[2][256 * 64];

    const int w = threadIdx.x >> 6, l = threadIdx.x & 63;
    const int l15 = l & 15, lg = l >> 4;
    const int arow = blockIdx.x * 128 + w * 16 + l15;

    short8 ah[8], al[8];
#pragma unroll
    for (int ks = 0; ks < 8; ++ks) {
        ah[ks] = ld8(&AOhi[arow * 256 + ks * 32 + lg * 8]);
        al[ks] = ld8(&AOlo[arow * 256 + ks * 32 + lg * 8]);
    }
    f32x4 acc[16];
#pragma unroll
    for (int n = 0; n < 16; ++n) acc[n] = (f32x4){0.f, 0.f, 0.f, 0.f};

    STAGE_W(wh_lds[0], wl_lds[0], WThi, WTlo, 0);
    __syncthreads();
#pragma unroll
    for (int kt = 0; kt < 4; ++kt) {
        const int cur = kt & 1, nx = cur ^ 1;
        if (kt < 3) STAGE_W(wh_lds[nx], wl_lds[nx], WThi, WTlo, kt + 1);
        GEMM_TILE(wh_lds[cur], wl_lds[cur], kt);
        __syncthreads();
    }

    const int orow0 = blockIdx.x * 128 + w * 16 + lg * 4;
#pragma unroll
    for (int n = 0; n < 16; ++n) {
        const int col = n * 16 + l15;
        const float bn = bo[col];
#pragma unroll
        for (int r = 0; r < 4; ++r)
            out[(orow0 + r) * 256 + col] = acc[n][r] + bn;
    }
}

// ---------------------------------------------------------------------------
extern "C" void kernel_launch(void* const* d_in, const int* in_sizes, int n_in,
                              void* d_out, int out_size, void* d_ws, size_t ws_size,
                              hipStream_t stream) {
    const float* query = (const float*)d_in[0];
    const float* kv    = (const float*)d_in[1];
    const float* rel   = (const float*)d_in[2];
    const float* Wq    = (const float*)d_in[3];
    const float* bq    = (const float*)d_in[4];
    const float* Wk    = (const float*)d_in[5];
    const float* bk    = (const float*)d_in[6];
    const float* Wv    = (const float*)d_in[7];
    const float* bv    = (const float*)d_in[8];
    const float* Wo    = (const float*)d_in[9];
    const float* bo    = (const float*)d_in[10];

    char* ws = (char*)d_ws;
    unsigned short* WThi = (unsigned short*)(ws + 0);          // 512KB
    unsigned short* WTlo = (unsigned short*)(ws + 524288);     // 512KB
    unsigned short* Qhi  = (unsigned short*)(ws + 1048576);    // 4MB each below
    unsigned short* Qlo  = (unsigned short*)(ws + 5242880);
    unsigned short* Khi  = (unsigned short*)(ws + 9437184);
    unsigned short* Klo  = (unsigned short*)(ws + 13631488);
    unsigned short* Vtmp = (unsigned short*)(ws + 17825792);
    unsigned short* Vt   = (unsigned short*)(ws + 22020096);
    unsigned short* AOhi = (unsigned short*)(ws + 26214400);
    unsigned short* AOlo = (unsigned short*)(ws + 30408704);   // end = 34603008

    float* out = (float*)d_out;
    float* attn_mean = (float*)d_out + 2097152;

    wsplit_kernel<<<1024, 256, 0, stream>>>(Wq, Wk, Wv, Wo, WThi, WTlo);
    proj3_kernel<<<dim3(64, 3), 512, 0, stream>>>(query, kv, rel, WThi, WTlo,
                                                  bq, bk, bv, Qhi, Qlo, Khi, Klo, Vtmp);
    transpose_v_kernel<<<dim3(64, 8, 4), 256, 0, stream>>>(Vtmp, Vt);
    attn_kernel<<<256, 512, 0, stream>>>(Qhi, Qlo, Khi, Klo, Vt, rel,
                                         attn_mean, AOhi, AOlo);
    final_kernel<<<64, 512, 0, stream>>>(AOhi, AOlo, WThi + 3 * 65536, WTlo + 3 * 65536,
                                         bo, out);
}

// Round 6
// 161.522 us; speedup vs baseline: 2.5987x; 1.5781x over previous
//
#include <hip/hip_runtime.h>

// ---------------------------------------------------------------------------
// ReliabilityGatedCrossAttention — fp16 MFMA pipeline, gfx950.
//
// R6 (R5 post-mortem: kernel is LDS-PORT-throughput-bound; ~2000+cy of LDS
// traffic per kt vs ~600cy MFMA):
//   * fp16 single precision everywhere (11-bit mantissa ~ 5e-4 rel):
//     QK = 2 MFMA (was 6 hi/lo), K stage 16KB/kt (was 32), proj 1-MFMA core.
//   * attn: 4 waves x 32 q-rows (2 A-frags reuse each K/V fragment).
//   * pass 2 (attn_mean) split into its own kernel, k-sliced 4x, sinv via ws.
//   * V LDS layout conflict-free for 64B rows; staged with inverse-permuted
//     global source (linear gld_lds dest), XOR-swizzled reads.
// ---------------------------------------------------------------------------

typedef __attribute__((ext_vector_type(8))) _Float16 half8;
typedef __attribute__((ext_vector_type(4))) float f32x4;

#define MFMAH(A, B, C) __builtin_amdgcn_mfma_f32_16x16x32_f16((A), (B), (C), 0, 0, 0)

__device__ __forceinline__ unsigned short f2h(float f) {
    union { _Float16 h; unsigned short u; } c; c.h = (_Float16)f; return c.u;
}
__device__ __forceinline__ float h2f(unsigned short u) {
    union { unsigned short u; _Float16 h; } c; c.u = u; return (float)c.h;
}
__device__ __forceinline__ half8 ldh8(const unsigned short* p) {
    return *reinterpret_cast<const half8*>(p);
}
__device__ __forceinline__ void gld16(const unsigned short* g, unsigned short* l) {
    __builtin_amdgcn_global_load_lds(
        (const __attribute__((address_space(1))) unsigned int*)g,
        (__attribute__((address_space(3))) unsigned int*)l, 16, 0, 0);
}

// ---------------------------------------------------------------------------
// 1. Weights -> fp16, transposed [n][k]
// ---------------------------------------------------------------------------
__global__ void wsplit_kernel(const float* __restrict__ Wq, const float* __restrict__ Wk,
                              const float* __restrict__ Wv, const float* __restrict__ Wo,
                              unsigned short* __restrict__ WT) {
    int e = blockIdx.x * 256 + threadIdx.x;   // 0 .. 262143
    int m = e >> 16;
    int idx = e & 65535;
    int k = idx >> 8, n = idx & 255;
    const float* W = (m == 0) ? Wq : (m == 1) ? Wk : (m == 2) ? Wv : Wo;
    WT[m * 65536 + n * 256 + k] = f2h(W[idx]);   // W[k][n] -> WT[n][k]
}

// ---------------------------------------------------------------------------
// Weight-staged fp16 GEMM core (proj3 + final).  LDS tile [256 n][64 k],
// rows 128B = 8 granules, swizzle g ^= (row&7).
// ---------------------------------------------------------------------------
#define STAGE_W(dst_, src_, kt_) do {                                               \
    _Pragma("unroll")                                                               \
    for (int j_ = 0; j_ < 4; ++j_) {                                                \
        int s_ = w * 4 + j_;                                                        \
        int rowl_ = 8 * s_ + (l >> 3);                                              \
        int so_ = rowl_ * 256 + (kt_) * 64 + (((l & 7) ^ (rowl_ & 7)) << 3);        \
        gld16(&(src_)[so_], &(dst_)[s_ * 512]);                                     \
    }                                                                               \
} while (0)

#define GEMM_TILE(buf_, kt_) do {                                                   \
    _Pragma("unroll")                                                               \
    for (int ksl_ = 0; ksl_ < 2; ++ksl_) {                                          \
        _Pragma("unroll")                                                           \
        for (int n_ = 0; n_ < 16; ++n_) {                                           \
            int r_ = n_ * 16 + l15;                                                 \
            int idx_ = r_ * 64 + ((((ksl_)*4 + lg) ^ (r_ & 7)) << 3);               \
            half8 b_ = ldh8(&(buf_)[idx_]);                                         \
            acc[n_] = MFMAH(ah[(kt_) * 2 + ksl_], b_, acc[n_]);                     \
        }                                                                           \
    }                                                                               \
} while (0)

// ---------------------------------------------------------------------------
// 2. Projections (job 0:Q, 1:K, 2:V).  512 thr, 128 rows/block, grid (64,3).
// ---------------------------------------------------------------------------
__global__ __launch_bounds__(512, 1) void proj3_kernel(
    const float* __restrict__ query, const float* __restrict__ kv,
    const float* __restrict__ rel, const unsigned short* __restrict__ WT,
    const float* __restrict__ bq, const float* __restrict__ bk, const float* __restrict__ bv,
    unsigned short* __restrict__ Qh, unsigned short* __restrict__ Kh,
    unsigned short* __restrict__ Vtmp) {
    const int job = blockIdx.y;
    const float* X = (job == 0) ? query : kv;
    const unsigned short* wg = WT + job * 65536;
    const float* bias = (job == 0) ? bq : (job == 1) ? bk : bv;
    const float* rs = (job == 0) ? nullptr : rel;
    unsigned short* oh = (job == 0) ? Qh : (job == 1) ? Kh : Vtmp;

    __shared__ __align__(16) unsigned short wlds[2][256 * 64];   // 32KB x2

    const int w = threadIdx.x >> 6, l = threadIdx.x & 63;
    const int l15 = l & 15, lg = l >> 4;
    const int arow = blockIdx.x * 128 + w * 16 + l15;

    half8 ah[8];
#pragma unroll
    for (int ks = 0; ks < 8; ++ks) {
        const float* p = &X[arow * 256 + ks * 32 + lg * 8];
        float4 f0 = *reinterpret_cast<const float4*>(p);
        float4 f1 = *reinterpret_cast<const float4*>(p + 4);
        half8 t;
        t[0] = (_Float16)f0.x; t[1] = (_Float16)f0.y; t[2] = (_Float16)f0.z; t[3] = (_Float16)f0.w;
        t[4] = (_Float16)f1.x; t[5] = (_Float16)f1.y; t[6] = (_Float16)f1.z; t[7] = (_Float16)f1.w;
        ah[ks] = t;
    }
    f32x4 acc[16];
#pragma unroll
    for (int n = 0; n < 16; ++n) acc[n] = (f32x4){0.f, 0.f, 0.f, 0.f};

    STAGE_W(wlds[0], wg, 0);
    __syncthreads();
#pragma unroll
    for (int kt = 0; kt < 4; ++kt) {
        const int cur = kt & 1, nx = cur ^ 1;
        if (kt < 3) STAGE_W(wlds[nx], wg, kt + 1);
        GEMM_TILE(wlds[cur], kt);
        __syncthreads();
    }

    const int orow0 = blockIdx.x * 128 + w * 16 + lg * 4;
    float rsv[4];
#pragma unroll
    for (int r = 0; r < 4; ++r) rsv[r] = rs ? rs[orow0 + r] : 1.0f;
#pragma unroll
    for (int n = 0; n < 16; ++n) {
        const int col = n * 16 + l15;
        const float bn = bias[col];
#pragma unroll
        for (int r = 0; r < 4; ++r)
            oh[(orow0 + r) * 256 + col] = f2h((acc[n][r] + bn) * rsv[r]);
    }
}

// ---------------------------------------------------------------------------
// 3. Transpose V: [b][k][256] -> Vt [b][256 d][2048 k]  (fp16 bits)
// ---------------------------------------------------------------------------
__global__ void transpose_v_kernel(const unsigned short* __restrict__ Vtmp,
                                   unsigned short* __restrict__ Vt) {
    __shared__ unsigned short tile[32][36];
    const int b = blockIdx.z;
    const int k0 = blockIdx.x * 32, d0 = blockIdx.y * 32;
    const int t = threadIdx.x;
    {
        int kr = t >> 3, dc4 = (t & 7) * 4;
        ushort4 v = *reinterpret_cast<const ushort4*>(&Vtmp[(b * 2048 + k0 + kr) * 256 + d0 + dc4]);
        tile[kr][dc4 + 0] = v.x; tile[kr][dc4 + 1] = v.y;
        tile[kr][dc4 + 2] = v.z; tile[kr][dc4 + 3] = v.w;
    }
    __syncthreads();
    {
        int dr = t >> 3, kc4 = (t & 7) * 4;
        ushort4 o;
        o.x = tile[kc4 + 0][dr]; o.y = tile[kc4 + 1][dr];
        o.z = tile[kc4 + 2][dr]; o.w = tile[kc4 + 3][dr];
        *reinterpret_cast<ushort4*>(&Vt[(b * 256 + d0 + dr) * 2048 + k0 + kc4]) = o;
    }
}

// ---------------------------------------------------------------------------
// Shared staging macros for attention kernels.
// K tile [32 r][256 k] fp16, rows 512B, granule swizzle ^(r&7): 16 x 1KB slots.
// V tile [256 d][32 k] fp16, 16 x 1KB slots (16 d-rows each); phys granule
//   P = 8*(d&7) + 4*(d>>3) + (j ^ (d&3))  (conflict-free for the dc-read).
// ---------------------------------------------------------------------------
#define STAGE_K(dst_, kt_) do {                                                     \
    _Pragma("unroll")                                                               \
    for (int j_ = 0; j_ < 4; ++j_) {                                                \
        int s_ = w * 4 + j_;                                                        \
        int r_ = 2 * s_ + (l >> 5);                                                 \
        size_t so_ = (size_t)(kb + (kt_) * 32 + r_) * 256 +                         \
                     (((l & 31) ^ (r_ & 7)) << 3);                                  \
        gld16(&Kh[so_], &(dst_)[s_ * 512]);                                         \
    }                                                                               \
} while (0)

#define STAGE_V(dst_, kt_) do {                                                     \
    _Pragma("unroll")                                                               \
    for (int j_ = 0; j_ < 4; ++j_) {                                                \
        int s_ = w * 4 + j_;                                                        \
        int d_ = (l >> 3) + 8 * ((l >> 2) & 1);                                     \
        int jj_ = (l & 3) ^ ((l >> 3) & 3);                                         \
        size_t so_ = (size_t)(vb + s_ * 16 + d_) * 2048 + (kt_) * 32 + jj_ * 8;     \
        gld16(&Vt[so_], &(dst_)[s_ * 512]);                                         \
    }                                                                               \
} while (0)

// ---------------------------------------------------------------------------
// 4. Attention pass 1.  Grid 256 (XCD-swizzled), 256 thr = 4 waves = 4 heads,
//    32 q-rows (2 A-frags/wave).  Per kt: stage K+V(next), QK (2 MFMA/kc/qs),
//    ptilde = exp2(S*c)*r -> pbf fp16, rowsum, PV (V-frag shared by both qs).
//    Outputs: AO fp16 (rescaled), sinv f32 -> ws.
// ---------------------------------------------------------------------------
__global__ __launch_bounds__(256, 2) void attn_pass1(
    const unsigned short* __restrict__ Qh, const unsigned short* __restrict__ Kh,
    const unsigned short* __restrict__ Vt, const float* __restrict__ rel,
    float* __restrict__ sinv_ws, unsigned short* __restrict__ AO) {
    const int bid = blockIdx.x;                       // 0..255
    const int sw = (bid & 7) * 32 + (bid >> 3);       // XCD batch-locality
    const int b = sw >> 6;                            // batch 0..3
    const int q0 = (sw & 63) * 32;                    // 32-row q tile
    const int tid = threadIdx.x;
    const int w = tid >> 6;                           // wave = head
    const int h = w;
    const int l = tid & 63, l15 = l & 15, lg = l >> 4;
    const int kb = b * 2048, vb = b * 256;
    const float C2 = 0.18033688011112042f;            // 0.125 * log2(e)

    __shared__ __align__(16) unsigned short ldsK[2][8192];     // 16KB x2
    __shared__ __align__(16) unsigned short ldsV[2][8192];     // 16KB x2
    __shared__ __align__(16) unsigned short pbf[4][2][16][40]; // 10KB
    __shared__ __align__(16) unsigned short rel_h[2048];       // 4KB

    {   // stage clamped rel (fp16)
        float4 v0 = reinterpret_cast<const float4*>(&rel[b * 2048])[tid * 2];
        float4 v1 = reinterpret_cast<const float4*>(&rel[b * 2048])[tid * 2 + 1];
        ushort4 o0, o1;
        o0.x = f2h(fmaxf(v0.x, 1e-6f)); o0.y = f2h(fmaxf(v0.y, 1e-6f));
        o0.z = f2h(fmaxf(v0.z, 1e-6f)); o0.w = f2h(fmaxf(v0.w, 1e-6f));
        o1.x = f2h(fmaxf(v1.x, 1e-6f)); o1.y = f2h(fmaxf(v1.y, 1e-6f));
        o1.z = f2h(fmaxf(v1.z, 1e-6f)); o1.w = f2h(fmaxf(v1.w, 1e-6f));
        *reinterpret_cast<ushort4*>(&rel_h[tid * 8]) = o0;
        *reinterpret_cast<ushort4*>(&rel_h[tid * 8 + 4]) = o1;
    }

    // Q fragments: A-frag row = l15, k = kd*32 + lg*8 + j
    half8 qf00, qf01, qf10, qf11;   // [qs][kd]
    {
        const int o0 = (b * 2048 + q0 + l15) * 256 + h * 64 + lg * 8;
        const int o1 = (b * 2048 + q0 + 16 + l15) * 256 + h * 64 + lg * 8;
        qf00 = ldh8(&Qh[o0]); qf01 = ldh8(&Qh[o0 + 32]);
        qf10 = ldh8(&Qh[o1]); qf11 = ldh8(&Qh[o1 + 32]);
    }

    float ssum0[4] = {0.f, 0.f, 0.f, 0.f}, ssum1[4] = {0.f, 0.f, 0.f, 0.f};
    f32x4 oacc0[4], oacc1[4];
#pragma unroll
    for (int dc = 0; dc < 4; ++dc) {
        oacc0[dc] = (f32x4){0.f, 0.f, 0.f, 0.f};
        oacc1[dc] = (f32x4){0.f, 0.f, 0.f, 0.f};
    }

    STAGE_K(ldsK[0], 0); STAGE_V(ldsV[0], 0);
    __syncthreads();
    for (int kt = 0; kt < 64; ++kt) {
        const int cur = kt & 1, nx = cur ^ 1;
        if (kt < 63) { STAGE_K(ldsK[nx], kt + 1); STAGE_V(ldsV[nx], kt + 1); }
#pragma unroll
        for (int kc = 0; kc < 2; ++kc) {
            const int r = kc * 16 + l15;
            const int rx = r & 7;
            half8 k0 = ldh8(&ldsK[cur][r * 256 + (((h * 8 + lg) ^ rx) << 3)]);
            half8 k1 = ldh8(&ldsK[cur][r * 256 + (((h * 8 + 4 + lg) ^ rx) << 3)]);
            f32x4 a0 = (f32x4){0.f, 0.f, 0.f, 0.f}, a1 = a0;
            a0 = MFMAH(qf00, k0, a0); a0 = MFMAH(qf01, k1, a0);
            a1 = MFMAH(qf10, k0, a1); a1 = MFMAH(qf11, k1, a1);
            const float rc = h2f(rel_h[kt * 32 + r]);
#pragma unroll
            for (int r4 = 0; r4 < 4; ++r4) {
                float p0 = exp2f(a0[r4] * C2) * rc;
                float p1 = exp2f(a1[r4] * C2) * rc;
                ssum0[r4] += p0; ssum1[r4] += p1;
                pbf[h][0][lg * 4 + r4][kc * 16 + l15] = f2h(p0);
                pbf[h][1][lg * 4 + r4][kc * 16 + l15] = f2h(p1);
            }
        }
        {   // PV: V-frags shared by both qs (same-wave LDS RAW on pbf)
            half8 pa0 = ldh8(&pbf[h][0][l15][lg * 8]);
            half8 pa1 = ldh8(&pbf[h][1][l15][lg * 8]);
#pragma unroll
            for (int dc = 0; dc < 4; ++dc) {
                half8 vf = ldh8(&ldsV[cur][(h * 4 + dc) * 512 + 64 * (l15 & 7) +
                                           32 * (l15 >> 3) + 8 * (lg ^ (l15 & 3))]);
                oacc0[dc] = MFMAH(pa0, vf, oacc0[dc]);
                oacc1[dc] = MFMAH(pa1, vf, oacc1[dc]);
            }
        }
        __syncthreads();
    }

    // row sums -> sinv
    float si0[4], si1[4];
#pragma unroll
    for (int r4 = 0; r4 < 4; ++r4) {
        float v = ssum0[r4];
        v += __shfl_xor(v, 1); v += __shfl_xor(v, 2);
        v += __shfl_xor(v, 4); v += __shfl_xor(v, 8);
        si0[r4] = 1.0f / v;
        float u = ssum1[r4];
        u += __shfl_xor(u, 1); u += __shfl_xor(u, 2);
        u += __shfl_xor(u, 4); u += __shfl_xor(u, 8);
        si1[r4] = 1.0f / u;
    }
    if (l15 == 0) {
#pragma unroll
        for (int r4 = 0; r4 < 4; ++r4) {
            sinv_ws[(b * 4 + h) * 2048 + q0 + lg * 4 + r4] = si0[r4];
            sinv_ws[(b * 4 + h) * 2048 + q0 + 16 + lg * 4 + r4] = si1[r4];
        }
    }
    // AO (fp16, rescaled)
#pragma unroll
    for (int dc = 0; dc < 4; ++dc)
#pragma unroll
        for (int r4 = 0; r4 < 4; ++r4) {
            AO[(size_t)(b * 2048 + q0 + lg * 4 + r4) * 256 + h * 64 + dc * 16 + l15] =
                f2h(oacc0[dc][r4] * si0[r4]);
            AO[(size_t)(b * 2048 + q0 + 16 + lg * 4 + r4) * 256 + h * 64 + dc * 16 + l15] =
                f2h(oacc1[dc][r4] * si1[r4]);
        }
}

// ---------------------------------------------------------------------------
// 5. Attention pass 2: attn_mean.  Grid 1024 = (4 k-slices) x (4b x 64 q).
//    Per kt: QK again, p = ptilde * sinv (from ws), fp16 pstage (dbuf),
//    all 256 threads reduce 4 heads -> float4 writes.
// ---------------------------------------------------------------------------
__global__ __launch_bounds__(256, 2) void attn_mean_kernel(
    const unsigned short* __restrict__ Qh, const unsigned short* __restrict__ Kh,
    const float* __restrict__ rel, const float* __restrict__ sinv_ws,
    float* __restrict__ attn_mean) {
    const int kslice = blockIdx.x >> 8;
    const int inner = blockIdx.x & 255;
    const int sw = (inner & 7) * 32 + (inner >> 3);
    const int b = sw >> 6;
    const int q0 = (sw & 63) * 32;
    const int tid = threadIdx.x;
    const int w = tid >> 6;
    const int h = w;
    const int l = tid & 63, l15 = l & 15, lg = l >> 4;
    const int kb = b * 2048;
    const float C2 = 0.18033688011112042f;

    __shared__ __align__(16) unsigned short ldsK[2][8192];         // 16KB x2
    __shared__ __align__(16) unsigned short pbf2[2][4][2][16][40]; // 20KB
    __shared__ __align__(16) unsigned short rel_h[2048];           // 4KB

    {
        float4 v0 = reinterpret_cast<const float4*>(&rel[b * 2048])[tid * 2];
        float4 v1 = reinterpret_cast<const float4*>(&rel[b * 2048])[tid * 2 + 1];
        ushort4 o0, o1;
        o0.x = f2h(fmaxf(v0.x, 1e-6f)); o0.y = f2h(fmaxf(v0.y, 1e-6f));
        o0.z = f2h(fmaxf(v0.z, 1e-6f)); o0.w = f2h(fmaxf(v0.w, 1e-6f));
        o1.x = f2h(fmaxf(v1.x, 1e-6f)); o1.y = f2h(fmaxf(v1.y, 1e-6f));
        o1.z = f2h(fmaxf(v1.z, 1e-6f)); o1.w = f2h(fmaxf(v1.w, 1e-6f));
        *reinterpret_cast<ushort4*>(&rel_h[tid * 8]) = o0;
        *reinterpret_cast<ushort4*>(&rel_h[tid * 8 + 4]) = o1;
    }

    half8 qf00, qf01, qf10, qf11;
    {
        const int o0 = (b * 2048 + q0 + l15) * 256 + h * 64 + lg * 8;
        const int o1 = (b * 2048 + q0 + 16 + l15) * 256 + h * 64 + lg * 8;
        qf00 = ldh8(&Qh[o0]); qf01 = ldh8(&Qh[o0 + 32]);
        qf10 = ldh8(&Qh[o1]); qf11 = ldh8(&Qh[o1 + 32]);
    }
    float si0[4], si1[4];
#pragma unroll
    for (int r4 = 0; r4 < 4; ++r4) {
        si0[r4] = sinv_ws[(b * 4 + h) * 2048 + q0 + lg * 4 + r4];
        si1[r4] = sinv_ws[(b * 4 + h) * 2048 + q0 + 16 + lg * 4 + r4];
    }

    const int kt0 = kslice * 16;
    STAGE_K(ldsK[0], kt0);
    __syncthreads();
    for (int ki = 0; ki < 16; ++ki) {
        const int kt = kt0 + ki;
        const int cur = ki & 1, nx = cur ^ 1;
        if (ki < 15) STAGE_K(ldsK[nx], kt + 1);
#pragma unroll
        for (int kc = 0; kc < 2; ++kc) {
            const int r = kc * 16 + l15;
            const int rx = r & 7;
            half8 k0 = ldh8(&ldsK[cur][r * 256 + (((h * 8 + lg) ^ rx) << 3)]);
            half8 k1 = ldh8(&ldsK[cur][r * 256 + (((h * 8 + 4 + lg) ^ rx) << 3)]);
            f32x4 a0 = (f32x4){0.f, 0.f, 0.f, 0.f}, a1 = a0;
            a0 = MFMAH(qf00, k0, a0); a0 = MFMAH(qf01, k1, a0);
            a1 = MFMAH(qf10, k0, a1); a1 = MFMAH(qf11, k1, a1);
            const float rc = h2f(rel_h[kt * 32 + r]);
#pragma unroll
            for (int r4 = 0; r4 < 4; ++r4) {
                pbf2[cur][h][0][lg * 4 + r4][kc * 16 + l15] =
                    f2h(exp2f(a0[r4] * C2) * rc * si0[r4]);
                pbf2[cur][h][1][lg * 4 + r4][kc * 16 + l15] =
                    f2h(exp2f(a1[r4] * C2) * rc * si1[r4]);
            }
        }
        __syncthreads();
        {   // head-mean: 256 threads cover 2 qs x 16 rows x 8 col-chunks
            const int qs_ = tid >> 7, row = (tid >> 3) & 15, kq = tid & 7;
            float m0 = 0.f, m1 = 0.f, m2 = 0.f, m3 = 0.f;
#pragma unroll
            for (int hh = 0; hh < 4; ++hh) {
                ushort4 u = *reinterpret_cast<const ushort4*>(&pbf2[cur][hh][qs_][row][kq * 4]);
                m0 += h2f(u.x); m1 += h2f(u.y); m2 += h2f(u.z); m3 += h2f(u.w);
            }
            float4 o = (float4){m0 * 0.25f, m1 * 0.25f, m2 * 0.25f, m3 * 0.25f};
            *reinterpret_cast<float4*>(
                &attn_mean[(size_t)(b * 2048 + q0 + qs_ * 16 + row) * 2048 + kt * 32 + kq * 4]) = o;
        }
    }
}

// ---------------------------------------------------------------------------
// 6. out = AO @ Wo + bo  (fp16 single GEMM)
// ---------------------------------------------------------------------------
__global__ __launch_bounds__(512, 1) void final_kernel(
    const unsigned short* __restrict__ AO, const unsigned short* __restrict__ WoT,
    const float* __restrict__ bo, float* __restrict__ out) {
    __shared__ __align__(16) unsigned short wlds[2][256 * 64];

    const int w = threadIdx.x >> 6, l = threadIdx.x & 63;
    const int l15 = l & 15, lg = l >> 4;
    const int arow = blockIdx.x * 128 + w * 16 + l15;

    half8 ah[8];
#pragma unroll
    for (int ks = 0; ks < 8; ++ks)
        ah[ks] = ldh8(&AO[arow * 256 + ks * 32 + lg * 8]);
    f32x4 acc[16];
#pragma unroll
    for (int n = 0; n < 16; ++n) acc[n] = (f32x4){0.f, 0.f, 0.f, 0.f};

    STAGE_W(wlds[0], WoT, 0);
    __syncthreads();
#pragma unroll
    for (int kt = 0; kt < 4; ++kt) {
        const int cur = kt & 1, nx = cur ^ 1;
        if (kt < 3) STAGE_W(wlds[nx], WoT, kt + 1);
        GEMM_TILE(wlds[cur], kt);
        __syncthreads();
    }

    const int orow0 = blockIdx.x * 128 + w * 16 + lg * 4;
#pragma unroll
    for (int n = 0; n < 16; ++n) {
        const int col = n * 16 + l15;
        const float bn = bo[col];
#pragma unroll
        for (int r = 0; r < 4; ++r)
            out[(orow0 + r) * 256 + col] = acc[n][r] + bn;
    }
}

// ---------------------------------------------------------------------------
extern "C" void kernel_launch(void* const* d_in, const int* in_sizes, int n_in,
                              void* d_out, int out_size, void* d_ws, size_t ws_size,
                              hipStream_t stream) {
    const float* query = (const float*)d_in[0];
    const float* kv    = (const float*)d_in[1];
    const float* rel   = (const float*)d_in[2];
    const float* Wq    = (const float*)d_in[3];
    const float* bq    = (const float*)d_in[4];
    const float* Wk    = (const float*)d_in[5];
    const float* bk    = (const float*)d_in[6];
    const float* Wv    = (const float*)d_in[7];
    const float* bv    = (const float*)d_in[8];
    const float* Wo    = (const float*)d_in[9];
    const float* bo    = (const float*)d_in[10];

    char* ws = (char*)d_ws;
    unsigned short* WT   = (unsigned short*)(ws + 0);          // 512KB
    unsigned short* Qh   = (unsigned short*)(ws + 524288);     // 4MB
    unsigned short* Kh   = (unsigned short*)(ws + 4718592);    // 4MB
    unsigned short* Vtmp = (unsigned short*)(ws + 8912896);    // 4MB
    unsigned short* Vt   = (unsigned short*)(ws + 13107200);   // 4MB
    unsigned short* AO   = (unsigned short*)(ws + 17301504);   // 4MB
    float*          sinv = (float*)(ws + 21495808);            // 128KB -> end 21.6MB

    float* out = (float*)d_out;
    float* attn_mean = (float*)d_out + 2097152;

    wsplit_kernel<<<1024, 256, 0, stream>>>(Wq, Wk, Wv, Wo, WT);
    proj3_kernel<<<dim3(64, 3), 512, 0, stream>>>(query, kv, rel, WT,
                                                  bq, bk, bv, Qh, Kh, Vtmp);
    transpose_v_kernel<<<dim3(64, 8, 4), 256, 0, stream>>>(Vtmp, Vt);
    attn_pass1<<<256, 256, 0, stream>>>(Qh, Kh, Vt, rel, sinv, AO);
    attn_mean_kernel<<<1024, 256, 0, stream>>>(Qh, Kh, rel, sinv, attn_mean);
    final_kernel<<<64, 512, 0, stream>>>(AO, WT + 3 * 65536, bo, out);
}

// Round 7
// 129.288 us; speedup vs baseline: 3.2466x; 1.2493x over previous
//
#include <hip/hip_runtime.h>

// ---------------------------------------------------------------------------
// ReliabilityGatedCrossAttention — fp16 MFMA pipeline, gfx950.  R7.
//
// R6 post-mortem: attn_pass1 at 1 wave/SIMD (grid 256, 1 block/CU) with a
// barrier (implicit vmcnt(0) drain) every kt -> 3150cy/kt vs ~1100cy work.
// R7:
//   * attn_pass1: 8 waves = (head x k-half), PER-WAVE private K/V staging
//     (global_load_lds into own dbuf), NO barriers in loop, counted
//     s_waitcnt vmcnt(8) (T4: never drain to 0).  k-half combine at end.
//   * swapped QK (mfma(K,Q)): S^T gives per-lane k-consecutive values ->
//     p-store = 1 ds_write_b64 per kc/qs (was 8 b16), rc per-reg broadcast,
//     rowsum = in-reg + 2 shuffles.  Applied to attn_mean too.
// ---------------------------------------------------------------------------

typedef __attribute__((ext_vector_type(8))) _Float16 half8;
typedef __attribute__((ext_vector_type(4))) float f32x4;

#define MFMAH(A, B, C) __builtin_amdgcn_mfma_f32_16x16x32_f16((A), (B), (C), 0, 0, 0)

__device__ __forceinline__ unsigned short f2h(float f) {
    union { _Float16 h; unsigned short u; } c; c.h = (_Float16)f; return c.u;
}
__device__ __forceinline__ float h2f(unsigned short u) {
    union { unsigned short u; _Float16 h; } c; c.u = u; return (float)c.h;
}
__device__ __forceinline__ half8 ldh8(const unsigned short* p) {
    return *reinterpret_cast<const half8*>(p);
}
__device__ __forceinline__ void gld16(const unsigned short* g, unsigned short* l) {
    __builtin_amdgcn_global_load_lds(
        (const __attribute__((address_space(1))) unsigned int*)g,
        (__attribute__((address_space(3))) unsigned int*)l, 16, 0, 0);
}

// ---------------------------------------------------------------------------
// 1. Weights -> fp16, transposed [n][k]
// ---------------------------------------------------------------------------
__global__ void wsplit_kernel(const float* __restrict__ Wq, const float* __restrict__ Wk,
                              const float* __restrict__ Wv, const float* __restrict__ Wo,
                              unsigned short* __restrict__ WT) {
    int e = blockIdx.x * 256 + threadIdx.x;   // 0 .. 262143
    int m = e >> 16;
    int idx = e & 65535;
    int k = idx >> 8, n = idx & 255;
    const float* W = (m == 0) ? Wq : (m == 1) ? Wk : (m == 2) ? Wv : Wo;
    WT[m * 65536 + n * 256 + k] = f2h(W[idx]);   // W[k][n] -> WT[n][k]
}

// ---------------------------------------------------------------------------
// Weight-staged fp16 GEMM core (proj3 + final).  LDS tile [256 n][64 k],
// rows 128B = 8 granules, swizzle g ^= (row&7).
// ---------------------------------------------------------------------------
#define STAGE_W(dst_, src_, kt_) do {                                               \
    _Pragma("unroll")                                                               \
    for (int j_ = 0; j_ < 4; ++j_) {                                                \
        int s_ = w * 4 + j_;                                                        \
        int rowl_ = 8 * s_ + (l >> 3);                                              \
        int so_ = rowl_ * 256 + (kt_) * 64 + (((l & 7) ^ (rowl_ & 7)) << 3);        \
        gld16(&(src_)[so_], &(dst_)[s_ * 512]);                                     \
    }                                                                               \
} while (0)

#define GEMM_TILE(buf_, kt_) do {                                                   \
    _Pragma("unroll")                                                               \
    for (int ksl_ = 0; ksl_ < 2; ++ksl_) {                                          \
        _Pragma("unroll")                                                           \
        for (int n_ = 0; n_ < 16; ++n_) {                                           \
            int r_ = n_ * 16 + l15;                                                 \
            int idx_ = r_ * 64 + ((((ksl_)*4 + lg) ^ (r_ & 7)) << 3);               \
            half8 b_ = ldh8(&(buf_)[idx_]);                                         \
            acc[n_] = MFMAH(ah[(kt_) * 2 + ksl_], b_, acc[n_]);                     \
        }                                                                           \
    }                                                                               \
} while (0)

// ---------------------------------------------------------------------------
// 2. Projections (job 0:Q, 1:K, 2:V).  512 thr, 128 rows/block, grid (64,3).
// ---------------------------------------------------------------------------
__global__ __launch_bounds__(512, 1) void proj3_kernel(
    const float* __restrict__ query, const float* __restrict__ kv,
    const float* __restrict__ rel, const unsigned short* __restrict__ WT,
    const float* __restrict__ bq, const float* __restrict__ bk, const float* __restrict__ bv,
    unsigned short* __restrict__ Qh, unsigned short* __restrict__ Kh,
    unsigned short* __restrict__ Vtmp) {
    const int job = blockIdx.y;
    const float* X = (job == 0) ? query : kv;
    const unsigned short* wg = WT + job * 65536;
    const float* bias = (job == 0) ? bq : (job == 1) ? bk : bv;
    const float* rs = (job == 0) ? nullptr : rel;
    unsigned short* oh = (job == 0) ? Qh : (job == 1) ? Kh : Vtmp;

    __shared__ __align__(16) unsigned short wlds[2][256 * 64];   // 32KB x2

    const int w = threadIdx.x >> 6, l = threadIdx.x & 63;
    const int l15 = l & 15, lg = l >> 4;
    const int arow = blockIdx.x * 128 + w * 16 + l15;

    half8 ah[8];
#pragma unroll
    for (int ks = 0; ks < 8; ++ks) {
        const float* p = &X[arow * 256 + ks * 32 + lg * 8];
        float4 f0 = *reinterpret_cast<const float4*>(p);
        float4 f1 = *reinterpret_cast<const float4*>(p + 4);
        half8 t;
        t[0] = (_Float16)f0.x; t[1] = (_Float16)f0.y; t[2] = (_Float16)f0.z; t[3] = (_Float16)f0.w;
        t[4] = (_Float16)f1.x; t[5] = (_Float16)f1.y; t[6] = (_Float16)f1.z; t[7] = (_Float16)f1.w;
        ah[ks] = t;
    }
    f32x4 acc[16];
#pragma unroll
    for (int n = 0; n < 16; ++n) acc[n] = (f32x4){0.f, 0.f, 0.f, 0.f};

    STAGE_W(wlds[0], wg, 0);
    __syncthreads();
#pragma unroll
    for (int kt = 0; kt < 4; ++kt) {
        const int cur = kt & 1, nx = cur ^ 1;
        if (kt < 3) STAGE_W(wlds[nx], wg, kt + 1);
        GEMM_TILE(wlds[cur], kt);
        __syncthreads();
    }

    const int orow0 = blockIdx.x * 128 + w * 16 + lg * 4;
    float rsv[4];
#pragma unroll
    for (int r = 0; r < 4; ++r) rsv[r] = rs ? rs[orow0 + r] : 1.0f;
#pragma unroll
    for (int n = 0; n < 16; ++n) {
        const int col = n * 16 + l15;
        const float bn = bias[col];
#pragma unroll
        for (int r = 0; r < 4; ++r)
            oh[(orow0 + r) * 256 + col] = f2h((acc[n][r] + bn) * rsv[r]);
    }
}

// ---------------------------------------------------------------------------
// 3. Transpose V: [b][k][256] -> Vt [b][256 d][2048 k]  (fp16 bits)
// ---------------------------------------------------------------------------
__global__ void transpose_v_kernel(const unsigned short* __restrict__ Vtmp,
                                   unsigned short* __restrict__ Vt) {
    __shared__ unsigned short tile[32][36];
    const int b = blockIdx.z;
    const int k0 = blockIdx.x * 32, d0 = blockIdx.y * 32;
    const int t = threadIdx.x;
    {
        int kr = t >> 3, dc4 = (t & 7) * 4;
        ushort4 v = *reinterpret_cast<const ushort4*>(&Vtmp[(b * 2048 + k0 + kr) * 256 + d0 + dc4]);
        tile[kr][dc4 + 0] = v.x; tile[kr][dc4 + 1] = v.y;
        tile[kr][dc4 + 2] = v.z; tile[kr][dc4 + 3] = v.w;
    }
    __syncthreads();
    {
        int dr = t >> 3, kc4 = (t & 7) * 4;
        ushort4 o;
        o.x = tile[kc4 + 0][dr]; o.y = tile[kc4 + 1][dr];
        o.z = tile[kc4 + 2][dr]; o.w = tile[kc4 + 3][dr];
        *reinterpret_cast<ushort4*>(&Vt[(b * 256 + d0 + dr) * 2048 + k0 + kc4]) = o;
    }
}

// ---------------------------------------------------------------------------
// 4. Attention pass 1, R7.  Grid 256 (XCD-swizzled), 512 thr = 8 waves =
//    (k-half ks = w>>2) x (head h = w&3); 32 q-rows/block (2 qs frags/wave).
//    Per-wave PRIVATE double-buffered staging (K-quarter 4KB + V-quarter 4KB
//    per kt), counted vmcnt(8), NO loop barriers.  Swapped QK: S^T in regs.
//    End: k-half combine of oacc (via ldsV[4..7] reuse) + ssum -> AO, sinv.
// ---------------------------------------------------------------------------
__global__ __launch_bounds__(512, 1) void attn_pass1(
    const unsigned short* __restrict__ Qh, const unsigned short* __restrict__ Kh,
    const unsigned short* __restrict__ Vt, const float* __restrict__ rel,
    float* __restrict__ sinv_ws, unsigned short* __restrict__ AO) {
    const int bid = blockIdx.x;                       // 0..255
    const int sw = (bid & 7) * 32 + (bid >> 3);       // XCD batch-locality
    const int b = sw >> 6;                            // batch 0..3
    const int q0 = (sw & 63) * 32;                    // 32-row q tile
    const int tid = threadIdx.x;
    const int w = tid >> 6;                           // 0..7
    const int h = w & 3, ks = w >> 2;
    const int l = tid & 63, l15 = l & 15, lg = l >> 4;
    const float C2 = 0.18033688011112042f;            // 0.125 * log2(e)

    __shared__ __align__(16) unsigned short ldsK[8][2][2048];   // 64KB (4KB/wave/buf)
    __shared__ __align__(16) unsigned short ldsV[8][2][2048];   // 64KB
    __shared__ __align__(16) unsigned short pbf[8][2][640];     // 20KB ([16 q][40 k])
    __shared__ __align__(16) unsigned short rel_h[2048];        // 4KB
    __shared__ float ssum_sh[2][4][2][16];                      // 1KB

    {   // stage clamped rel (fp16): 512 thr x 4
        float4 v = reinterpret_cast<const float4*>(&rel[b * 2048])[tid];
        ushort4 o;
        o.x = f2h(fmaxf(v.x, 1e-6f)); o.y = f2h(fmaxf(v.y, 1e-6f));
        o.z = f2h(fmaxf(v.z, 1e-6f)); o.w = f2h(fmaxf(v.w, 1e-6f));
        *reinterpret_cast<ushort4*>(&rel_h[tid * 4]) = o;
    }

    // Q fragments (as MFMA B-operand: col=q=l15, d = kd*32 + lg*8 + j)
    half8 qf00, qf01, qf10, qf11;   // [qs][kd]
    {
        const int o0 = (b * 2048 + q0 + l15) * 256 + h * 64 + lg * 8;
        const int o1 = (b * 2048 + q0 + 16 + l15) * 256 + h * 64 + lg * 8;
        qf00 = ldh8(&Qh[o0]); qf01 = ldh8(&Qh[o0 + 32]);
        qf10 = ldh8(&Qh[o1]); qf11 = ldh8(&Qh[o1 + 32]);
    }
    __syncthreads();   // rel_h ready (only barrier before epilogue)

    // per-wave staging: K quarter [32 r][64 d] (granule ^= r&7),
    //                   V quarter [64 d][32 k] (granule ^= (d>>1)&3)
#define STAGE1(buf_, kt_) do {                                                      \
    _Pragma("unroll")                                                               \
    for (int j_ = 0; j_ < 4; ++j_) {                                                \
        int r_ = 8 * j_ + (l >> 3);                                                 \
        size_t sk_ = (size_t)(b * 2048 + (kt_) * 32 + r_) * 256 + h * 64 +          \
                     (((l & 7) ^ (l >> 3)) << 3);                                   \
        gld16(&Kh[sk_], &ldsK[w][buf_][j_ * 512]);                                  \
    }                                                                               \
    _Pragma("unroll")                                                               \
    for (int j_ = 0; j_ < 4; ++j_) {                                                \
        int d_ = 16 * j_ + (l >> 2);                                                \
        size_t sv_ = (size_t)(b * 256 + h * 64 + d_) * 2048 + (kt_) * 32 +          \
                     (((l & 3) ^ ((l >> 3) & 3)) << 3);                             \
        gld16(&Vt[sv_], &ldsV[w][buf_][j_ * 512]);                                  \
    }                                                                               \
} while (0)

    float ssum0 = 0.f, ssum1 = 0.f;
    f32x4 oacc0[4], oacc1[4];
#pragma unroll
    for (int dc = 0; dc < 4; ++dc) {
        oacc0[dc] = (f32x4){0.f, 0.f, 0.f, 0.f};
        oacc1[dc] = (f32x4){0.f, 0.f, 0.f, 0.f};
    }

    const int ktb = ks * 32;
    STAGE1(0, ktb);
    for (int i = 0; i < 32; ++i) {
        const int cur = i & 1, nx = cur ^ 1;
        if (i < 31) {
            STAGE1(nx, ktb + i + 1);
            asm volatile("s_waitcnt vmcnt(8)" ::: "memory");
        } else {
            asm volatile("s_waitcnt vmcnt(0)" ::: "memory");
        }
        __builtin_amdgcn_sched_barrier(0);
        const int kt = ktb + i;
#pragma unroll
        for (int kc = 0; kc < 2; ++kc) {
            const int r = kc * 16 + l15;
            const int rx = l15 & 7;
            half8 kf0 = ldh8(&ldsK[w][cur][r * 64 + ((lg ^ rx) << 3)]);
            half8 kf1 = ldh8(&ldsK[w][cur][r * 64 + (((4 + lg) ^ rx) << 3)]);
            // swapped: D = S^T [k][q]: col=l15=q, row=lg*4+r4 = k (within kc)
            f32x4 a0 = (f32x4){0.f, 0.f, 0.f, 0.f}, a1 = a0;
            a0 = MFMAH(kf0, qf00, a0); a0 = MFMAH(kf1, qf01, a0);
            a1 = MFMAH(kf0, qf10, a1); a1 = MFMAH(kf1, qf11, a1);
            float p00, p01, p02, p03, p10, p11, p12, p13;
            {
                const int kb0 = kt * 32 + kc * 16 + lg * 4;
                float rc0 = h2f(rel_h[kb0]),     rc1 = h2f(rel_h[kb0 + 1]);
                float rc2 = h2f(rel_h[kb0 + 2]), rc3 = h2f(rel_h[kb0 + 3]);
                p00 = exp2f(a0[0] * C2) * rc0; p01 = exp2f(a0[1] * C2) * rc1;
                p02 = exp2f(a0[2] * C2) * rc2; p03 = exp2f(a0[3] * C2) * rc3;
                p10 = exp2f(a1[0] * C2) * rc0; p11 = exp2f(a1[1] * C2) * rc1;
                p12 = exp2f(a1[2] * C2) * rc2; p13 = exp2f(a1[3] * C2) * rc3;
            }
            ssum0 += (p00 + p01) + (p02 + p03);
            ssum1 += (p10 + p11) + (p12 + p13);
            uint2 w0, w1;
            w0.x = (unsigned)f2h(p00) | ((unsigned)f2h(p01) << 16);
            w0.y = (unsigned)f2h(p02) | ((unsigned)f2h(p03) << 16);
            w1.x = (unsigned)f2h(p10) | ((unsigned)f2h(p11) << 16);
            w1.y = (unsigned)f2h(p12) | ((unsigned)f2h(p13) << 16);
            *reinterpret_cast<uint2*>(&pbf[w][0][l15 * 40 + kc * 16 + lg * 4]) = w0;
            *reinterpret_cast<uint2*>(&pbf[w][1][l15 * 40 + kc * 16 + lg * 4]) = w1;
        }
        {   // PV: P as A-frag (row=q=l15, k=lg*8+j); V-frags shared by both qs
            half8 pa0 = ldh8(&pbf[w][0][l15 * 40 + lg * 8]);
            half8 pa1 = ldh8(&pbf[w][1][l15 * 40 + lg * 8]);
#pragma unroll
            for (int dc = 0; dc < 4; ++dc) {
                const int d = dc * 16 + l15;
                half8 vf = ldh8(&ldsV[w][cur][d * 32 + ((lg ^ ((l15 >> 1) & 3)) << 3)]);
                oacc0[dc] = MFMAH(pa0, vf, oacc0[dc]);
                oacc1[dc] = MFMAH(pa1, vf, oacc1[dc]);
            }
        }
    }
#undef STAGE1

    // ssum: in-reg k rows done; reduce across lg groups (k) only
    {
        float v0 = ssum0, v1 = ssum1;
        v0 += __shfl_xor(v0, 16); v0 += __shfl_xor(v0, 32);
        v1 += __shfl_xor(v1, 16); v1 += __shfl_xor(v1, 32);
        if (lg == 0) {
            ssum_sh[ks][h][0][l15] = v0;
            ssum_sh[ks][h][1][l15] = v1;
        }
    }
    // k-half combine buffer: reuse ldsV[4..7] (32KB), written only by ks=1
    float* ob = (float*)&ldsV[4][0][0];
    if (ks == 1) {
        const int base = (h * 64 + l) * 32;
#pragma unroll
        for (int dc = 0; dc < 4; ++dc)
#pragma unroll
            for (int r4 = 0; r4 < 4; ++r4) {
                int i0 = dc * 4 + r4, i1 = 16 + dc * 4 + r4;
                ob[base + ((i0 + l) & 31)] = oacc0[dc][r4];
                ob[base + ((i1 + l) & 31)] = oacc1[dc][r4];
            }
    }
    __syncthreads();
    if (ks == 0) {
        const int base = (h * 64 + l) * 32;
        float siv0[4], siv1[4];
#pragma unroll
        for (int r4 = 0; r4 < 4; ++r4) {
            int q = lg * 4 + r4;
            siv0[r4] = 1.0f / (ssum_sh[0][h][0][q] + ssum_sh[1][h][0][q]);
            siv1[r4] = 1.0f / (ssum_sh[0][h][1][q] + ssum_sh[1][h][1][q]);
        }
#pragma unroll
        for (int dc = 0; dc < 4; ++dc)
#pragma unroll
            for (int r4 = 0; r4 < 4; ++r4) {
                int i0 = dc * 4 + r4, i1 = 16 + dc * 4 + r4;
                float t0 = (oacc0[dc][r4] + ob[base + ((i0 + l) & 31)]) * siv0[r4];
                float t1 = (oacc1[dc][r4] + ob[base + ((i1 + l) & 31)]) * siv1[r4];
                AO[(size_t)(b * 2048 + q0 + lg * 4 + r4) * 256 + h * 64 + dc * 16 + l15] = f2h(t0);
                AO[(size_t)(b * 2048 + q0 + 16 + lg * 4 + r4) * 256 + h * 64 + dc * 16 + l15] = f2h(t1);
            }
        if (l15 == 0) {
#pragma unroll
            for (int r4 = 0; r4 < 4; ++r4) {
                sinv_ws[(b * 4 + h) * 2048 + q0 + lg * 4 + r4] = siv0[r4];
                sinv_ws[(b * 4 + h) * 2048 + q0 + 16 + lg * 4 + r4] = siv1[r4];
            }
        }
    }
}

// ---------------------------------------------------------------------------
// 5. Attention pass 2: attn_mean.  Grid 1024 = (4 k-slices) x (4b x 64 q).
//    Cooperative K stage (4 waves share full tile) + barriers; swapped QK,
//    packed b64 p-writes, per-lane sinv (q = l15).
// ---------------------------------------------------------------------------
__global__ __launch_bounds__(256, 2) void attn_mean_kernel(
    const unsigned short* __restrict__ Qh, const unsigned short* __restrict__ Kh,
    const float* __restrict__ rel, const float* __restrict__ sinv_ws,
    float* __restrict__ attn_mean) {
    const int kslice = blockIdx.x >> 8;
    const int inner = blockIdx.x & 255;
    const int sw = (inner & 7) * 32 + (inner >> 3);
    const int b = sw >> 6;
    const int q0 = (sw & 63) * 32;
    const int tid = threadIdx.x;
    const int w = tid >> 6;
    const int h = w;
    const int l = tid & 63, l15 = l & 15, lg = l >> 4;
    const int kb = b * 2048;
    const float C2 = 0.18033688011112042f;

    __shared__ __align__(16) unsigned short ldsK[2][8192];      // 16KB x2
    __shared__ __align__(16) unsigned short pbf2[2][4][2][640]; // 20KB
    __shared__ __align__(16) unsigned short rel_h[2048];        // 4KB

#define STAGE_KM(dst_, kt_) do {                                                    \
    _Pragma("unroll")                                                               \
    for (int j_ = 0; j_ < 4; ++j_) {                                                \
        int s_ = w * 4 + j_;                                                        \
        int r_ = 2 * s_ + (l >> 5);                                                 \
        size_t so_ = (size_t)(kb + (kt_) * 32 + r_) * 256 +                         \
                     (((l & 31) ^ (r_ & 7)) << 3);                                  \
        gld16(&Kh[so_], &(dst_)[s_ * 512]);                                         \
    }                                                                               \
} while (0)

    {
        float4 v0 = reinterpret_cast<const float4*>(&rel[b * 2048])[tid * 2];
        float4 v1 = reinterpret_cast<const float4*>(&rel[b * 2048])[tid * 2 + 1];
        ushort4 o0, o1;
        o0.x = f2h(fmaxf(v0.x, 1e-6f)); o0.y = f2h(fmaxf(v0.y, 1e-6f));
        o0.z = f2h(fmaxf(v0.z, 1e-6f)); o0.w = f2h(fmaxf(v0.w, 1e-6f));
        o1.x = f2h(fmaxf(v1.x, 1e-6f)); o1.y = f2h(fmaxf(v1.y, 1e-6f));
        o1.z = f2h(fmaxf(v1.z, 1e-6f)); o1.w = f2h(fmaxf(v1.w, 1e-6f));
        *reinterpret_cast<ushort4*>(&rel_h[tid * 8]) = o0;
        *reinterpret_cast<ushort4*>(&rel_h[tid * 8 + 4]) = o1;
    }

    half8 qf00, qf01, qf10, qf11;
    {
        const int o0 = (b * 2048 + q0 + l15) * 256 + h * 64 + lg * 8;
        const int o1 = (b * 2048 + q0 + 16 + l15) * 256 + h * 64 + lg * 8;
        qf00 = ldh8(&Qh[o0]); qf01 = ldh8(&Qh[o0 + 32]);
        qf10 = ldh8(&Qh[o1]); qf11 = ldh8(&Qh[o1 + 32]);
    }
    // per-lane sinv: q = l15
    const float si0 = sinv_ws[(b * 4 + h) * 2048 + q0 + l15];
    const float si1 = sinv_ws[(b * 4 + h) * 2048 + q0 + 16 + l15];

    const int kt0 = kslice * 16;
    STAGE_KM(ldsK[0], kt0);
    __syncthreads();
    for (int ki = 0; ki < 16; ++ki) {
        const int kt = kt0 + ki;
        const int cur = ki & 1, nx = cur ^ 1;
        if (ki < 15) STAGE_KM(ldsK[nx], kt + 1);
#pragma unroll
        for (int kc = 0; kc < 2; ++kc) {
            const int r = kc * 16 + l15;
            const int rx = r & 7;
            half8 kf0 = ldh8(&ldsK[cur][r * 256 + (((h * 8 + lg) ^ rx) << 3)]);
            half8 kf1 = ldh8(&ldsK[cur][r * 256 + (((h * 8 + 4 + lg) ^ rx) << 3)]);
            f32x4 a0 = (f32x4){0.f, 0.f, 0.f, 0.f}, a1 = a0;
            a0 = MFMAH(kf0, qf00, a0); a0 = MFMAH(kf1, qf01, a0);
            a1 = MFMAH(kf0, qf10, a1); a1 = MFMAH(kf1, qf11, a1);
            const int kb0 = kt * 32 + kc * 16 + lg * 4;
            float rc0 = h2f(rel_h[kb0]),     rc1 = h2f(rel_h[kb0 + 1]);
            float rc2 = h2f(rel_h[kb0 + 2]), rc3 = h2f(rel_h[kb0 + 3]);
            uint2 w0, w1;
            w0.x = (unsigned)f2h(exp2f(a0[0] * C2) * rc0 * si0) |
                   ((unsigned)f2h(exp2f(a0[1] * C2) * rc1 * si0) << 16);
            w0.y = (unsigned)f2h(exp2f(a0[2] * C2) * rc2 * si0) |
                   ((unsigned)f2h(exp2f(a0[3] * C2) * rc3 * si0) << 16);
            w1.x = (unsigned)f2h(exp2f(a1[0] * C2) * rc0 * si1) |
                   ((unsigned)f2h(exp2f(a1[1] * C2) * rc1 * si1) << 16);
            w1.y = (unsigned)f2h(exp2f(a1[2] * C2) * rc2 * si1) |
                   ((unsigned)f2h(exp2f(a1[3] * C2) * rc3 * si1) << 16);
            *reinterpret_cast<uint2*>(&pbf2[cur][h][0][l15 * 40 + kc * 16 + lg * 4]) = w0;
            *reinterpret_cast<uint2*>(&pbf2[cur][h][1][l15 * 40 + kc * 16 + lg * 4]) = w1;
        }
        __syncthreads();
        {   // head-mean: 256 threads cover 2 qs x 16 rows x 8 col-chunks
            const int qs_ = tid >> 7, row = (tid >> 3) & 15, kq = tid & 7;
            float m0 = 0.f, m1 = 0.f, m2 = 0.f, m3 = 0.f;
#pragma unroll
            for (int hh = 0; hh < 4; ++hh) {
                ushort4 u = *reinterpret_cast<const ushort4*>(&pbf2[cur][hh][qs_][row * 40 + kq * 4]);
                m0 += h2f(u.x); m1 += h2f(u.y); m2 += h2f(u.z); m3 += h2f(u.w);
            }
            float4 o = (float4){m0 * 0.25f, m1 * 0.25f, m2 * 0.25f, m3 * 0.25f};
            *reinterpret_cast<float4*>(
                &attn_mean[(size_t)(b * 2048 + q0 + qs_ * 16 + row) * 2048 + kt * 32 + kq * 4]) = o;
        }
    }
#undef STAGE_KM
}

// ---------------------------------------------------------------------------
// 6. out = AO @ Wo + bo  (fp16 single GEMM)
// ---------------------------------------------------------------------------
__global__ __launch_bounds__(512, 1) void final_kernel(
    const unsigned short* __restrict__ AO, const unsigned short* __restrict__ WoT,
    const float* __restrict__ bo, float* __restrict__ out) {
    __shared__ __align__(16) unsigned short wlds[2][256 * 64];

    const int w = threadIdx.x >> 6, l = threadIdx.x & 63;
    const int l15 = l & 15, lg = l >> 4;
    const int arow = blockIdx.x * 128 + w * 16 + l15;

    half8 ah[8];
#pragma unroll
    for (int ks = 0; ks < 8; ++ks)
        ah[ks] = ldh8(&AO[arow * 256 + ks * 32 + lg * 8]);
    f32x4 acc[16];
#pragma unroll
    for (int n = 0; n < 16; ++n) acc[n] = (f32x4){0.f, 0.f, 0.f, 0.f};

    STAGE_W(wlds[0], WoT, 0);
    __syncthreads();
#pragma unroll
    for (int kt = 0; kt < 4; ++kt) {
        const int cur = kt & 1, nx = cur ^ 1;
        if (kt < 3) STAGE_W(wlds[nx], WoT, kt + 1);
        GEMM_TILE(wlds[cur], kt);
        __syncthreads();
    }

    const int orow0 = blockIdx.x * 128 + w * 16 + lg * 4;
#pragma unroll
    for (int n = 0; n < 16; ++n) {
        const int col = n * 16 + l15;
        const float bn = bo[col];
#pragma unroll
        for (int r = 0; r < 4; ++r)
            out[(orow0 + r) * 256 + col] = acc[n][r] + bn;
    }
}

// ---------------------------------------------------------------------------
extern "C" void kernel_launch(void* const* d_in, const int* in_sizes, int n_in,
                              void* d_out, int out_size, void* d_ws, size_t ws_size,
                              hipStream_t stream) {
    const float* query = (const float*)d_in[0];
    const float* kv    = (const float*)d_in[1];
    const float* rel   = (const float*)d_in[2];
    const float* Wq    = (const float*)d_in[3];
    const float* bq    = (const float*)d_in[4];
    const float* Wk    = (const float*)d_in[5];
    const float* bk    = (const float*)d_in[6];
    const float* Wv    = (const float*)d_in[7];
    const float* bv    = (const float*)d_in[8];
    const float* Wo    = (const float*)d_in[9];
    const float* bo    = (const float*)d_in[10];

    char* ws = (char*)d_ws;
    unsigned short* WT   = (unsigned short*)(ws + 0);          // 512KB
    unsigned short* Qh   = (unsigned short*)(ws + 524288);     // 4MB
    unsigned short* Kh   = (unsigned short*)(ws + 4718592);    // 4MB
    unsigned short* Vtmp = (unsigned short*)(ws + 8912896);    // 4MB
    unsigned short* Vt   = (unsigned short*)(ws + 13107200);   // 4MB
    unsigned short* AO   = (unsigned short*)(ws + 17301504);   // 4MB
    float*          sinv = (float*)(ws + 21495808);            // 128KB -> end 21.6MB

    float* out = (float*)d_out;
    float* attn_mean = (float*)d_out + 2097152;

    wsplit_kernel<<<1024, 256, 0, stream>>>(Wq, Wk, Wv, Wo, WT);
    proj3_kernel<<<dim3(64, 3), 512, 0, stream>>>(query, kv, rel, WT,
                                                  bq, bk, bv, Qh, Kh, Vtmp);
    transpose_v_kernel<<<dim3(64, 8, 4), 256, 0, stream>>>(Vtmp, Vt);
    attn_pass1<<<256, 512, 0, stream>>>(Qh, Kh, Vt, rel, sinv, AO);
    attn_mean_kernel<<<1024, 256, 0, stream>>>(Qh, Kh, rel, sinv, attn_mean);
    final_kernel<<<64, 512, 0, stream>>>(AO, WT + 3 * 65536, bo, out);
}

// Round 9
// 123.077 us; speedup vs baseline: 3.4105x; 1.0505x over previous
//
#include <hip/hip_runtime.h>

// ---------------------------------------------------------------------------
// ReliabilityGatedCrossAttention — fp16 MFMA pipeline, gfx950.  R9 (= R8 +
// cvt_pkrtz type fix: builtin returns __fp16 ext_vector(2), not _Float16).
//
//   * swapped-QK S^T register layout == mfma_f32_16x16x16f16 A-frag layout
//     -> P goes exp -> cvt_pkrtz -> PV A-operand IN-LANE (no P LDS at all).
//   * 16-k-row steps halve K/V buffers; k-halves split ACROSS blocks
//     (grid 512, LDS 73KB, launch_bounds(512,4)) -> 2 blocks/CU.
//     Partials (O, rowsum) -> ws; tiny combine kernel writes AO + sinv.
//   * exp-fold: p = exp2(fma(a, C2, log2(rel))); mean also folds log2(sinv)-2.
//   * Vt re-laid out [b][st16][d][k16] -> V staging fully contiguous.
//   * attn_mean: kslice 8, raw s_barrier + counted vmcnt pipeline.
// ---------------------------------------------------------------------------

typedef __attribute__((ext_vector_type(8))) _Float16 half8;
typedef __attribute__((ext_vector_type(4))) _Float16 half4;
typedef __attribute__((ext_vector_type(2))) __fp16 fp16x2;   // cvt_pkrtz result type
typedef __attribute__((ext_vector_type(4))) float f32x4;

#define MFMAH32(A, B, C) __builtin_amdgcn_mfma_f32_16x16x32_f16((A), (B), (C), 0, 0, 0)
#define MFMAH16(A, B, C) __builtin_amdgcn_mfma_f32_16x16x16f16((A), (B), (C), 0, 0, 0)

__device__ __forceinline__ unsigned short f2h(float f) {
    union { _Float16 h; unsigned short u; } c; c.h = (_Float16)f; return c.u;
}
__device__ __forceinline__ float h2f(unsigned short u) {
    union { unsigned short u; _Float16 h; } c; c.u = u; return (float)c.h;
}
__device__ __forceinline__ half8 ldh8(const unsigned short* p) {
    return *reinterpret_cast<const half8*>(p);
}
__device__ __forceinline__ half4 ldh4(const unsigned short* p) {
    return *reinterpret_cast<const half4*>(p);
}
__device__ __forceinline__ half4 pk4(float a, float b, float c, float d) {
    union { fp16x2 h2[2]; half4 h4; } u;
    u.h2[0] = __builtin_amdgcn_cvt_pkrtz(a, b);
    u.h2[1] = __builtin_amdgcn_cvt_pkrtz(c, d);
    return u.h4;
}
__device__ __forceinline__ unsigned int pku(float a, float b) {
    union { fp16x2 h2; unsigned int u; } c;
    c.h2 = __builtin_amdgcn_cvt_pkrtz(a, b);
    return c.u;
}
__device__ __forceinline__ void gld16(const unsigned short* g, unsigned short* l) {
    __builtin_amdgcn_global_load_lds(
        (const __attribute__((address_space(1))) unsigned int*)g,
        (__attribute__((address_space(3))) unsigned int*)l, 16, 0, 0);
}

// ---------------------------------------------------------------------------
// 1. Weights -> fp16, transposed [n][k]
// ---------------------------------------------------------------------------
__global__ void wsplit_kernel(const float* __restrict__ Wq, const float* __restrict__ Wk,
                              const float* __restrict__ Wv, const float* __restrict__ Wo,
                              unsigned short* __restrict__ WT) {
    int e = blockIdx.x * 256 + threadIdx.x;
    int m = e >> 16;
    int idx = e & 65535;
    int k = idx >> 8, n = idx & 255;
    const float* W = (m == 0) ? Wq : (m == 1) ? Wk : (m == 2) ? Wv : Wo;
    WT[m * 65536 + n * 256 + k] = f2h(W[idx]);
}

// ---------------------------------------------------------------------------
// Weight-staged fp16 GEMM core (proj3 + final).
// ---------------------------------------------------------------------------
#define STAGE_W(dst_, src_, kt_) do {                                               \
    _Pragma("unroll")                                                               \
    for (int j_ = 0; j_ < 4; ++j_) {                                                \
        int s_ = w * 4 + j_;                                                        \
        int rowl_ = 8 * s_ + (l >> 3);                                              \
        int so_ = rowl_ * 256 + (kt_) * 64 + (((l & 7) ^ (rowl_ & 7)) << 3);        \
        gld16(&(src_)[so_], &(dst_)[s_ * 512]);                                     \
    }                                                                               \
} while (0)

#define GEMM_TILE(buf_, kt_) do {                                                   \
    _Pragma("unroll")                                                               \
    for (int ksl_ = 0; ksl_ < 2; ++ksl_) {                                          \
        _Pragma("unroll")                                                           \
        for (int n_ = 0; n_ < 16; ++n_) {                                           \
            int r_ = n_ * 16 + l15;                                                 \
            int idx_ = r_ * 64 + ((((ksl_)*4 + lg) ^ (r_ & 7)) << 3);               \
            half8 b_ = ldh8(&(buf_)[idx_]);                                         \
            acc[n_] = MFMAH32(ah[(kt_) * 2 + ksl_], b_, acc[n_]);                   \
        }                                                                           \
    }                                                                               \
} while (0)

// ---------------------------------------------------------------------------
// 2. Projections (job 0:Q, 1:K, 2:V).  512 thr, 128 rows/block, grid (64,3).
// ---------------------------------------------------------------------------
__global__ __launch_bounds__(512, 1) void proj3_kernel(
    const float* __restrict__ query, const float* __restrict__ kv,
    const float* __restrict__ rel, const unsigned short* __restrict__ WT,
    const float* __restrict__ bq, const float* __restrict__ bk, const float* __restrict__ bv,
    unsigned short* __restrict__ Qh, unsigned short* __restrict__ Kh,
    unsigned short* __restrict__ Vtmp) {
    const int job = blockIdx.y;
    const float* X = (job == 0) ? query : kv;
    const unsigned short* wg = WT + job * 65536;
    const float* bias = (job == 0) ? bq : (job == 1) ? bk : bv;
    const float* rs = (job == 0) ? nullptr : rel;
    unsigned short* oh = (job == 0) ? Qh : (job == 1) ? Kh : Vtmp;

    __shared__ __align__(16) unsigned short wlds[2][256 * 64];

    const int w = threadIdx.x >> 6, l = threadIdx.x & 63;
    const int l15 = l & 15, lg = l >> 4;
    const int arow = blockIdx.x * 128 + w * 16 + l15;

    half8 ah[8];
#pragma unroll
    for (int ks = 0; ks < 8; ++ks) {
        const float* p = &X[arow * 256 + ks * 32 + lg * 8];
        float4 f0 = *reinterpret_cast<const float4*>(p);
        float4 f1 = *reinterpret_cast<const float4*>(p + 4);
        half8 t;
        t[0] = (_Float16)f0.x; t[1] = (_Float16)f0.y; t[2] = (_Float16)f0.z; t[3] = (_Float16)f0.w;
        t[4] = (_Float16)f1.x; t[5] = (_Float16)f1.y; t[6] = (_Float16)f1.z; t[7] = (_Float16)f1.w;
        ah[ks] = t;
    }
    f32x4 acc[16];
#pragma unroll
    for (int n = 0; n < 16; ++n) acc[n] = (f32x4){0.f, 0.f, 0.f, 0.f};

    STAGE_W(wlds[0], wg, 0);
    __syncthreads();
#pragma unroll
    for (int kt = 0; kt < 4; ++kt) {
        const int cur = kt & 1, nx = cur ^ 1;
        if (kt < 3) STAGE_W(wlds[nx], wg, kt + 1);
        GEMM_TILE(wlds[cur], kt);
        __syncthreads();
    }

    const int orow0 = blockIdx.x * 128 + w * 16 + lg * 4;
    float rsv[4];
#pragma unroll
    for (int r = 0; r < 4; ++r) rsv[r] = rs ? rs[orow0 + r] : 1.0f;
#pragma unroll
    for (int n = 0; n < 16; ++n) {
        const int col = n * 16 + l15;
        const float bn = bias[col];
#pragma unroll
        for (int r = 0; r < 4; ++r)
            oh[(orow0 + r) * 256 + col] = f2h((acc[n][r] + bn) * rsv[r]);
    }
}

// ---------------------------------------------------------------------------
// 3. Transpose V: Vtmp [b][k][256 d] -> Vt [b][st=k/16][256 d][16 k]
//    grid (128 st, 4 b), 256 thr.
// ---------------------------------------------------------------------------
__global__ void transpose_v_kernel(const unsigned short* __restrict__ Vtmp,
                                   unsigned short* __restrict__ Vt) {
    __shared__ unsigned short tile[16][264];
    const int st = blockIdx.x, b = blockIdx.y;
    const int t = threadIdx.x;
#pragma unroll
    for (int it = 0; it < 4; ++it) {
        int idx = it * 256 + t;              // ushort4 units, 1024 total
        int kr = idx >> 6;
        int d4 = (idx & 63) * 4;
        ushort4 v = *reinterpret_cast<const ushort4*>(
            &Vtmp[(size_t)(b * 2048 + st * 16 + kr) * 256 + d4]);
        tile[kr][d4 + 0] = v.x; tile[kr][d4 + 1] = v.y;
        tile[kr][d4 + 2] = v.z; tile[kr][d4 + 3] = v.w;
    }
    __syncthreads();
    {
        const int d = t;
        unsigned int u[8];
#pragma unroll
        for (int k2 = 0; k2 < 8; ++k2)
            u[k2] = (unsigned int)tile[k2 * 2][d] | ((unsigned int)tile[k2 * 2 + 1][d] << 16);
        uint4* dst = reinterpret_cast<uint4*>(&Vt[((size_t)(b * 128 + st) * 256 + d) * 16]);
        dst[0] = (uint4){u[0], u[1], u[2], u[3]};
        dst[1] = (uint4){u[4], u[5], u[6], u[7]};
    }
}

// ---------------------------------------------------------------------------
// 4. Attention pass 1.  Grid 512 (b, qtile32, khalf), 512 thr = 8 waves =
//    (4 heads) x (2 k-subhalves); per-wave PRIVATE dbuf staging of 16-row
//    K steps + V steps, counted vmcnt(4), no loop barriers.
//    S^T regs -> exp2(fma(a,C2,lr)) -> pkrtz -> PV A-frag (mfma 16x16x16).
//    In-block ks-combine; per-(b,kh) partials to ws.
// ---------------------------------------------------------------------------
__global__ __launch_bounds__(512, 4) void attn_pass1(
    const unsigned short* __restrict__ Qh, const unsigned short* __restrict__ Kh,
    const unsigned short* __restrict__ Vt, const float* __restrict__ rel,
    float* __restrict__ po_a, float* __restrict__ po_b, float* __restrict__ ps) {
    const int bid = blockIdx.x;                       // 0..511
    const int sw = (bid & 7) * 64 + (bid >> 3);       // XCD batch-locality
    const int b = sw >> 7;
    const int rem = sw & 127;
    const int kh = rem & 1;
    const int q0 = (rem >> 1) * 32;
    const int tid = threadIdx.x;
    const int w = tid >> 6, h = w & 3, ks = w >> 2;
    const int l = tid & 63, l15 = l & 15, lg = l >> 4;
    const float C2 = 0.18033688011112042f;            // 0.125 * log2(e)

    __shared__ __align__(16) unsigned short ldsK[8][2][1024];   // 32KB
    __shared__ __align__(16) unsigned short ldsV[8][2][1024];   // 32KB
    __shared__ float rel_lr[2048];                              // 8KB
    __shared__ float ssum_sh[2][4][2][16];                      // 1KB

    {   // lr = log2(clamp(rel))
        float4 v = reinterpret_cast<const float4*>(&rel[b * 2048])[tid];
        float* d = &rel_lr[tid * 4];
        d[0] = log2f(fmaxf(v.x, 1e-6f)); d[1] = log2f(fmaxf(v.y, 1e-6f));
        d[2] = log2f(fmaxf(v.z, 1e-6f)); d[3] = log2f(fmaxf(v.w, 1e-6f));
    }

    half8 qf00, qf01, qf10, qf11;                     // [qs][kd] B-frags
    {
        const int o0 = (b * 2048 + q0 + l15) * 256 + h * 64 + lg * 8;
        const int o1 = o0 + 16 * 256;
        qf00 = ldh8(&Qh[o0]); qf01 = ldh8(&Qh[o0 + 32]);
        qf10 = ldh8(&Qh[o1]); qf11 = ldh8(&Qh[o1 + 32]);
    }
    __syncthreads();

    const int st0 = kh * 64 + ks * 32;                // 16-row step units

#define STG(buf_, i_) do {                                                          \
    const unsigned short* kbp_ = Kh + (size_t)(b * 2048 + (st0 + (i_)) * 16) * 256  \
                                 + h * 64;                                          \
    _Pragma("unroll")                                                               \
    for (int j_ = 0; j_ < 2; ++j_) {                                                \
        int r_ = j_ * 8 + (l >> 3);                                                 \
        gld16(kbp_ + r_ * 256 + (((l & 7) ^ ((l >> 3) & 7)) << 3),                  \
              &ldsK[w][buf_][j_ * 512]);                                            \
    }                                                                               \
    const unsigned short* vbp_ = Vt + (size_t)((b * 128 + st0 + (i_)) * 256         \
                                 + h * 64) * 16;                                    \
    _Pragma("unroll")                                                               \
    for (int j_ = 0; j_ < 2; ++j_) {                                                \
        int d_ = j_ * 32 + (l >> 1);                                                \
        gld16(vbp_ + d_ * 16 + (((l & 1) ^ ((l >> 1) & 1)) << 3),                   \
              &ldsV[w][buf_][j_ * 512]);                                            \
    }                                                                               \
} while (0)

    float ssum0 = 0.f, ssum1 = 0.f;
    f32x4 o0acc[4], o1acc[4];
#pragma unroll
    for (int dc = 0; dc < 4; ++dc) {
        o0acc[dc] = (f32x4){0.f, 0.f, 0.f, 0.f};
        o1acc[dc] = (f32x4){0.f, 0.f, 0.f, 0.f};
    }

    STG(0, 0);
    for (int i = 0; i < 32; ++i) {
        const int cur = i & 1, nx = cur ^ 1;
        if (i < 31) {
            STG(nx, i + 1);
            asm volatile("s_waitcnt vmcnt(4)" ::: "memory");
        } else {
            asm volatile("s_waitcnt vmcnt(0)" ::: "memory");
        }
        __builtin_amdgcn_sched_barrier(0);
        half8 kf0 = ldh8(&ldsK[w][cur][l15 * 64 + ((lg ^ (l15 & 7)) << 3)]);
        half8 kf1 = ldh8(&ldsK[w][cur][l15 * 64 + (((4 + lg) ^ (l15 & 7)) << 3)]);
        f32x4 a0 = (f32x4){0.f, 0.f, 0.f, 0.f}, a1 = a0;
        a0 = MFMAH32(kf0, qf00, a0); a0 = MFMAH32(kf1, qf01, a0);
        a1 = MFMAH32(kf0, qf10, a1); a1 = MFMAH32(kf1, qf11, a1);
        float4 lr4 = *reinterpret_cast<const float4*>(&rel_lr[(st0 + i) * 16 + lg * 4]);
        float p00 = exp2f(__builtin_fmaf(a0[0], C2, lr4.x));
        float p01 = exp2f(__builtin_fmaf(a0[1], C2, lr4.y));
        float p02 = exp2f(__builtin_fmaf(a0[2], C2, lr4.z));
        float p03 = exp2f(__builtin_fmaf(a0[3], C2, lr4.w));
        float p10 = exp2f(__builtin_fmaf(a1[0], C2, lr4.x));
        float p11 = exp2f(__builtin_fmaf(a1[1], C2, lr4.y));
        float p12 = exp2f(__builtin_fmaf(a1[2], C2, lr4.z));
        float p13 = exp2f(__builtin_fmaf(a1[3], C2, lr4.w));
        ssum0 += (p00 + p01) + (p02 + p03);
        ssum1 += (p10 + p11) + (p12 + p13);
        half4 pa0 = pk4(p00, p01, p02, p03);
        half4 pa1 = pk4(p10, p11, p12, p13);
#pragma unroll
        for (int dc = 0; dc < 4; ++dc) {
            const int d = dc * 16 + l15;
            half4 vf = ldh4(&ldsV[w][cur][d * 16 + ((((lg >> 1) ^ (d & 1))) << 3) + (lg & 1) * 4]);
            o0acc[dc] = MFMAH16(pa0, vf, o0acc[dc]);
            o1acc[dc] = MFMAH16(pa1, vf, o1acc[dc]);
        }
    }
#undef STG

    float v0 = ssum0, v1 = ssum1;
    v0 += __shfl_xor(v0, 16); v0 += __shfl_xor(v0, 32);
    v1 += __shfl_xor(v1, 16); v1 += __shfl_xor(v1, 32);

    __syncthreads();                                  // done with ldsK/V
    if (l < 16) { ssum_sh[ks][h][0][l] = v0; ssum_sh[ks][h][1][l] = v1; }
    float* obuf = (float*)&ldsK[0][0][0];             // [32 q][256 d]
    if (ks == 1) {
#pragma unroll
        for (int dc = 0; dc < 4; ++dc)
#pragma unroll
            for (int r = 0; r < 4; ++r) {
                const int d = h * 64 + dc * 16 + l15;
                obuf[(lg * 4 + r) * 256 + d] = o0acc[dc][r];
                obuf[(16 + lg * 4 + r) * 256 + d] = o1acc[dc][r];
            }
    }
    __syncthreads();
    if (ks == 0) {
        const int chunk = b * 2 + kh;
        float* po = (chunk < 2) ? (po_a + (size_t)chunk * 524288)
                                : (po_b + (size_t)(chunk - 2) * 524288);
#pragma unroll
        for (int dc = 0; dc < 4; ++dc)
#pragma unroll
            for (int r = 0; r < 4; ++r) {
                const int d = h * 64 + dc * 16 + l15;
                const int qa = lg * 4 + r, qb = 16 + lg * 4 + r;
                po[(size_t)(q0 + qa) * 256 + d] = o0acc[dc][r] + obuf[qa * 256 + d];
                po[(size_t)(q0 + qb) * 256 + d] = o1acc[dc][r] + obuf[qb * 256 + d];
            }
        if (l < 16) {
            ps[(chunk * 4 + h) * 2048 + q0 + l] =
                ssum_sh[0][h][0][l] + ssum_sh[1][h][0][l];
            ps[(chunk * 4 + h) * 2048 + q0 + 16 + l] =
                ssum_sh[0][h][1][l] + ssum_sh[1][h][1][l];
        }
    }
}

// ---------------------------------------------------------------------------
// 5. Combine k-half partials: AO = (po0+po1)/s (fp16), sinv_ws = 1/s.
//    grid 2048 x 256: thread -> (b, q, 4 d).
// ---------------------------------------------------------------------------
__global__ __launch_bounds__(256) void combine_kernel(
    const float* __restrict__ po_a, const float* __restrict__ po_b,
    const float* __restrict__ ps, unsigned short* __restrict__ AO,
    float* __restrict__ sinv_ws) {
    const int t = blockIdx.x * 256 + threadIdx.x;
    const int d4 = t & 63;
    const int bq = t >> 6;
    const int q = bq & 2047;
    const int b = bq >> 11;
    const int d0 = d4 * 4, h = d0 >> 6;
    const int c0 = b * 2, c1 = b * 2 + 1;
    const float* p0 = (c0 < 2) ? po_a + (size_t)c0 * 524288 : po_b + (size_t)(c0 - 2) * 524288;
    const float* p1 = (c1 < 2) ? po_a + (size_t)c1 * 524288 : po_b + (size_t)(c1 - 2) * 524288;
    float4 x = *reinterpret_cast<const float4*>(&p0[(size_t)q * 256 + d0]);
    float4 y = *reinterpret_cast<const float4*>(&p1[(size_t)q * 256 + d0]);
    float s = ps[(c0 * 4 + h) * 2048 + q] + ps[(c1 * 4 + h) * 2048 + q];
    float si = 1.0f / s;
    ushort4 o;
    o.x = f2h((x.x + y.x) * si); o.y = f2h((x.y + y.y) * si);
    o.z = f2h((x.z + y.z) * si); o.w = f2h((x.w + y.w) * si);
    *reinterpret_cast<ushort4*>(&AO[((size_t)(b * 2048 + q)) * 256 + d0]) = o;
    if (d4 == (h << 4)) sinv_ws[(b * 4 + h) * 2048 + q] = si;
}

// ---------------------------------------------------------------------------
// 6. Attention pass 2: attn_mean.  Grid 2048 = 8 kslices x 256; 256 thr.
//    Counted-vmcnt + raw s_barrier pipeline; p/4 = exp2(a*C2 + lr + lsi-2).
// ---------------------------------------------------------------------------
__global__ __launch_bounds__(256, 2) void attn_mean_kernel(
    const unsigned short* __restrict__ Qh, const unsigned short* __restrict__ Kh,
    const float* __restrict__ rel, const float* __restrict__ sinv_ws,
    float* __restrict__ attn_mean) {
    const int kslice = blockIdx.x >> 8;
    const int inner = blockIdx.x & 255;
    const int sw = (inner & 7) * 32 + (inner >> 3);
    const int b = sw >> 6;
    const int q0 = (sw & 63) * 32;
    const int tid = threadIdx.x;
    const int w = tid >> 6;
    const int h = w;
    const int l = tid & 63, l15 = l & 15, lg = l >> 4;
    const int kb = b * 2048;
    const float C2 = 0.18033688011112042f;

    __shared__ __align__(16) unsigned short ldsK[2][8192];      // 32KB
    __shared__ __align__(16) unsigned short pbf2[2][4][2][640]; // 20KB
    __shared__ float rel_lr[2048];                              // 8KB

#define STAGE_KM(dst_, kt_) do {                                                    \
    _Pragma("unroll")                                                               \
    for (int j_ = 0; j_ < 4; ++j_) {                                                \
        int s_ = w * 4 + j_;                                                        \
        int r_ = 2 * s_ + (l >> 5);                                                 \
        size_t so_ = (size_t)(kb + (kt_) * 32 + r_) * 256 +                         \
                     (((l & 31) ^ (r_ & 7)) << 3);                                  \
        gld16(&Kh[so_], &(dst_)[s_ * 512]);                                         \
    }                                                                               \
} while (0)

    {
        float4 v0 = reinterpret_cast<const float4*>(&rel[b * 2048])[tid * 2];
        float4 v1 = reinterpret_cast<const float4*>(&rel[b * 2048])[tid * 2 + 1];
        float* d = &rel_lr[tid * 8];
        d[0] = log2f(fmaxf(v0.x, 1e-6f)); d[1] = log2f(fmaxf(v0.y, 1e-6f));
        d[2] = log2f(fmaxf(v0.z, 1e-6f)); d[3] = log2f(fmaxf(v0.w, 1e-6f));
        d[4] = log2f(fmaxf(v1.x, 1e-6f)); d[5] = log2f(fmaxf(v1.y, 1e-6f));
        d[6] = log2f(fmaxf(v1.z, 1e-6f)); d[7] = log2f(fmaxf(v1.w, 1e-6f));
    }

    half8 qf00, qf01, qf10, qf11;
    {
        const int o0 = (b * 2048 + q0 + l15) * 256 + h * 64 + lg * 8;
        const int o1 = o0 + 16 * 256;
        qf00 = ldh8(&Qh[o0]); qf01 = ldh8(&Qh[o0 + 32]);
        qf10 = ldh8(&Qh[o1]); qf11 = ldh8(&Qh[o1 + 32]);
    }
    const float lsi0 = log2f(sinv_ws[(b * 4 + h) * 2048 + q0 + l15]) - 2.0f;
    const float lsi1 = log2f(sinv_ws[(b * 4 + h) * 2048 + q0 + 16 + l15]) - 2.0f;
    __syncthreads();

    const int kt0 = kslice * 8;
    STAGE_KM(ldsK[0], kt0);
    for (int ki = 0; ki < 8; ++ki) {
        const int kt = kt0 + ki;
        const int cur = ki & 1, nx = cur ^ 1;
        if (ki < 7) {
            STAGE_KM(ldsK[nx], kt + 1);
            asm volatile("s_waitcnt vmcnt(4)" ::: "memory");
        } else {
            asm volatile("s_waitcnt vmcnt(0)" ::: "memory");
        }
        asm volatile("s_barrier" ::: "memory");       // buf[cur] ready (all waves)
        __builtin_amdgcn_sched_barrier(0);
#pragma unroll
        for (int kc = 0; kc < 2; ++kc) {
            const int r = kc * 16 + l15;
            const int rx = r & 7;
            half8 kf0 = ldh8(&ldsK[cur][r * 256 + (((h * 8 + lg) ^ rx) << 3)]);
            half8 kf1 = ldh8(&ldsK[cur][r * 256 + (((h * 8 + 4 + lg) ^ rx) << 3)]);
            f32x4 a0 = (f32x4){0.f, 0.f, 0.f, 0.f}, a1 = a0;
            a0 = MFMAH32(kf0, qf00, a0); a0 = MFMAH32(kf1, qf01, a0);
            a1 = MFMAH32(kf0, qf10, a1); a1 = MFMAH32(kf1, qf11, a1);
            float4 lr4 = *reinterpret_cast<const float4*>(
                &rel_lr[kt * 32 + kc * 16 + lg * 4]);
            float q00 = exp2f(__builtin_fmaf(a0[0], C2, lsi0) + lr4.x);
            float q01 = exp2f(__builtin_fmaf(a0[1], C2, lsi0) + lr4.y);
            float q02 = exp2f(__builtin_fmaf(a0[2], C2, lsi0) + lr4.z);
            float q03 = exp2f(__builtin_fmaf(a0[3], C2, lsi0) + lr4.w);
            float q10 = exp2f(__builtin_fmaf(a1[0], C2, lsi1) + lr4.x);
            float q11 = exp2f(__builtin_fmaf(a1[1], C2, lsi1) + lr4.y);
            float q12 = exp2f(__builtin_fmaf(a1[2], C2, lsi1) + lr4.z);
            float q13 = exp2f(__builtin_fmaf(a1[3], C2, lsi1) + lr4.w);
            uint2 w0, w1;
            w0.x = pku(q00, q01); w0.y = pku(q02, q03);
            w1.x = pku(q10, q11); w1.y = pku(q12, q13);
            *reinterpret_cast<uint2*>(&pbf2[cur][h][0][l15 * 40 + kc * 16 + lg * 4]) = w0;
            *reinterpret_cast<uint2*>(&pbf2[cur][h][1][l15 * 40 + kc * 16 + lg * 4]) = w1;
        }
        asm volatile("s_waitcnt lgkmcnt(0)\n\ts_barrier" ::: "memory");
        {   // head-mean (already /4-scaled): 2 qs x 16 rows x 8 col-chunks
            const int qs_ = tid >> 7, row = (tid >> 3) & 15, kq = tid & 7;
            float m0 = 0.f, m1 = 0.f, m2 = 0.f, m3 = 0.f;
#pragma unroll
            for (int hh = 0; hh < 4; ++hh) {
                ushort4 u = *reinterpret_cast<const ushort4*>(
                    &pbf2[cur][hh][qs_][row * 40 + kq * 4]);
                m0 += h2f(u.x); m1 += h2f(u.y); m2 += h2f(u.z); m3 += h2f(u.w);
            }
            *reinterpret_cast<float4*>(
                &attn_mean[(size_t)(b * 2048 + q0 + qs_ * 16 + row) * 2048 +
                           kt * 32 + kq * 4]) = (float4){m0, m1, m2, m3};
        }
    }
#undef STAGE_KM
}

// ---------------------------------------------------------------------------
// 7. out = AO @ Wo + bo
// ---------------------------------------------------------------------------
__global__ __launch_bounds__(512, 1) void final_kernel(
    const unsigned short* __restrict__ AO, const unsigned short* __restrict__ WoT,
    const float* __restrict__ bo, float* __restrict__ out) {
    __shared__ __align__(16) unsigned short wlds[2][256 * 64];

    const int w = threadIdx.x >> 6, l = threadIdx.x & 63;
    const int l15 = l & 15, lg = l >> 4;
    const int arow = blockIdx.x * 128 + w * 16 + l15;

    half8 ah[8];
#pragma unroll
    for (int ks = 0; ks < 8; ++ks)
        ah[ks] = ldh8(&AO[arow * 256 + ks * 32 + lg * 8]);
    f32x4 acc[16];
#pragma unroll
    for (int n = 0; n < 16; ++n) acc[n] = (f32x4){0.f, 0.f, 0.f, 0.f};

    STAGE_W(wlds[0], WoT, 0);
    __syncthreads();
#pragma unroll
    for (int kt = 0; kt < 4; ++kt) {
        const int cur = kt & 1, nx = cur ^ 1;
        if (kt < 3) STAGE_W(wlds[nx], WoT, kt + 1);
        GEMM_TILE(wlds[cur], kt);
        __syncthreads();
    }

    const int orow0 = blockIdx.x * 128 + w * 16 + lg * 4;
#pragma unroll
    for (int n = 0; n < 16; ++n) {
        const int col = n * 16 + l15;
        const float bn = bo[col];
#pragma unroll
        for (int r = 0; r < 4; ++r)
            out[(orow0 + r) * 256 + col] = acc[n][r] + bn;
    }
}

// ---------------------------------------------------------------------------
extern "C" void kernel_launch(void* const* d_in, const int* in_sizes, int n_in,
                              void* d_out, int out_size, void* d_ws, size_t ws_size,
                              hipStream_t stream) {
    const float* query = (const float*)d_in[0];
    const float* kv    = (const float*)d_in[1];
    const float* rel   = (const float*)d_in[2];
    const float* Wq    = (const float*)d_in[3];
    const float* bq    = (const float*)d_in[4];
    const float* Wk    = (const float*)d_in[5];
    const float* bk    = (const float*)d_in[6];
    const float* Wv    = (const float*)d_in[7];
    const float* bv    = (const float*)d_in[8];
    const float* Wo    = (const float*)d_in[9];
    const float* bo    = (const float*)d_in[10];

    char* ws = (char*)d_ws;
    unsigned short* WT   = (unsigned short*)(ws + 0);          // 512KB
    unsigned short* Qh   = (unsigned short*)(ws + 524288);     // 4MB
    unsigned short* Kh   = (unsigned short*)(ws + 4718592);    // 4MB
    unsigned short* Vtmp = (unsigned short*)(ws + 8912896);    // 4MB (po chunks 0,1 after transpose)
    unsigned short* Vt   = (unsigned short*)(ws + 13107200);   // 4MB
    unsigned short* AO   = (unsigned short*)(ws + 17301504);   // 4MB
    float*          sinv = (float*)(ws + 21495808);            // 128KB
    float*          ps   = (float*)(ws + 21626880);            // 256KB
    float*          po_b = (float*)(ws + 21889024);            // 12MB -> end ~32.9MB
    float*          po_a = (float*)Vtmp;                       // overlay (Vtmp dead post-transpose)

    float* out = (float*)d_out;
    float* attn_mean = (float*)d_out + 2097152;

    wsplit_kernel<<<1024, 256, 0, stream>>>(Wq, Wk, Wv, Wo, WT);
    proj3_kernel<<<dim3(64, 3), 512, 0, stream>>>(query, kv, rel, WT,
                                                  bq, bk, bv, Qh, Kh, Vtmp);
    transpose_v_kernel<<<dim3(128, 4), 256, 0, stream>>>(Vtmp, Vt);
    attn_pass1<<<512, 512, 0, stream>>>(Qh, Kh, Vt, rel, po_a, po_b, ps);
    combine_kernel<<<2048, 256, 0, stream>>>(po_a, po_b, ps, AO, sinv);
    attn_mean_kernel<<<2048, 256, 0, stream>>>(Qh, Kh, rel, sinv, attn_mean);
    final_kernel<<<64, 512, 0, stream>>>(AO, WT + 3 * 65536, bo, out);
}

// Round 10
// 111.765 us; speedup vs baseline: 3.7556x; 1.1012x over previous
//
#include <hip/hip_runtime.h>

// ---------------------------------------------------------------------------
// ReliabilityGatedCrossAttention — fp16 MFMA pipeline, gfx950.  R10.
//
// R9 post-mortem: attn_mean (52us) is the largest kernel — VALU+LDS bound on
// the fp16 pack->LDS->unpack head-mean round trip.  R10: waves = (qs x kc)
// quadrants, each wave computes ALL 4 heads for its 16q x 16k tile
// (unswapped mfma(Q,K), R6-verified layout) -> head-mean fully in-register,
// fp32 stores direct to attn_mean.  pbf2 LDS eliminated; LDS 60->40KB.
// Everything else unchanged from R9.
// ---------------------------------------------------------------------------

typedef __attribute__((ext_vector_type(8))) _Float16 half8;
typedef __attribute__((ext_vector_type(4))) _Float16 half4;
typedef __attribute__((ext_vector_type(2))) __fp16 fp16x2;   // cvt_pkrtz result type
typedef __attribute__((ext_vector_type(4))) float f32x4;

#define MFMAH32(A, B, C) __builtin_amdgcn_mfma_f32_16x16x32_f16((A), (B), (C), 0, 0, 0)
#define MFMAH16(A, B, C) __builtin_amdgcn_mfma_f32_16x16x16f16((A), (B), (C), 0, 0, 0)

__device__ __forceinline__ unsigned short f2h(float f) {
    union { _Float16 h; unsigned short u; } c; c.h = (_Float16)f; return c.u;
}
__device__ __forceinline__ float h2f(unsigned short u) {
    union { unsigned short u; _Float16 h; } c; c.u = u; return (float)c.h;
}
__device__ __forceinline__ half8 ldh8(const unsigned short* p) {
    return *reinterpret_cast<const half8*>(p);
}
__device__ __forceinline__ half4 ldh4(const unsigned short* p) {
    return *reinterpret_cast<const half4*>(p);
}
__device__ __forceinline__ half4 pk4(float a, float b, float c, float d) {
    union { fp16x2 h2[2]; half4 h4; } u;
    u.h2[0] = __builtin_amdgcn_cvt_pkrtz(a, b);
    u.h2[1] = __builtin_amdgcn_cvt_pkrtz(c, d);
    return u.h4;
}
__device__ __forceinline__ void gld16(const unsigned short* g, unsigned short* l) {
    __builtin_amdgcn_global_load_lds(
        (const __attribute__((address_space(1))) unsigned int*)g,
        (__attribute__((address_space(3))) unsigned int*)l, 16, 0, 0);
}

// ---------------------------------------------------------------------------
// 1. Weights -> fp16, transposed [n][k]
// ---------------------------------------------------------------------------
__global__ void wsplit_kernel(const float* __restrict__ Wq, const float* __restrict__ Wk,
                              const float* __restrict__ Wv, const float* __restrict__ Wo,
                              unsigned short* __restrict__ WT) {
    int e = blockIdx.x * 256 + threadIdx.x;
    int m = e >> 16;
    int idx = e & 65535;
    int k = idx >> 8, n = idx & 255;
    const float* W = (m == 0) ? Wq : (m == 1) ? Wk : (m == 2) ? Wv : Wo;
    WT[m * 65536 + n * 256 + k] = f2h(W[idx]);
}

// ---------------------------------------------------------------------------
// Weight-staged fp16 GEMM core (proj3 + final).
// ---------------------------------------------------------------------------
#define STAGE_W(dst_, src_, kt_) do {                                               \
    _Pragma("unroll")                                                               \
    for (int j_ = 0; j_ < 4; ++j_) {                                                \
        int s_ = w * 4 + j_;                                                        \
        int rowl_ = 8 * s_ + (l >> 3);                                              \
        int so_ = rowl_ * 256 + (kt_) * 64 + (((l & 7) ^ (rowl_ & 7)) << 3);        \
        gld16(&(src_)[so_], &(dst_)[s_ * 512]);                                     \
    }                                                                               \
} while (0)

#define GEMM_TILE(buf_, kt_) do {                                                   \
    _Pragma("unroll")                                                               \
    for (int ksl_ = 0; ksl_ < 2; ++ksl_) {                                          \
        _Pragma("unroll")                                                           \
        for (int n_ = 0; n_ < 16; ++n_) {                                           \
            int r_ = n_ * 16 + l15;                                                 \
            int idx_ = r_ * 64 + ((((ksl_)*4 + lg) ^ (r_ & 7)) << 3);               \
            half8 b_ = ldh8(&(buf_)[idx_]);                                         \
            acc[n_] = MFMAH32(ah[(kt_) * 2 + ksl_], b_, acc[n_]);                   \
        }                                                                           \
    }                                                                               \
} while (0)

// ---------------------------------------------------------------------------
// 2. Projections (job 0:Q, 1:K, 2:V).  512 thr, 128 rows/block, grid (64,3).
// ---------------------------------------------------------------------------
__global__ __launch_bounds__(512, 1) void proj3_kernel(
    const float* __restrict__ query, const float* __restrict__ kv,
    const float* __restrict__ rel, const unsigned short* __restrict__ WT,
    const float* __restrict__ bq, const float* __restrict__ bk, const float* __restrict__ bv,
    unsigned short* __restrict__ Qh, unsigned short* __restrict__ Kh,
    unsigned short* __restrict__ Vtmp) {
    const int job = blockIdx.y;
    const float* X = (job == 0) ? query : kv;
    const unsigned short* wg = WT + job * 65536;
    const float* bias = (job == 0) ? bq : (job == 1) ? bk : bv;
    const float* rs = (job == 0) ? nullptr : rel;
    unsigned short* oh = (job == 0) ? Qh : (job == 1) ? Kh : Vtmp;

    __shared__ __align__(16) unsigned short wlds[2][256 * 64];

    const int w = threadIdx.x >> 6, l = threadIdx.x & 63;
    const int l15 = l & 15, lg = l >> 4;
    const int arow = blockIdx.x * 128 + w * 16 + l15;

    half8 ah[8];
#pragma unroll
    for (int ks = 0; ks < 8; ++ks) {
        const float* p = &X[arow * 256 + ks * 32 + lg * 8];
        float4 f0 = *reinterpret_cast<const float4*>(p);
        float4 f1 = *reinterpret_cast<const float4*>(p + 4);
        half8 t;
        t[0] = (_Float16)f0.x; t[1] = (_Float16)f0.y; t[2] = (_Float16)f0.z; t[3] = (_Float16)f0.w;
        t[4] = (_Float16)f1.x; t[5] = (_Float16)f1.y; t[6] = (_Float16)f1.z; t[7] = (_Float16)f1.w;
        ah[ks] = t;
    }
    f32x4 acc[16];
#pragma unroll
    for (int n = 0; n < 16; ++n) acc[n] = (f32x4){0.f, 0.f, 0.f, 0.f};

    STAGE_W(wlds[0], wg, 0);
    __syncthreads();
#pragma unroll
    for (int kt = 0; kt < 4; ++kt) {
        const int cur = kt & 1, nx = cur ^ 1;
        if (kt < 3) STAGE_W(wlds[nx], wg, kt + 1);
        GEMM_TILE(wlds[cur], kt);
        __syncthreads();
    }

    const int orow0 = blockIdx.x * 128 + w * 16 + lg * 4;
    float rsv[4];
#pragma unroll
    for (int r = 0; r < 4; ++r) rsv[r] = rs ? rs[orow0 + r] : 1.0f;
#pragma unroll
    for (int n = 0; n < 16; ++n) {
        const int col = n * 16 + l15;
        const float bn = bias[col];
#pragma unroll
        for (int r = 0; r < 4; ++r)
            oh[(orow0 + r) * 256 + col] = f2h((acc[n][r] + bn) * rsv[r]);
    }
}

// ---------------------------------------------------------------------------
// 3. Transpose V: Vtmp [b][k][256 d] -> Vt [b][st=k/16][256 d][16 k]
// ---------------------------------------------------------------------------
__global__ void transpose_v_kernel(const unsigned short* __restrict__ Vtmp,
                                   unsigned short* __restrict__ Vt) {
    __shared__ unsigned short tile[16][264];
    const int st = blockIdx.x, b = blockIdx.y;
    const int t = threadIdx.x;
#pragma unroll
    for (int it = 0; it < 4; ++it) {
        int idx = it * 256 + t;              // ushort4 units, 1024 total
        int kr = idx >> 6;
        int d4 = (idx & 63) * 4;
        ushort4 v = *reinterpret_cast<const ushort4*>(
            &Vtmp[(size_t)(b * 2048 + st * 16 + kr) * 256 + d4]);
        tile[kr][d4 + 0] = v.x; tile[kr][d4 + 1] = v.y;
        tile[kr][d4 + 2] = v.z; tile[kr][d4 + 3] = v.w;
    }
    __syncthreads();
    {
        const int d = t;
        unsigned int u[8];
#pragma unroll
        for (int k2 = 0; k2 < 8; ++k2)
            u[k2] = (unsigned int)tile[k2 * 2][d] | ((unsigned int)tile[k2 * 2 + 1][d] << 16);
        uint4* dst = reinterpret_cast<uint4*>(&Vt[((size_t)(b * 128 + st) * 256 + d) * 16]);
        dst[0] = (uint4){u[0], u[1], u[2], u[3]};
        dst[1] = (uint4){u[4], u[5], u[6], u[7]};
    }
}

// ---------------------------------------------------------------------------
// 4. Attention pass 1 (unchanged from R9).
// ---------------------------------------------------------------------------
__global__ __launch_bounds__(512, 4) void attn_pass1(
    const unsigned short* __restrict__ Qh, const unsigned short* __restrict__ Kh,
    const unsigned short* __restrict__ Vt, const float* __restrict__ rel,
    float* __restrict__ po_a, float* __restrict__ po_b, float* __restrict__ ps) {
    const int bid = blockIdx.x;                       // 0..511
    const int sw = (bid & 7) * 64 + (bid >> 3);       // XCD batch-locality
    const int b = sw >> 7;
    const int rem = sw & 127;
    const int kh = rem & 1;
    const int q0 = (rem >> 1) * 32;
    const int tid = threadIdx.x;
    const int w = tid >> 6, h = w & 3, ks = w >> 2;
    const int l = tid & 63, l15 = l & 15, lg = l >> 4;
    const float C2 = 0.18033688011112042f;            // 0.125 * log2(e)

    __shared__ __align__(16) unsigned short ldsK[8][2][1024];   // 32KB
    __shared__ __align__(16) unsigned short ldsV[8][2][1024];   // 32KB
    __shared__ float rel_lr[2048];                              // 8KB
    __shared__ float ssum_sh[2][4][2][16];                      // 1KB

    {   // lr = log2(clamp(rel))
        float4 v = reinterpret_cast<const float4*>(&rel[b * 2048])[tid];
        float* d = &rel_lr[tid * 4];
        d[0] = log2f(fmaxf(v.x, 1e-6f)); d[1] = log2f(fmaxf(v.y, 1e-6f));
        d[2] = log2f(fmaxf(v.z, 1e-6f)); d[3] = log2f(fmaxf(v.w, 1e-6f));
    }

    half8 qf00, qf01, qf10, qf11;                     // [qs][kd] B-frags
    {
        const int o0 = (b * 2048 + q0 + l15) * 256 + h * 64 + lg * 8;
        const int o1 = o0 + 16 * 256;
        qf00 = ldh8(&Qh[o0]); qf01 = ldh8(&Qh[o0 + 32]);
        qf10 = ldh8(&Qh[o1]); qf11 = ldh8(&Qh[o1 + 32]);
    }
    __syncthreads();

    const int st0 = kh * 64 + ks * 32;                // 16-row step units

#define STG(buf_, i_) do {                                                          \
    const unsigned short* kbp_ = Kh + (size_t)(b * 2048 + (st0 + (i_)) * 16) * 256  \
                                 + h * 64;                                          \
    _Pragma("unroll")                                                               \
    for (int j_ = 0; j_ < 2; ++j_) {                                                \
        int r_ = j_ * 8 + (l >> 3);                                                 \
        gld16(kbp_ + r_ * 256 + (((l & 7) ^ ((l >> 3) & 7)) << 3),                  \
              &ldsK[w][buf_][j_ * 512]);                                            \
    }                                                                               \
    const unsigned short* vbp_ = Vt + (size_t)((b * 128 + st0 + (i_)) * 256         \
                                 + h * 64) * 16;                                    \
    _Pragma("unroll")                                                               \
    for (int j_ = 0; j_ < 2; ++j_) {                                                \
        int d_ = j_ * 32 + (l >> 1);                                                \
        gld16(vbp_ + d_ * 16 + (((l & 1) ^ ((l >> 1) & 1)) << 3),                   \
              &ldsV[w][buf_][j_ * 512]);                                            \
    }                                                                               \
} while (0)

    float ssum0 = 0.f, ssum1 = 0.f;
    f32x4 o0acc[4], o1acc[4];
#pragma unroll
    for (int dc = 0; dc < 4; ++dc) {
        o0acc[dc] = (f32x4){0.f, 0.f, 0.f, 0.f};
        o1acc[dc] = (f32x4){0.f, 0.f, 0.f, 0.f};
    }

    STG(0, 0);
    for (int i = 0; i < 32; ++i) {
        const int cur = i & 1, nx = cur ^ 1;
        if (i < 31) {
            STG(nx, i + 1);
            asm volatile("s_waitcnt vmcnt(4)" ::: "memory");
        } else {
            asm volatile("s_waitcnt vmcnt(0)" ::: "memory");
        }
        __builtin_amdgcn_sched_barrier(0);
        half8 kf0 = ldh8(&ldsK[w][cur][l15 * 64 + ((lg ^ (l15 & 7)) << 3)]);
        half8 kf1 = ldh8(&ldsK[w][cur][l15 * 64 + (((4 + lg) ^ (l15 & 7)) << 3)]);
        f32x4 a0 = (f32x4){0.f, 0.f, 0.f, 0.f}, a1 = a0;
        a0 = MFMAH32(kf0, qf00, a0); a0 = MFMAH32(kf1, qf01, a0);
        a1 = MFMAH32(kf0, qf10, a1); a1 = MFMAH32(kf1, qf11, a1);
        float4 lr4 = *reinterpret_cast<const float4*>(&rel_lr[(st0 + i) * 16 + lg * 4]);
        float p00 = exp2f(__builtin_fmaf(a0[0], C2, lr4.x));
        float p01 = exp2f(__builtin_fmaf(a0[1], C2, lr4.y));
        float p02 = exp2f(__builtin_fmaf(a0[2], C2, lr4.z));
        float p03 = exp2f(__builtin_fmaf(a0[3], C2, lr4.w));
        float p10 = exp2f(__builtin_fmaf(a1[0], C2, lr4.x));
        float p11 = exp2f(__builtin_fmaf(a1[1], C2, lr4.y));
        float p12 = exp2f(__builtin_fmaf(a1[2], C2, lr4.z));
        float p13 = exp2f(__builtin_fmaf(a1[3], C2, lr4.w));
        ssum0 += (p00 + p01) + (p02 + p03);
        ssum1 += (p10 + p11) + (p12 + p13);
        half4 pa0 = pk4(p00, p01, p02, p03);
        half4 pa1 = pk4(p10, p11, p12, p13);
#pragma unroll
        for (int dc = 0; dc < 4; ++dc) {
            const int d = dc * 16 + l15;
            half4 vf = ldh4(&ldsV[w][cur][d * 16 + ((((lg >> 1) ^ (d & 1))) << 3) + (lg & 1) * 4]);
            o0acc[dc] = MFMAH16(pa0, vf, o0acc[dc]);
            o1acc[dc] = MFMAH16(pa1, vf, o1acc[dc]);
        }
    }
#undef STG

    float v0 = ssum0, v1 = ssum1;
    v0 += __shfl_xor(v0, 16); v0 += __shfl_xor(v0, 32);
    v1 += __shfl_xor(v1, 16); v1 += __shfl_xor(v1, 32);

    __syncthreads();                                  // done with ldsK/V
    if (l < 16) { ssum_sh[ks][h][0][l] = v0; ssum_sh[ks][h][1][l] = v1; }
    float* obuf = (float*)&ldsK[0][0][0];             // [32 q][256 d]
    if (ks == 1) {
#pragma unroll
        for (int dc = 0; dc < 4; ++dc)
#pragma unroll
            for (int r = 0; r < 4; ++r) {
                const int d = h * 64 + dc * 16 + l15;
                obuf[(lg * 4 + r) * 256 + d] = o0acc[dc][r];
                obuf[(16 + lg * 4 + r) * 256 + d] = o1acc[dc][r];
            }
    }
    __syncthreads();
    if (ks == 0) {
        const int chunk = b * 2 + kh;
        float* po = (chunk < 2) ? (po_a + (size_t)chunk * 524288)
                                : (po_b + (size_t)(chunk - 2) * 524288);
#pragma unroll
        for (int dc = 0; dc < 4; ++dc)
#pragma unroll
            for (int r = 0; r < 4; ++r) {
                const int d = h * 64 + dc * 16 + l15;
                const int qa = lg * 4 + r, qb = 16 + lg * 4 + r;
                po[(size_t)(q0 + qa) * 256 + d] = o0acc[dc][r] + obuf[qa * 256 + d];
                po[(size_t)(q0 + qb) * 256 + d] = o1acc[dc][r] + obuf[qb * 256 + d];
            }
        if (l < 16) {
            ps[(chunk * 4 + h) * 2048 + q0 + l] =
                ssum_sh[0][h][0][l] + ssum_sh[1][h][0][l];
            ps[(chunk * 4 + h) * 2048 + q0 + 16 + l] =
                ssum_sh[0][h][1][l] + ssum_sh[1][h][1][l];
        }
    }
}

// ---------------------------------------------------------------------------
// 5. Combine k-half partials: AO = (po0+po1)/s (fp16), sinv_ws = 1/s.
// ---------------------------------------------------------------------------
__global__ __launch_bounds__(256) void combine_kernel(
    const float* __restrict__ po_a, const float* __restrict__ po_b,
    const float* __restrict__ ps, unsigned short* __restrict__ AO,
    float* __restrict__ sinv_ws) {
    const int t = blockIdx.x * 256 + threadIdx.x;
    const int d4 = t & 63;
    const int bq = t >> 6;
    const int q = bq & 2047;
    const int b = bq >> 11;
    const int d0 = d4 * 4, h = d0 >> 6;
    const int c0 = b * 2, c1 = b * 2 + 1;
    const float* p0 = (c0 < 2) ? po_a + (size_t)c0 * 524288 : po_b + (size_t)(c0 - 2) * 524288;
    const float* p1 = (c1 < 2) ? po_a + (size_t)c1 * 524288 : po_b + (size_t)(c1 - 2) * 524288;
    float4 x = *reinterpret_cast<const float4*>(&p0[(size_t)q * 256 + d0]);
    float4 y = *reinterpret_cast<const float4*>(&p1[(size_t)q * 256 + d0]);
    float s = ps[(c0 * 4 + h) * 2048 + q] + ps[(c1 * 4 + h) * 2048 + q];
    float si = 1.0f / s;
    ushort4 o;
    o.x = f2h((x.x + y.x) * si); o.y = f2h((x.y + y.y) * si);
    o.z = f2h((x.z + y.z) * si); o.w = f2h((x.w + y.w) * si);
    *reinterpret_cast<ushort4*>(&AO[((size_t)(b * 2048 + q)) * 256 + d0]) = o;
    if (d4 == (h << 4)) sinv_ws[(b * 4 + h) * 2048 + q] = si;
}

// ---------------------------------------------------------------------------
// 6. Attention pass 2: attn_mean.  Grid 2048 = 8 kslices x 256; 256 thr =
//    4 waves = (qs x kc) quadrants; each wave computes ALL 4 heads for its
//    16q x 16k tile -> head-mean in-register -> fp32 stores.  No P LDS.
//    p/4 = exp2(a*C2 + lr + log2(sinv) - 2).
// ---------------------------------------------------------------------------
__global__ __launch_bounds__(256, 4) void attn_mean_kernel(
    const unsigned short* __restrict__ Qh, const unsigned short* __restrict__ Kh,
    const float* __restrict__ rel, const float* __restrict__ sinv_ws,
    float* __restrict__ attn_mean) {
    const int kslice = blockIdx.x >> 8;
    const int inner = blockIdx.x & 255;
    const int sw = (inner & 7) * 32 + (inner >> 3);
    const int b = sw >> 6;
    const int q0 = (sw & 63) * 32;
    const int tid = threadIdx.x;
    const int w = tid >> 6;
    const int qs = w >> 1, kc = w & 1;                 // wave quadrant
    const int l = tid & 63, l15 = l & 15, lg = l >> 4;
    const int kb = b * 2048;
    const float C2 = 0.18033688011112042f;

    __shared__ __align__(16) unsigned short ldsK[2][8192];      // 32KB
    __shared__ float rel_lr[2048];                              // 8KB

#define STAGE_KM(dst_, kt_) do {                                                    \
    _Pragma("unroll")                                                               \
    for (int j_ = 0; j_ < 4; ++j_) {                                                \
        int s_ = w * 4 + j_;                                                        \
        int r_ = 2 * s_ + (l >> 5);                                                 \
        size_t so_ = (size_t)(kb + (kt_) * 32 + r_) * 256 +                         \
                     (((l & 31) ^ (r_ & 7)) << 3);                                  \
        gld16(&Kh[so_], &(dst_)[s_ * 512]);                                         \
    }                                                                               \
} while (0)

    {
        float4 v0 = reinterpret_cast<const float4*>(&rel[b * 2048])[tid * 2];
        float4 v1 = reinterpret_cast<const float4*>(&rel[b * 2048])[tid * 2 + 1];
        float* d = &rel_lr[tid * 8];
        d[0] = log2f(fmaxf(v0.x, 1e-6f)); d[1] = log2f(fmaxf(v0.y, 1e-6f));
        d[2] = log2f(fmaxf(v0.z, 1e-6f)); d[3] = log2f(fmaxf(v0.w, 1e-6f));
        d[4] = log2f(fmaxf(v1.x, 1e-6f)); d[5] = log2f(fmaxf(v1.y, 1e-6f));
        d[6] = log2f(fmaxf(v1.z, 1e-6f)); d[7] = log2f(fmaxf(v1.w, 1e-6f));
    }

    // Q A-frags for all 4 heads (row = q = l15 within this wave's qs half)
    half8 qf[4][2];
    {
        const int qrow = b * 2048 + q0 + qs * 16 + l15;
#pragma unroll
        for (int h = 0; h < 4; ++h)
#pragma unroll
            for (int kd = 0; kd < 2; ++kd)
                qf[h][kd] = ldh8(&Qh[qrow * 256 + h * 64 + kd * 32 + lg * 8]);
    }
    // lsi[h][r4] = log2(sinv_h(q)) - 2   (q = q0 + qs*16 + lg*4 + r4)
    float lsi[4][4];
#pragma unroll
    for (int h = 0; h < 4; ++h)
#pragma unroll
        for (int r4 = 0; r4 < 4; ++r4)
            lsi[h][r4] = log2f(sinv_ws[(b * 4 + h) * 2048 + q0 + qs * 16 + lg * 4 + r4]) - 2.0f;
    __syncthreads();

    const int kt0 = kslice * 8;
    STAGE_KM(ldsK[0], kt0);
    for (int ki = 0; ki < 8; ++ki) {
        const int kt = kt0 + ki;
        const int cur = ki & 1, nx = cur ^ 1;
        if (ki < 7) {
            STAGE_KM(ldsK[nx], kt + 1);
            asm volatile("s_waitcnt vmcnt(4)" ::: "memory");
        } else {
            asm volatile("s_waitcnt vmcnt(0)" ::: "memory");
        }
        asm volatile("s_barrier" ::: "memory");       // buf[cur] ready
        __builtin_amdgcn_sched_barrier(0);
        // B-frag: K row r = kc*16 + l15 (col=k), all 4 heads
        const int r = kc * 16 + l15;
        const int rx = r & 7;
        f32x4 a[4];
#pragma unroll
        for (int h = 0; h < 4; ++h) {
            half8 kf0 = ldh8(&ldsK[cur][r * 256 + (((h * 8 + lg) ^ rx) << 3)]);
            half8 kf1 = ldh8(&ldsK[cur][r * 256 + (((h * 8 + 4 + lg) ^ rx) << 3)]);
            f32x4 t = (f32x4){0.f, 0.f, 0.f, 0.f};
            t = MFMAH32(qf[h][0], kf0, t);
            t = MFMAH32(qf[h][1], kf1, t);
            a[h] = t;
        }
        const float lr = rel_lr[kt * 32 + kc * 16 + l15];
        const size_t kcol = (size_t)(kt * 32 + kc * 16 + l15);
#pragma unroll
        for (int r4 = 0; r4 < 4; ++r4) {
            float m = exp2f(__builtin_fmaf(a[0][r4], C2, lsi[0][r4]) + lr)
                    + exp2f(__builtin_fmaf(a[1][r4], C2, lsi[1][r4]) + lr)
                    + exp2f(__builtin_fmaf(a[2][r4], C2, lsi[2][r4]) + lr)
                    + exp2f(__builtin_fmaf(a[3][r4], C2, lsi[3][r4]) + lr);
            attn_mean[(size_t)(b * 2048 + q0 + qs * 16 + lg * 4 + r4) * 2048 + kcol] = m;
        }
        asm volatile("s_waitcnt lgkmcnt(0)\n\ts_barrier" ::: "memory");  // reads done
    }
#undef STAGE_KM
}

// ---------------------------------------------------------------------------
// 7. out = AO @ Wo + bo
// ---------------------------------------------------------------------------
__global__ __launch_bounds__(512, 1) void final_kernel(
    const unsigned short* __restrict__ AO, const unsigned short* __restrict__ WoT,
    const float* __restrict__ bo, float* __restrict__ out) {
    __shared__ __align__(16) unsigned short wlds[2][256 * 64];

    const int w = threadIdx.x >> 6, l = threadIdx.x & 63;
    const int l15 = l & 15, lg = l >> 4;
    const int arow = blockIdx.x * 128 + w * 16 + l15;

    half8 ah[8];
#pragma unroll
    for (int ks = 0; ks < 8; ++ks)
        ah[ks] = ldh8(&AO[arow * 256 + ks * 32 + lg * 8]);
    f32x4 acc[16];
#pragma unroll
    for (int n = 0; n < 16; ++n) acc[n] = (f32x4){0.f, 0.f, 0.f, 0.f};

    STAGE_W(wlds[0], WoT, 0);
    __syncthreads();
#pragma unroll
    for (int kt = 0; kt < 4; ++kt) {
        const int cur = kt & 1, nx = cur ^ 1;
        if (kt < 3) STAGE_W(wlds[nx], WoT, kt + 1);
        GEMM_TILE(wlds[cur], kt);
        __syncthreads();
    }

    const int orow0 = blockIdx.x * 128 + w * 16 + lg * 4;
#pragma unroll
    for (int n = 0; n < 16; ++n) {
        const int col = n * 16 + l15;
        const float bn = bo[col];
#pragma unroll
        for (int r = 0; r < 4; ++r)
            out[(orow0 + r) * 256 + col] = acc[n][r] + bn;
    }
}

// ---------------------------------------------------------------------------
extern "C" void kernel_launch(void* const* d_in, const int* in_sizes, int n_in,
                              void* d_out, int out_size, void* d_ws, size_t ws_size,
                              hipStream_t stream) {
    const float* query = (const float*)d_in[0];
    const float* kv    = (const float*)d_in[1];
    const float* rel   = (const float*)d_in[2];
    const float* Wq    = (const float*)d_in[3];
    const float* bq    = (const float*)d_in[4];
    const float* Wk    = (const float*)d_in[5];
    const float* bk    = (const float*)d_in[6];
    const float* Wv    = (const float*)d_in[7];
    const float* bv    = (const float*)d_in[8];
    const float* Wo    = (const float*)d_in[9];
    const float* bo    = (const float*)d_in[10];

    char* ws = (char*)d_ws;
    unsigned short* WT   = (unsigned short*)(ws + 0);          // 512KB
    unsigned short* Qh   = (unsigned short*)(ws + 524288);     // 4MB
    unsigned short* Kh   = (unsigned short*)(ws + 4718592);    // 4MB
    unsigned short* Vtmp = (unsigned short*)(ws + 8912896);    // 4MB (po chunks 0,1 after transpose)
    unsigned short* Vt   = (unsigned short*)(ws + 13107200);   // 4MB
    unsigned short* AO   = (unsigned short*)(ws + 17301504);   // 4MB
    float*          sinv = (float*)(ws + 21495808);            // 128KB
    float*          ps   = (float*)(ws + 21626880);            // 256KB
    float*          po_b = (float*)(ws + 21889024);            // 12MB -> end ~32.9MB
    float*          po_a = (float*)Vtmp;                       // overlay (Vtmp dead post-transpose)

    float* out = (float*)d_out;
    float* attn_mean = (float*)d_out + 2097152;

    wsplit_kernel<<<1024, 256, 0, stream>>>(Wq, Wk, Wv, Wo, WT);
    proj3_kernel<<<dim3(64, 3), 512, 0, stream>>>(query, kv, rel, WT,
                                                  bq, bk, bv, Qh, Kh, Vtmp);
    transpose_v_kernel<<<dim3(128, 4), 256, 0, stream>>>(Vtmp, Vt);
    attn_pass1<<<512, 512, 0, stream>>>(Qh, Kh, Vt, rel, po_a, po_b, ps);
    combine_kernel<<<2048, 256, 0, stream>>>(po_a, po_b, ps, AO, sinv);
    attn_mean_kernel<<<2048, 256, 0, stream>>>(Qh, Kh, rel, sinv, attn_mean);
    final_kernel<<<64, 512, 0, stream>>>(AO, WT + 3 * 65536, bo, out);
}

// Round 11
// 109.780 us; speedup vs baseline: 3.8236x; 1.0181x over previous
//
#include <hip/hip_runtime.h>

// ---------------------------------------------------------------------------
// ReliabilityGatedCrossAttention — fp16 MFMA pipeline, gfx950.  R11.
//
// R10 post-mortem: pass1 dominated by K/V re-staging (512MB staged for 8MB
// data; each byte feeds only 2 MFMAs).  R11: double q-reuse per staged byte:
//   * pass1: 64 q-rows/block (4 qf frags/wave), grid 256 (32qt x 4b x 2kh).
//     Staging traffic halves; 8xK32 + 16xK16 MFMA per iter per wave.
//   * attn_mean: 64 q-rows/block (wave=qs, kc looped), grid 1024
//     (8 kslices x 32qt x 4b) -> still 4 blocks/CU; K staging halves.
// Everything else unchanged from R10.
// ---------------------------------------------------------------------------

typedef __attribute__((ext_vector_type(8))) _Float16 half8;
typedef __attribute__((ext_vector_type(4))) _Float16 half4;
typedef __attribute__((ext_vector_type(2))) __fp16 fp16x2;   // cvt_pkrtz result type
typedef __attribute__((ext_vector_type(4))) float f32x4;

#define MFMAH32(A, B, C) __builtin_amdgcn_mfma_f32_16x16x32_f16((A), (B), (C), 0, 0, 0)
#define MFMAH16(A, B, C) __builtin_amdgcn_mfma_f32_16x16x16f16((A), (B), (C), 0, 0, 0)

__device__ __forceinline__ unsigned short f2h(float f) {
    union { _Float16 h; unsigned short u; } c; c.h = (_Float16)f; return c.u;
}
__device__ __forceinline__ float h2f(unsigned short u) {
    union { unsigned short u; _Float16 h; } c; c.u = u; return (float)c.h;
}
__device__ __forceinline__ half8 ldh8(const unsigned short* p) {
    return *reinterpret_cast<const half8*>(p);
}
__device__ __forceinline__ half4 ldh4(const unsigned short* p) {
    return *reinterpret_cast<const half4*>(p);
}
__device__ __forceinline__ half4 pk4(float a, float b, float c, float d) {
    union { fp16x2 h2[2]; half4 h4; } u;
    u.h2[0] = __builtin_amdgcn_cvt_pkrtz(a, b);
    u.h2[1] = __builtin_amdgcn_cvt_pkrtz(c, d);
    return u.h4;
}
__device__ __forceinline__ void gld16(const unsigned short* g, unsigned short* l) {
    __builtin_amdgcn_global_load_lds(
        (const __attribute__((address_space(1))) unsigned int*)g,
        (__attribute__((address_space(3))) unsigned int*)l, 16, 0, 0);
}

// ---------------------------------------------------------------------------
// 1. Weights -> fp16, transposed [n][k]
// ---------------------------------------------------------------------------
__global__ void wsplit_kernel(const float* __restrict__ Wq, const float* __restrict__ Wk,
                              const float* __restrict__ Wv, const float* __restrict__ Wo,
                              unsigned short* __restrict__ WT) {
    int e = blockIdx.x * 256 + threadIdx.x;
    int m = e >> 16;
    int idx = e & 65535;
    int k = idx >> 8, n = idx & 255;
    const float* W = (m == 0) ? Wq : (m == 1) ? Wk : (m == 2) ? Wv : Wo;
    WT[m * 65536 + n * 256 + k] = f2h(W[idx]);
}

// ---------------------------------------------------------------------------
// Weight-staged fp16 GEMM core (proj3 + final).
// ---------------------------------------------------------------------------
#define STAGE_W(dst_, src_, kt_) do {                                               \
    _Pragma("unroll")                                                               \
    for (int j_ = 0; j_ < 4; ++j_) {                                                \
        int s_ = w * 4 + j_;                                                        \
        int rowl_ = 8 * s_ + (l >> 3);                                              \
        int so_ = rowl_ * 256 + (kt_) * 64 + (((l & 7) ^ (rowl_ & 7)) << 3);        \
        gld16(&(src_)[so_], &(dst_)[s_ * 512]);                                     \
    }                                                                               \
} while (0)

#define GEMM_TILE(buf_, kt_) do {                                                   \
    _Pragma("unroll")                                                               \
    for (int ksl_ = 0; ksl_ < 2; ++ksl_) {                                          \
        _Pragma("unroll")                                                           \
        for (int n_ = 0; n_ < 16; ++n_) {                                           \
            int r_ = n_ * 16 + l15;                                                 \
            int idx_ = r_ * 64 + ((((ksl_)*4 + lg) ^ (r_ & 7)) << 3);               \
            half8 b_ = ldh8(&(buf_)[idx_]);                                         \
            acc[n_] = MFMAH32(ah[(kt_) * 2 + ksl_], b_, acc[n_]);                   \
        }                                                                           \
    }                                                                               \
} while (0)

// ---------------------------------------------------------------------------
// 2. Projections (job 0:Q, 1:K, 2:V).  512 thr, 128 rows/block, grid (64,3).
// ---------------------------------------------------------------------------
__global__ __launch_bounds__(512, 1) void proj3_kernel(
    const float* __restrict__ query, const float* __restrict__ kv,
    const float* __restrict__ rel, const unsigned short* __restrict__ WT,
    const float* __restrict__ bq, const float* __restrict__ bk, const float* __restrict__ bv,
    unsigned short* __restrict__ Qh, unsigned short* __restrict__ Kh,
    unsigned short* __restrict__ Vtmp) {
    const int job = blockIdx.y;
    const float* X = (job == 0) ? query : kv;
    const unsigned short* wg = WT + job * 65536;
    const float* bias = (job == 0) ? bq : (job == 1) ? bk : bv;
    const float* rs = (job == 0) ? nullptr : rel;
    unsigned short* oh = (job == 0) ? Qh : (job == 1) ? Kh : Vtmp;

    __shared__ __align__(16) unsigned short wlds[2][256 * 64];

    const int w = threadIdx.x >> 6, l = threadIdx.x & 63;
    const int l15 = l & 15, lg = l >> 4;
    const int arow = blockIdx.x * 128 + w * 16 + l15;

    half8 ah[8];
#pragma unroll
    for (int ks = 0; ks < 8; ++ks) {
        const float* p = &X[arow * 256 + ks * 32 + lg * 8];
        float4 f0 = *reinterpret_cast<const float4*>(p);
        float4 f1 = *reinterpret_cast<const float4*>(p + 4);
        half8 t;
        t[0] = (_Float16)f0.x; t[1] = (_Float16)f0.y; t[2] = (_Float16)f0.z; t[3] = (_Float16)f0.w;
        t[4] = (_Float16)f1.x; t[5] = (_Float16)f1.y; t[6] = (_Float16)f1.z; t[7] = (_Float16)f1.w;
        ah[ks] = t;
    }
    f32x4 acc[16];
#pragma unroll
    for (int n = 0; n < 16; ++n) acc[n] = (f32x4){0.f, 0.f, 0.f, 0.f};

    STAGE_W(wlds[0], wg, 0);
    __syncthreads();
#pragma unroll
    for (int kt = 0; kt < 4; ++kt) {
        const int cur = kt & 1, nx = cur ^ 1;
        if (kt < 3) STAGE_W(wlds[nx], wg, kt + 1);
        GEMM_TILE(wlds[cur], kt);
        __syncthreads();
    }

    const int orow0 = blockIdx.x * 128 + w * 16 + lg * 4;
    float rsv[4];
#pragma unroll
    for (int r = 0; r < 4; ++r) rsv[r] = rs ? rs[orow0 + r] : 1.0f;
#pragma unroll
    for (int n = 0; n < 16; ++n) {
        const int col = n * 16 + l15;
        const float bn = bias[col];
#pragma unroll
        for (int r = 0; r < 4; ++r)
            oh[(orow0 + r) * 256 + col] = f2h((acc[n][r] + bn) * rsv[r]);
    }
}

// ---------------------------------------------------------------------------
// 3. Transpose V: Vtmp [b][k][256 d] -> Vt [b][st=k/16][256 d][16 k]
// ---------------------------------------------------------------------------
__global__ void transpose_v_kernel(const unsigned short* __restrict__ Vtmp,
                                   unsigned short* __restrict__ Vt) {
    __shared__ unsigned short tile[16][264];
    const int st = blockIdx.x, b = blockIdx.y;
    const int t = threadIdx.x;
#pragma unroll
    for (int it = 0; it < 4; ++it) {
        int idx = it * 256 + t;              // ushort4 units, 1024 total
        int kr = idx >> 6;
        int d4 = (idx & 63) * 4;
        ushort4 v = *reinterpret_cast<const ushort4*>(
            &Vtmp[(size_t)(b * 2048 + st * 16 + kr) * 256 + d4]);
        tile[kr][d4 + 0] = v.x; tile[kr][d4 + 1] = v.y;
        tile[kr][d4 + 2] = v.z; tile[kr][d4 + 3] = v.w;
    }
    __syncthreads();
    {
        const int d = t;
        unsigned int u[8];
#pragma unroll
        for (int k2 = 0; k2 < 8; ++k2)
            u[k2] = (unsigned int)tile[k2 * 2][d] | ((unsigned int)tile[k2 * 2 + 1][d] << 16);
        uint4* dst = reinterpret_cast<uint4*>(&Vt[((size_t)(b * 128 + st) * 256 + d) * 16]);
        dst[0] = (uint4){u[0], u[1], u[2], u[3]};
        dst[1] = (uint4){u[4], u[5], u[6], u[7]};
    }
}

// ---------------------------------------------------------------------------
// 4. Attention pass 1, R11.  Grid 256 = 32 qtiles(64 rows) x 4 b x 2 kh.
//    512 thr = 8 waves = (4 heads) x (2 k-subhalves).  Each wave: 4 q-subtile
//    fragments (qf[4][2]) -> each staged K/V byte feeds 4 q-subtiles.
//    Per-wave private dbuf staging, counted vmcnt(4), no loop barriers.
// ---------------------------------------------------------------------------
__global__ __launch_bounds__(512, 2) void attn_pass1(
    const unsigned short* __restrict__ Qh, const unsigned short* __restrict__ Kh,
    const unsigned short* __restrict__ Vt, const float* __restrict__ rel,
    float* __restrict__ po_a, float* __restrict__ po_b, float* __restrict__ ps) {
    const int bid = blockIdx.x;                       // 0..255
    const int sw = (bid & 7) * 32 + (bid >> 3);       // XCD batch-locality
    const int b = sw >> 6;
    const int rem = sw & 63;
    const int kh = rem & 1;
    const int q0 = (rem >> 1) * 64;                   // 64-row q tile
    const int tid = threadIdx.x;
    const int w = tid >> 6, h = w & 3, ks = w >> 2;
    const int l = tid & 63, l15 = l & 15, lg = l >> 4;
    const float C2 = 0.18033688011112042f;            // 0.125 * log2(e)

    // [0]=K, [1]=V per-wave private double buffers (contiguous 64KB)
    __shared__ __align__(16) unsigned short ldsKV[2][8][2][1024];   // 64KB
    __shared__ float rel_lr[2048];                                  // 8KB
    __shared__ float ssum_sh[2][4][64];                             // 2KB

    {   // lr = log2(clamp(rel))
        float4 v = reinterpret_cast<const float4*>(&rel[b * 2048])[tid];
        float* d = &rel_lr[tid * 4];
        d[0] = log2f(fmaxf(v.x, 1e-6f)); d[1] = log2f(fmaxf(v.y, 1e-6f));
        d[2] = log2f(fmaxf(v.z, 1e-6f)); d[3] = log2f(fmaxf(v.w, 1e-6f));
    }

    half8 qf[4][2];                                   // [qs][kd] B-frags
#pragma unroll
    for (int qs = 0; qs < 4; ++qs)
#pragma unroll
        for (int kd = 0; kd < 2; ++kd)
            qf[qs][kd] = ldh8(&Qh[(b * 2048 + q0 + qs * 16 + l15) * 256 +
                                  h * 64 + kd * 32 + lg * 8]);
    __syncthreads();

    const int st0 = kh * 64 + ks * 32;                // 16-row step units

#define STG(buf_, i_) do {                                                          \
    const unsigned short* kbp_ = Kh + (size_t)(b * 2048 + (st0 + (i_)) * 16) * 256  \
                                 + h * 64;                                          \
    _Pragma("unroll")                                                               \
    for (int j_ = 0; j_ < 2; ++j_) {                                                \
        int r_ = j_ * 8 + (l >> 3);                                                 \
        gld16(kbp_ + r_ * 256 + (((l & 7) ^ ((l >> 3) & 7)) << 3),                  \
              &ldsKV[0][w][buf_][j_ * 512]);                                        \
    }                                                                               \
    const unsigned short* vbp_ = Vt + (size_t)((b * 128 + st0 + (i_)) * 256         \
                                 + h * 64) * 16;                                    \
    _Pragma("unroll")                                                               \
    for (int j_ = 0; j_ < 2; ++j_) {                                                \
        int d_ = j_ * 32 + (l >> 1);                                                \
        gld16(vbp_ + d_ * 16 + (((l & 1) ^ ((l >> 1) & 1)) << 3),                   \
              &ldsKV[1][w][buf_][j_ * 512]);                                        \
    }                                                                               \
} while (0)

    float ssum[4] = {0.f, 0.f, 0.f, 0.f};
    f32x4 oacc[4][4];
#pragma unroll
    for (int qs = 0; qs < 4; ++qs)
#pragma unroll
        for (int dc = 0; dc < 4; ++dc)
            oacc[qs][dc] = (f32x4){0.f, 0.f, 0.f, 0.f};

    STG(0, 0);
    for (int i = 0; i < 32; ++i) {
        const int cur = i & 1, nx = cur ^ 1;
        if (i < 31) {
            STG(nx, i + 1);
            asm volatile("s_waitcnt vmcnt(4)" ::: "memory");
        } else {
            asm volatile("s_waitcnt vmcnt(0)" ::: "memory");
        }
        __builtin_amdgcn_sched_barrier(0);
        half8 kf0 = ldh8(&ldsKV[0][w][cur][l15 * 64 + ((lg ^ (l15 & 7)) << 3)]);
        half8 kf1 = ldh8(&ldsKV[0][w][cur][l15 * 64 + (((4 + lg) ^ (l15 & 7)) << 3)]);
        f32x4 a[4];
#pragma unroll
        for (int qs = 0; qs < 4; ++qs) {
            f32x4 t = (f32x4){0.f, 0.f, 0.f, 0.f};
            t = MFMAH32(kf0, qf[qs][0], t);           // swapped: S^T
            t = MFMAH32(kf1, qf[qs][1], t);
            a[qs] = t;
        }
        float4 lr4 = *reinterpret_cast<const float4*>(&rel_lr[(st0 + i) * 16 + lg * 4]);
        half4 pa[4];
#pragma unroll
        for (int qs = 0; qs < 4; ++qs) {
            float p0 = exp2f(__builtin_fmaf(a[qs][0], C2, lr4.x));
            float p1 = exp2f(__builtin_fmaf(a[qs][1], C2, lr4.y));
            float p2 = exp2f(__builtin_fmaf(a[qs][2], C2, lr4.z));
            float p3 = exp2f(__builtin_fmaf(a[qs][3], C2, lr4.w));
            ssum[qs] += (p0 + p1) + (p2 + p3);
            pa[qs] = pk4(p0, p1, p2, p3);
        }
#pragma unroll
        for (int dc = 0; dc < 4; ++dc) {
            const int d = dc * 16 + l15;
            half4 vf = ldh4(&ldsKV[1][w][cur][d * 16 +
                            ((((lg >> 1) ^ (d & 1))) << 3) + (lg & 1) * 4]);
#pragma unroll
            for (int qs = 0; qs < 4; ++qs)
                oacc[qs][dc] = MFMAH16(pa[qs], vf, oacc[qs][dc]);
        }
    }
#undef STG

    float vred[4];
#pragma unroll
    for (int qs = 0; qs < 4; ++qs) {
        float v = ssum[qs];
        v += __shfl_xor(v, 16); v += __shfl_xor(v, 32);
        vred[qs] = v;
    }

    __syncthreads();                                  // done with ldsKV
    if (l < 16) {
#pragma unroll
        for (int qs = 0; qs < 4; ++qs)
            ssum_sh[ks][h][qs * 16 + l] = vred[qs];
    }
    float* obuf = (float*)&ldsKV[0][0][0][0];         // [64 q][256 d] = 64KB
    if (ks == 1) {
#pragma unroll
        for (int qs = 0; qs < 4; ++qs)
#pragma unroll
            for (int dc = 0; dc < 4; ++dc)
#pragma unroll
                for (int r = 0; r < 4; ++r)
                    obuf[(qs * 16 + lg * 4 + r) * 256 + h * 64 + dc * 16 + l15] =
                        oacc[qs][dc][r];
    }
    __syncthreads();
    if (ks == 0) {
        const int chunk = b * 2 + kh;
        float* po = (chunk < 2) ? (po_a + (size_t)chunk * 524288)
                                : (po_b + (size_t)(chunk - 2) * 524288);
#pragma unroll
        for (int qs = 0; qs < 4; ++qs)
#pragma unroll
            for (int dc = 0; dc < 4; ++dc)
#pragma unroll
                for (int r = 0; r < 4; ++r) {
                    const int d = h * 64 + dc * 16 + l15;
                    const int q = qs * 16 + lg * 4 + r;
                    po[(size_t)(q0 + q) * 256 + d] = oacc[qs][dc][r] + obuf[q * 256 + d];
                }
        if (l < 16) {
#pragma unroll
            for (int qs = 0; qs < 4; ++qs)
                ps[(chunk * 4 + h) * 2048 + q0 + qs * 16 + l] =
                    ssum_sh[0][h][qs * 16 + l] + ssum_sh[1][h][qs * 16 + l];
        }
    }
}

// ---------------------------------------------------------------------------
// 5. Combine k-half partials: AO = (po0+po1)/s (fp16), sinv_ws = 1/s.
// ---------------------------------------------------------------------------
__global__ __launch_bounds__(256) void combine_kernel(
    const float* __restrict__ po_a, const float* __restrict__ po_b,
    const float* __restrict__ ps, unsigned short* __restrict__ AO,
    float* __restrict__ sinv_ws) {
    const int t = blockIdx.x * 256 + threadIdx.x;
    const int d4 = t & 63;
    const int bq = t >> 6;
    const int q = bq & 2047;
    const int b = bq >> 11;
    const int d0 = d4 * 4, h = d0 >> 6;
    const int c0 = b * 2, c1 = b * 2 + 1;
    const float* p0 = (c0 < 2) ? po_a + (size_t)c0 * 524288 : po_b + (size_t)(c0 - 2) * 524288;
    const float* p1 = (c1 < 2) ? po_a + (size_t)c1 * 524288 : po_b + (size_t)(c1 - 2) * 524288;
    float4 x = *reinterpret_cast<const float4*>(&p0[(size_t)q * 256 + d0]);
    float4 y = *reinterpret_cast<const float4*>(&p1[(size_t)q * 256 + d0]);
    float s = ps[(c0 * 4 + h) * 2048 + q] + ps[(c1 * 4 + h) * 2048 + q];
    float si = 1.0f / s;
    ushort4 o;
    o.x = f2h((x.x + y.x) * si); o.y = f2h((x.y + y.y) * si);
    o.z = f2h((x.z + y.z) * si); o.w = f2h((x.w + y.w) * si);
    *reinterpret_cast<ushort4*>(&AO[((size_t)(b * 2048 + q)) * 256 + d0]) = o;
    if (d4 == (h << 4)) sinv_ws[(b * 4 + h) * 2048 + q] = si;
}

// ---------------------------------------------------------------------------
// 6. Attention pass 2: attn_mean.  Grid 1024 = 8 kslices x (4b x 32 qt of
//    64 rows); 256 thr = 4 waves = qs.  kc looped inside.  Head-mean fully
//    in-register -> fp32 stores.  p/4 = exp2(a*C2 + lr + log2(sinv) - 2).
// ---------------------------------------------------------------------------
__global__ __launch_bounds__(256, 4) void attn_mean_kernel(
    const unsigned short* __restrict__ Qh, const unsigned short* __restrict__ Kh,
    const float* __restrict__ rel, const float* __restrict__ sinv_ws,
    float* __restrict__ attn_mean) {
    const int kslice = blockIdx.x >> 7;               // 0..7
    const int inner = blockIdx.x & 127;
    const int sw = (inner & 7) * 16 + (inner >> 3);   // XCD batch-locality
    const int b = sw >> 5;
    const int q0 = (sw & 31) * 64;                    // 64-row q tile
    const int tid = threadIdx.x;
    const int w = tid >> 6;                           // wave = qs (0..3)
    const int l = tid & 63, l15 = l & 15, lg = l >> 4;
    const int kb = b * 2048;
    const float C2 = 0.18033688011112042f;

    __shared__ __align__(16) unsigned short ldsK[2][8192];      // 32KB
    __shared__ float rel_lr[2048];                              // 8KB

#define STAGE_KM(dst_, kt_) do {                                                    \
    _Pragma("unroll")                                                               \
    for (int j_ = 0; j_ < 4; ++j_) {                                                \
        int s_ = w * 4 + j_;                                                        \
        int r_ = 2 * s_ + (l >> 5);                                                 \
        size_t so_ = (size_t)(kb + (kt_) * 32 + r_) * 256 +                         \
                     (((l & 31) ^ (r_ & 7)) << 3);                                  \
        gld16(&Kh[so_], &(dst_)[s_ * 512]);                                         \
    }                                                                               \
} while (0)

    {
        float4 v0 = reinterpret_cast<const float4*>(&rel[b * 2048])[tid * 2];
        float4 v1 = reinterpret_cast<const float4*>(&rel[b * 2048])[tid * 2 + 1];
        float* d = &rel_lr[tid * 8];
        d[0] = log2f(fmaxf(v0.x, 1e-6f)); d[1] = log2f(fmaxf(v0.y, 1e-6f));
        d[2] = log2f(fmaxf(v0.z, 1e-6f)); d[3] = log2f(fmaxf(v0.w, 1e-6f));
        d[4] = log2f(fmaxf(v1.x, 1e-6f)); d[5] = log2f(fmaxf(v1.y, 1e-6f));
        d[6] = log2f(fmaxf(v1.z, 1e-6f)); d[7] = log2f(fmaxf(v1.w, 1e-6f));
    }

    // Q A-frags for all 4 heads (row = q = q0 + w*16 + l15)
    half8 qf[4][2];
    {
        const int qrow = b * 2048 + q0 + w * 16 + l15;
#pragma unroll
        for (int h = 0; h < 4; ++h)
#pragma unroll
            for (int kd = 0; kd < 2; ++kd)
                qf[h][kd] = ldh8(&Qh[qrow * 256 + h * 64 + kd * 32 + lg * 8]);
    }
    // lsi[h][r4] = log2(sinv_h(q)) - 2   (q = q0 + w*16 + lg*4 + r4)
    float lsi[4][4];
#pragma unroll
    for (int h = 0; h < 4; ++h)
#pragma unroll
        for (int r4 = 0; r4 < 4; ++r4)
            lsi[h][r4] = log2f(sinv_ws[(b * 4 + h) * 2048 + q0 + w * 16 + lg * 4 + r4]) - 2.0f;
    __syncthreads();

    const int kt0 = kslice * 8;
    STAGE_KM(ldsK[0], kt0);
    for (int ki = 0; ki < 8; ++ki) {
        const int kt = kt0 + ki;
        const int cur = ki & 1, nx = cur ^ 1;
        if (ki < 7) {
            STAGE_KM(ldsK[nx], kt + 1);
            asm volatile("s_waitcnt vmcnt(4)" ::: "memory");
        } else {
            asm volatile("s_waitcnt vmcnt(0)" ::: "memory");
        }
        asm volatile("s_barrier" ::: "memory");       // buf[cur] ready
        __builtin_amdgcn_sched_barrier(0);
#pragma unroll
        for (int kc = 0; kc < 2; ++kc) {
            const int r = kc * 16 + l15;
            const int rx = r & 7;
            f32x4 a[4];
#pragma unroll
            for (int h = 0; h < 4; ++h) {
                half8 kf0 = ldh8(&ldsK[cur][r * 256 + (((h * 8 + lg) ^ rx) << 3)]);
                half8 kf1 = ldh8(&ldsK[cur][r * 256 + (((h * 8 + 4 + lg) ^ rx) << 3)]);
                f32x4 t = (f32x4){0.f, 0.f, 0.f, 0.f};
                t = MFMAH32(qf[h][0], kf0, t);
                t = MFMAH32(qf[h][1], kf1, t);
                a[h] = t;
            }
            const float lr = rel_lr[kt * 32 + kc * 16 + l15];
            const size_t kcol = (size_t)(kt * 32 + kc * 16 + l15);
#pragma unroll
            for (int r4 = 0; r4 < 4; ++r4) {
                float m = exp2f(__builtin_fmaf(a[0][r4], C2, lsi[0][r4]) + lr)
                        + exp2f(__builtin_fmaf(a[1][r4], C2, lsi[1][r4]) + lr)
                        + exp2f(__builtin_fmaf(a[2][r4], C2, lsi[2][r4]) + lr)
                        + exp2f(__builtin_fmaf(a[3][r4], C2, lsi[3][r4]) + lr);
                attn_mean[(size_t)(b * 2048 + q0 + w * 16 + lg * 4 + r4) * 2048 + kcol] = m;
            }
        }
        asm volatile("s_waitcnt lgkmcnt(0)\n\ts_barrier" ::: "memory");  // reads done
    }
#undef STAGE_KM
}

// ---------------------------------------------------------------------------
// 7. out = AO @ Wo + bo
// ---------------------------------------------------------------------------
__global__ __launch_bounds__(512, 1) void final_kernel(
    const unsigned short* __restrict__ AO, const unsigned short* __restrict__ WoT,
    const float* __restrict__ bo, float* __restrict__ out) {
    __shared__ __align__(16) unsigned short wlds[2][256 * 64];

    const int w = threadIdx.x >> 6, l = threadIdx.x & 63;
    const int l15 = l & 15, lg = l >> 4;
    const int arow = blockIdx.x * 128 + w * 16 + l15;

    half8 ah[8];
#pragma unroll
    for (int ks = 0; ks < 8; ++ks)
        ah[ks] = ldh8(&AO[arow * 256 + ks * 32 + lg * 8]);
    f32x4 acc[16];
#pragma unroll
    for (int n = 0; n < 16; ++n) acc[n] = (f32x4){0.f, 0.f, 0.f, 0.f};

    STAGE_W(wlds[0], WoT, 0);
    __syncthreads();
#pragma unroll
    for (int kt = 0; kt < 4; ++kt) {
        const int cur = kt & 1, nx = cur ^ 1;
        if (kt < 3) STAGE_W(wlds[nx], WoT, kt + 1);
        GEMM_TILE(wlds[cur], kt);
        __syncthreads();
    }

    const int orow0 = blockIdx.x * 128 + w * 16 + lg * 4;
#pragma unroll
    for (int n = 0; n < 16; ++n) {
        const int col = n * 16 + l15;
        const float bn = bo[col];
#pragma unroll
        for (int r = 0; r < 4; ++r)
            out[(orow0 + r) * 256 + col] = acc[n][r] + bn;
    }
}

// ---------------------------------------------------------------------------
extern "C" void kernel_launch(void* const* d_in, const int* in_sizes, int n_in,
                              void* d_out, int out_size, void* d_ws, size_t ws_size,
                              hipStream_t stream) {
    const float* query = (const float*)d_in[0];
    const float* kv    = (const float*)d_in[1];
    const float* rel   = (const float*)d_in[2];
    const float* Wq    = (const float*)d_in[3];
    const float* bq    = (const float*)d_in[4];
    const float* Wk    = (const float*)d_in[5];
    const float* bk    = (const float*)d_in[6];
    const float* Wv    = (const float*)d_in[7];
    const float* bv    = (const float*)d_in[8];
    const float* Wo    = (const float*)d_in[9];
    const float* bo    = (const float*)d_in[10];

    char* ws = (char*)d_ws;
    unsigned short* WT   = (unsigned short*)(ws + 0);          // 512KB
    unsigned short* Qh   = (unsigned short*)(ws + 524288);     // 4MB
    unsigned short* Kh   = (unsigned short*)(ws + 4718592);    // 4MB
    unsigned short* Vtmp = (unsigned short*)(ws + 8912896);    // 4MB (po chunks 0,1 after transpose)
    unsigned short* Vt   = (unsigned short*)(ws + 13107200);   // 4MB
    unsigned short* AO   = (unsigned short*)(ws + 17301504);   // 4MB
    float*          sinv = (float*)(ws + 21495808);            // 128KB
    float*          ps   = (float*)(ws + 21626880);            // 256KB
    float*          po_b = (float*)(ws + 21889024);            // 12MB -> end ~32.9MB
    float*          po_a = (float*)Vtmp;                       // overlay (Vtmp dead post-transpose)

    float* out = (float*)d_out;
    float* attn_mean = (float*)d_out + 2097152;

    wsplit_kernel<<<1024, 256, 0, stream>>>(Wq, Wk, Wv, Wo, WT);
    proj3_kernel<<<dim3(64, 3), 512, 0, stream>>>(query, kv, rel, WT,
                                                  bq, bk, bv, Qh, Kh, Vtmp);
    transpose_v_kernel<<<dim3(128, 4), 256, 0, stream>>>(Vtmp, Vt);
    attn_pass1<<<256, 512, 0, stream>>>(Qh, Kh, Vt, rel, po_a, po_b, ps);
    combine_kernel<<<2048, 256, 0, stream>>>(po_a, po_b, ps, AO, sinv);
    attn_mean_kernel<<<1024, 256, 0, stream>>>(Qh, Kh, rel, sinv, attn_mean);
    final_kernel<<<64, 512, 0, stream>>>(AO, WT + 3 * 65536, bo, out);
}